// Round 7
// baseline (312.764 us; speedup 1.0000x reference)
//
#include <hip/hip_runtime.h>
#include <math.h>

// B=4 S=1024 D=1024 P=128 H=8 E=16, NT=4096, TPOS=2047

typedef __attribute__((ext_vector_type(8))) short short8;
typedef __attribute__((ext_vector_type(4))) float floatx4;

__device__ __forceinline__ float bf2f(unsigned int u) {
    union { unsigned int i; float f; } x; x.i = (u & 0xffffu) << 16; return x.f;
}
__device__ __forceinline__ unsigned short f2bf(float f) {
    union { float f; unsigned int i; } x; x.f = f;
    unsigned int r = x.i + 0x7fffu + ((x.i >> 16) & 1u);
    return (unsigned short)(r >> 16);
}

// async global->LDS: per-lane global addr, wave-uniform LDS base; lane data at base + lane*16
__device__ __forceinline__ void gload16(const void* g, void* l) {
    __builtin_amdgcn_global_load_lds(
        (const __attribute__((address_space(1))) unsigned int*)(uintptr_t)g,
        (__attribute__((address_space(3))) unsigned int*)(uintptr_t)l,
        16, 0, 0);
}

// Fragment layouts (16x16x32 bf16 MFMA), HW-verified R2-R6:
//   A-frag (MxK):  afrag[m>>4][k>>5][((k&31)>>3)*16 + (m&15)][k&7]
//   B-frag (KxN):  bfrag[n>>4][k>>5][((k&31)>>3)*16 + (n&15)][k&7]
//   C/D:           col = lane&15, row = (lane>>4)*4 + reg
// Chunk view (R7): frag = array of 16B chunks; chunk c -> (tile = c>>11 or >>12, kc = (c&mask)>>6,
//   lane = c&63); one thread produces all 8 j's of a chunk -> wave writes 1KB contiguous.

// ---------------- k_prep R7: sel + chunk-coalesced converters, one launch ----------------
// blocks [0,4096): sel (token = bx); [4096,4224): w_q; [4224,4352): w_out; [4352,4368): w_kv;
// [4368,4376): pos_pk; [4376,4504): pe; [4504,4760): conv_act. Converter blocks: 8 chunk-iters x 256 t.
__global__ __launch_bounds__(256) void k_prep(const float* __restrict__ curr,
                                              const float* __restrict__ attend,
                                              const float* __restrict__ w_q,
                                              const float* __restrict__ w_out,
                                              const float* __restrict__ w_kv,
                                              const float* __restrict__ pos_pk,
                                              const float* __restrict__ sel_dst,
                                              float* __restrict__ selval,
                                              int* __restrict__ selidx,
                                              unsigned short* __restrict__ afrag,
                                              unsigned short* __restrict__ attfrag,
                                              unsigned short* __restrict__ bfragq,
                                              unsigned short* __restrict__ bfragw,
                                              unsigned short* __restrict__ bfragkv,
                                              unsigned short* __restrict__ bfragp,
                                              unsigned short* __restrict__ pefrag) {
    __shared__ float row[1024];
    __shared__ float sel[16];
    const int bx = blockIdx.x;
    const int t = threadIdx.x;

    if (bx < 4096) {
        // ---- sel: selection + top-8 + sigmoid + curr->A-frag (unchanged structure) ----
        const int token = bx;
        const float4 v = ((const float4*)(curr + (size_t)token * 1024))[t];
        ((float4*)row)[t] = v;
        {
            const int mt = token >> 4, kc = t >> 3;
            const int lane = ((t & 7) >> 1) * 16 + (token & 15);
            const size_t off = (((size_t)mt * 32 + kc) * 64 + lane) * 8 + 4 * (t & 1);
            uint2 o;
            o.x = (unsigned)f2bf(v.x) | ((unsigned)f2bf(v.y) << 16);
            o.y = (unsigned)f2bf(v.z) | ((unsigned)f2bf(v.w) << 16);
            *(uint2*)(afrag + off) = o;
        }
        __syncthreads();
        const int wv = t >> 6, lane = t & 63;
        for (int e0 = 0; e0 < 4; ++e0) {
            const int e = wv * 4 + e0;
            const float* w = sel_dst + e * 1024;
            float p = 0.f;
            for (int i = lane; i < 1024; i += 64) p += row[i] * w[i];
            for (int off = 32; off; off >>= 1) p += __shfl_down(p, off, 64);
            if (lane == 0) sel[e] = p;
        }
        __syncthreads();
        if (t == 0) {
            float v16[16];
#pragma unroll
            for (int e = 0; e < 16; ++e) v16[e] = sel[e];
#pragma unroll
            for (int r = 0; r < 8; ++r) {
                int bi = 0; float bv = v16[0];
#pragma unroll
                for (int e = 1; e < 16; ++e) { if (v16[e] > bv) { bv = v16[e]; bi = e; } }
                selidx[token * 8 + r] = bi;
                selval[token * 8 + r] = 1.f / (1.f + __expf(-bv));
                v16[bi] = -INFINITY;
            }
        }
    } else if (bx < 4224) {
        // ---- w_q -> bfragq (B-frag, KC=32, N=2048); strided col reads, contiguous 16B writes ----
        const int bi = bx - 4096;
#pragma unroll
        for (int i = 0; i < 8; ++i) {
            const int c = (bi * 8 + i) * 256 + t;           // chunk in [0, 262144)
            const int nt = c >> 11, cc = c & 2047;
            const int kc = cc >> 6, lane = cc & 63;
            const int n = nt * 16 + (lane & 15);
            const int e = n >> 7, p = n & 127;
            const int k0 = kc * 32 + (lane >> 4) * 8;
            const float* src = w_q + (size_t)e * 131072 + (size_t)k0 * 128 + p;
            short8 o;
#pragma unroll
            for (int j = 0; j < 8; ++j) o[j] = (short)f2bf(src[j * 128]);
            *(short8*)(bfragq + (size_t)c * 8) = o;
        }
    } else if (bx < 4352) {
        // ---- w_out -> bfragw (B-frag, KC=64, N=1024) ----
        const int bi = bx - 4224;
#pragma unroll
        for (int i = 0; i < 8; ++i) {
            const int c = (bi * 8 + i) * 256 + t;           // chunk in [0, 262144)
            const int nt = c >> 12, cc = c & 4095;
            const int kc = cc >> 6, lane = cc & 63;
            const int n = nt * 16 + (lane & 15);
            const int k0 = kc * 32 + (lane >> 4) * 8;
            const float* src = w_out + (size_t)k0 * 1024 + n;
            short8 o;
#pragma unroll
            for (int j = 0; j < 8; ++j) o[j] = (short)f2bf(src[j * 1024]);
            *(short8*)(bfragw + (size_t)c * 8) = o;
        }
    } else if (bx < 4368) {
        // ---- w_kv -> bfragkv (B-frag, KC=32, N=256) ----
        const int bi = bx - 4352;
#pragma unroll
        for (int i = 0; i < 8; ++i) {
            const int c = (bi * 8 + i) * 256 + t;           // chunk in [0, 32768)
            const int nt = c >> 11, cc = c & 2047;
            const int kc = cc >> 6, lane = cc & 63;
            const int n = nt * 16 + (lane & 15);
            const int k0 = kc * 32 + (lane >> 4) * 8;
            const float* src = w_kv + (size_t)k0 * 256 + n;
            short8 o;
#pragma unroll
            for (int j = 0; j < 8; ++j) o[j] = (short)f2bf(src[j * 256]);
            *(short8*)(bfragkv + (size_t)c * 8) = o;
        }
    } else if (bx < 4376) {
        // ---- pos_pk -> bfragp (B-frag, KC=32, N=128); source n-major -> contiguous reads ----
        const int bi = bx - 4368;
#pragma unroll
        for (int i = 0; i < 8; ++i) {
            const int c = (bi * 8 + i) * 256 + t;           // chunk in [0, 16384)
            const int nt = c >> 11, cc = c & 2047;
            const int kc = cc >> 6, lane = cc & 63;
            const int n = nt * 16 + (lane & 15);
            const int k0 = kc * 32 + (lane >> 4) * 8;
            const float4 u0 = *(const float4*)(pos_pk + (size_t)n * 1024 + k0);
            const float4 u1 = *(const float4*)(pos_pk + (size_t)n * 1024 + k0 + 4);
            short8 o;
            o[0] = (short)f2bf(u0.x); o[1] = (short)f2bf(u0.y);
            o[2] = (short)f2bf(u0.z); o[3] = (short)f2bf(u0.w);
            o[4] = (short)f2bf(u1.x); o[5] = (short)f2bf(u1.y);
            o[6] = (short)f2bf(u1.z); o[7] = (short)f2bf(u1.w);
            *(short8*)(bfragp + (size_t)c * 8) = o;
        }
    } else if (bx < 4504) {
        // ---- pe -> pefrag (A-frag, 2048 rows, row 2047 = 0) ----
        const int bi = bx - 4376;
        const float c1 = -logf(10000.f) / 1024.f;
#pragma unroll
        for (int i = 0; i < 8; ++i) {
            const int c = (bi * 8 + i) * 256 + t;           // chunk in [0, 262144)
            const int mt = c >> 11, cc = c & 2047;
            const int kc = cc >> 6, lane = cc & 63;
            const int m = mt * 16 + (lane & 15);
            const int k0 = kc * 32 + (lane >> 4) * 8;
            short8 o;
            if (m >= 2047) {
#pragma unroll
                for (int j = 0; j < 8; ++j) o[j] = (short)0;
            } else {
                const float pos = (float)(m - 1023);
#pragma unroll
                for (int d = 0; d < 4; ++d) {
                    const float a = pos * expf((float)(k0 + 2 * d) * c1);
                    o[2 * d]     = (short)f2bf(sinf(a));
                    o[2 * d + 1] = (short)f2bf(cosf(a));
                }
            }
            *(short8*)(pefrag + (size_t)c * 8) = o;
        }
    } else {
        // ---- attend -> attfrag (A-frag, 4096 rows); contiguous reads + contiguous writes ----
        const int bi = bx - 4504;
#pragma unroll
        for (int i = 0; i < 8; ++i) {
            const int c = (bi * 8 + i) * 256 + t;           // chunk in [0, 524288)
            const int mt = c >> 11, cc = c & 2047;
            const int kc = cc >> 6, lane = cc & 63;
            const int m = mt * 16 + (lane & 15);
            const int k0 = kc * 32 + (lane >> 4) * 8;
            const float4 u0 = *(const float4*)(attend + (size_t)m * 1024 + k0);
            const float4 u1 = *(const float4*)(attend + (size_t)m * 1024 + k0 + 4);
            short8 o;
            o[0] = (short)f2bf(u0.x); o[1] = (short)f2bf(u0.y);
            o[2] = (short)f2bf(u0.z); o[3] = (short)f2bf(u0.w);
            o[4] = (short)f2bf(u1.x); o[5] = (short)f2bf(u1.y);
            o[6] = (short)f2bf(u1.z); o[7] = (short)f2bf(u1.w);
            *(short8*)(attfrag + (size_t)c * 8) = o;
        }
    }
}

// ---------------- MFMA GEMM core: 128x64 tile, 4 waves, frag-ordered global in ----------------
__device__ __forceinline__ void gemm_core64(const unsigned short* __restrict__ Afrag,
                                            const unsigned short* __restrict__ Bfrag,
                                            int mt0, int nt0, int KC,
                                            unsigned short (*aT)[512],
                                            unsigned short (*bT)[512],
                                            floatx4 acc[4][2]) {
    const int t = threadIdx.x;
    const int w = t >> 6, lane = t & 63;
    const int wm = w >> 1, wn = w & 1;
    for (int kc = 0; kc < KC; ++kc) {
        __syncthreads();
        {
            const int fi = w * 3;
#pragma unroll
            for (int l = 0; l < 3; ++l) {
                const int f = fi + l;   // 0..11: 8 A-frags then 4 B-frags
                if (f < 8)
                    gload16(Afrag + (((size_t)(mt0 + f) * KC + kc) * 64 + lane) * 8, &aT[f][0]);
                else
                    gload16(Bfrag + (((size_t)(nt0 + f - 8) * KC + kc) * 64 + lane) * 8, &bT[f - 8][0]);
            }
        }
        __syncthreads();
        short8 af[4], bf[2];
#pragma unroll
        for (int i = 0; i < 4; ++i) af[i] = *(const short8*)&aT[wm * 4 + i][lane * 8];
#pragma unroll
        for (int j = 0; j < 2; ++j) bf[j] = *(const short8*)&bT[wn * 2 + j][lane * 8];
#pragma unroll
        for (int i = 0; i < 4; ++i)
#pragma unroll
            for (int j = 0; j < 2; ++j)
                acc[i][j] = __builtin_amdgcn_mfma_f32_16x16x32_bf16(af[i], bf[j], acc[i][j], 0, 0, 0);
    }
}

// ---------------- GEMM: kpos = pe @ pos_pk^T * sc -> kposfg B-frag layout ----------------
__global__ __launch_bounds__(256) void k_gemm_kpos(const unsigned short* __restrict__ Afrag,
                                                   const unsigned short* __restrict__ Bfrag,
                                                   const float* __restrict__ scale,
                                                   unsigned short* __restrict__ kposfg) {
    __shared__ __align__(16) unsigned short aT[8][512], bT[4][512];
    floatx4 acc[4][2];
#pragma unroll
    for (int i = 0; i < 4; ++i) { acc[i][0] = (floatx4){0,0,0,0}; acc[i][1] = (floatx4){0,0,0,0}; }
    gemm_core64(Afrag, Bfrag, blockIdx.x * 8, blockIdx.y * 4, 32, aT, bT, acc);
    const float sc = sqrtf(scale[0]);
    const int t = threadIdx.x, w = t >> 6, lane = t & 63;
    const int wm = w >> 1, wn = w & 1, lq = lane >> 4, lm = lane & 15;
#pragma unroll
    for (int i = 0; i < 4; ++i)
#pragma unroll
        for (int j = 0; j < 2; ++j) {
            const int p = blockIdx.y * 64 + (wn * 2 + j) * 16 + lm;
#pragma unroll
            for (int r = 0; r < 4; ++r) {
                const int tp = blockIdx.x * 128 + (wm * 4 + i) * 16 + lq * 4 + r;
                const size_t addr = (((size_t)(tp >> 4) * 4 + (p >> 5)) * 64 +
                                     ((p & 31) >> 3) * 16 + (tp & 15)) * 8 + (p & 7);
                kposfg[addr] = f2bf(acc[i][j][r] * sc);
            }
        }
}

// ---------------- GEMM: qall = curr @ [w_q] * sc -> bf16 row-major 4096x2048 ----------------
__global__ __launch_bounds__(256) void k_gemm_qall(const unsigned short* __restrict__ Afrag,
                                                   const unsigned short* __restrict__ Bfrag,
                                                   const float* __restrict__ scale,
                                                   unsigned short* __restrict__ qall) {
    __shared__ __align__(16) unsigned short aT[8][512], bT[4][512];
    floatx4 acc[4][2];
#pragma unroll
    for (int i = 0; i < 4; ++i) { acc[i][0] = (floatx4){0,0,0,0}; acc[i][1] = (floatx4){0,0,0,0}; }
    gemm_core64(Afrag, Bfrag, blockIdx.x * 8, blockIdx.y * 4, 32, aT, bT, acc);
    const float sc = sqrtf(scale[0]);
    const int t = threadIdx.x, w = t >> 6, lane = t & 63;
    const int wm = w >> 1, wn = w & 1, lq = lane >> 4, lm = lane & 15;
#pragma unroll
    for (int i = 0; i < 4; ++i)
#pragma unroll
        for (int j = 0; j < 2; ++j)
#pragma unroll
            for (int r = 0; r < 4; ++r)
                qall[(size_t)(blockIdx.x * 128 + (wm * 4 + i) * 16 + lq * 4 + r) * 2048 +
                     blockIdx.y * 64 + (wn * 2 + j) * 16 + lm] = f2bf(acc[i][j][r] * sc);
}

// ---------------- GEMM: out = zfrag @ w_out -> f32 row-major 4096x1024 ----------------
__global__ __launch_bounds__(256) void k_gemm_out(const unsigned short* __restrict__ Afrag,
                                                  const unsigned short* __restrict__ Bfrag,
                                                  float* __restrict__ out) {
    __shared__ __align__(16) unsigned short aT[8][512], bT[4][512];
    floatx4 acc[4][2];
#pragma unroll
    for (int i = 0; i < 4; ++i) { acc[i][0] = (floatx4){0,0,0,0}; acc[i][1] = (floatx4){0,0,0,0}; }
    gemm_core64(Afrag, Bfrag, blockIdx.x * 8, blockIdx.y * 4, 64, aT, bT, acc);
    const int t = threadIdx.x, w = t >> 6, lane = t & 63;
    const int wm = w >> 1, wn = w & 1, lq = lane >> 4, lm = lane & 15;
#pragma unroll
    for (int i = 0; i < 4; ++i)
#pragma unroll
        for (int j = 0; j < 2; ++j)
#pragma unroll
            for (int r = 0; r < 4; ++r)
                out[(size_t)(blockIdx.x * 128 + (wm * 4 + i) * 16 + lq * 4 + r) * 1024 +
                    blockIdx.y * 64 + (wn * 2 + j) * 16 + lm] = acc[i][j][r];
}

// ---------------- GEMM: kv = attend @ w_kv -> K/V B-fragment layouts (bf16) ----------------
__global__ __launch_bounds__(256) void k_gemm_kv(const unsigned short* __restrict__ Afrag,
                                                 const unsigned short* __restrict__ Bfrag,
                                                 const float* __restrict__ scale,
                                                 unsigned short* __restrict__ kfragg,
                                                 unsigned short* __restrict__ vfragg) {
    __shared__ __align__(16) unsigned short aT[8][512], bT[4][512];
    floatx4 acc[4][2];
#pragma unroll
    for (int i = 0; i < 4; ++i) { acc[i][0] = (floatx4){0,0,0,0}; acc[i][1] = (floatx4){0,0,0,0}; }
    gemm_core64(Afrag, Bfrag, blockIdx.x * 8, blockIdx.y * 4, 32, aT, bT, acc);
    const float sc = sqrtf(scale[0]);
    const int t = threadIdx.x, w = t >> 6, lane = t & 63;
    const int wm = w >> 1, wn = w & 1, lq = lane >> 4, lm = lane & 15;
#pragma unroll
    for (int i = 0; i < 4; ++i)
#pragma unroll
        for (int j = 0; j < 2; ++j) {
            const int n = blockIdx.y * 64 + (wn * 2 + j) * 16 + lm;
#pragma unroll
            for (int r = 0; r < 4; ++r) {
                const int tok = blockIdx.x * 128 + (wm * 4 + i) * 16 + lq * 4 + r;
                const int bb = tok >> 10, jj = tok & 1023;
                if (n < 128) {
                    const int p = n;
                    const size_t addr = ((((size_t)bb * 64 + (jj >> 4)) * 4 + (p >> 5)) * 64 +
                                         ((p & 31) >> 3) * 16 + (jj & 15)) * 8 + (p & 7);
                    kfragg[addr] = f2bf(acc[i][j][r] * sc);
                } else {
                    const int p = n - 128;
                    const size_t addr = ((((size_t)bb * 32 + (jj >> 5)) * 8 + (p >> 4)) * 64 +
                                         ((jj & 31) >> 3) * 16 + (p & 15)) * 8 + (jj & 7);
                    vfragg[addr] = f2bf(acc[i][j][r]);
                }
            }
        }
}

// ---------------- k_attn (unchanged from R4): key-split 2x + K/V LDS double-buffer + sp carry ----------------
#define ATTN_FM 8.0f

__global__ __launch_bounds__(256, 2) void k_attn(const unsigned short* __restrict__ qall,
                                                 const unsigned short* __restrict__ kfragg,
                                                 const unsigned short* __restrict__ vfragg,
                                                 const unsigned short* __restrict__ kposfg,
                                                 const int* __restrict__ selidx,
                                                 const float* __restrict__ selval,
                                                 unsigned short* __restrict__ zfrag) {
    // pl+kst+vst live only inside the K-loop; cmb live only after the post-loop barrier.
    __shared__ __align__(16) union {
        struct {
            unsigned short pl[2][4][16][56];      // 14336 B (per-wave P staging, double-buffered)
            unsigned short kst[2][2][8][512];     // 32768 B [buf][ws][q]: 8x1KB K chunks per half
            unsigned short vst[2][2][8][512];     // 32768 B [buf][ws][q]: 8x1KB V chunks per half
        } s;
        float cmb[2][64][37];                     // 18944 B (37: bank-conflict pad)
    } sh;                                         // 79872 B total

    const int t = threadIdx.x;
    const int w = t >> 6, lane = t & 63;
    const int st = blockIdx.x & 63;
    const int hg = (blockIdx.x >> 6) & 3;       // 4 head-pairs
    const int b = blockIdx.x >> 8;
    const int wh = w & 1;                       // head within pair
    const int ws = w >> 1;                      // key-split half (0: keys 0-511, 1: keys 512-1023)
    const int h = hg * 2 + wh;
    const int s0 = st * 16;
    const int lq = lane >> 4;
    const int lm = lane & 15;
    const int loff = lane * 16;

    short8 qf[4];
    {
        const int token = b * 1024 + s0 + lm;
        const int e = selidx[token * 8 + h];
        const unsigned short* qb = qall + (size_t)token * 2048 + e * 128 + lq * 8;
#pragma unroll
        for (int c = 0; c < 4; ++c) qf[c] = *(const short8*)(qb + c * 32);
    }
    short8 onesf;
#pragma unroll
    for (int i = 0; i < 8; ++i) onesf[i] = (short)0x3F80;

    int baddr[4], bsel[4];
#pragma unroll
    for (int r = 0; r < 4; ++r) {
        const int c0 = 15 + lm - (lq * 4 + r);
        baddr[r] = (lq * 16 + (c0 & 15)) * 4;
        bsel[r] = (c0 < 16) ? 1 : 0;
    }

    floatx4 acc[8], accl;
#pragma unroll
    for (int nt = 0; nt < 8; ++nt) acc[nt] = (floatx4){0.f, 0.f, 0.f, 0.f};
    accl = (floatx4){0.f, 0.f, 0.f, 0.f};

    // second-half waves start 16 steps (512 keys / 512 positions) in
    const size_t koff = (size_t)ws * 131072;
    const char* pk = (const char*)kfragg + (size_t)b * 262144 + koff;
    const char* pv = (const char*)vfragg + (size_t)b * 262144 + koff;
    const char* pp = (const char*)kposfg + (size_t)((1008 - s0) >> 4) * 4096 + koff;

    // ---- prologue: stage iter-0 K/V into buf0; load pos frags; fold cry into sp_carry ----
    if (wh == 0) {
#pragma unroll
        for (int q = 0; q < 8; ++q)
            gload16(pk + q * 1024 + loff, &sh.s.kst[0][ws][q][0]);
    } else {
#pragma unroll
        for (int q = 0; q < 8; ++q)
            gload16(pv + q * 1024 + loff, &sh.s.vst[0][ws][q][0]);
    }
    short8 n1c[4], n2c[4];
    floatx4 sp_carry = {0.f, 0.f, 0.f, 0.f};
    {
        short8 cry[4];
#pragma unroll
        for (int c = 0; c < 4; ++c) {
            cry[c] = *(const short8*)(pp + c * 1024 + loff);
            n1c[c] = *(const short8*)(pp + 4096 + c * 1024 + loff);
            n2c[c] = *(const short8*)(pp + 8192 + c * 1024 + loff);
        }
#pragma unroll
        for (int c = 0; c < 4; ++c)
            sp_carry = __builtin_amdgcn_mfma_f32_16x16x32_bf16(qf[c], cry[c], sp_carry, 0, 0, 0);
    }
    __syncthreads();                            // buf0 staged

    unsigned short* pl0 = &sh.s.pl[0][w][0][0];
    unsigned short* pl1 = &sh.s.pl[1][w][0][0];

    for (int it = 0; it < 16; ++it) {
        const int cur = it & 1, nxt = cur ^ 1;
        // issue next-iteration staging FIRST: a full iteration of compute covers the latency
        if (it < 15) {
            if (wh == 0) {
#pragma unroll
                for (int q = 0; q < 8; ++q)
                    gload16(pk + 8192 + q * 1024 + loff, &sh.s.kst[nxt][ws][q][0]);
            } else {
#pragma unroll
                for (int q = 0; q < 8; ++q)
                    gload16(pv + 8192 + q * 1024 + loff, &sh.s.vst[nxt][ws][q][0]);
            }
        }
        // prefetch next-iteration pos fragments into regs
        short8 n1n[4], n2n[4];
        if (it < 15) {
#pragma unroll
            for (int c = 0; c < 4; ++c) {
                n1n[c] = *(const short8*)(pp + 12288 + c * 1024 + loff);
                n2n[c] = *(const short8*)(pp + 16384 + c * 1024 + loff);
            }
        }
        // sp0 carried from previous iteration's sp2 (cry == prev n2)
        const floatx4 sp0 = sp_carry;
        floatx4 sp1 = {0.f, 0.f, 0.f, 0.f}, sp2 = {0.f, 0.f, 0.f, 0.f};
#pragma unroll
        for (int c = 0; c < 4; ++c) {
            sp1 = __builtin_amdgcn_mfma_f32_16x16x32_bf16(qf[c], n1c[c], sp1, 0, 0, 0);
            sp2 = __builtin_amdgcn_mfma_f32_16x16x32_bf16(qf[c], n2c[c], sp2, 0, 0, 0);
        }
        floatx4 sk0 = {0.f, 0.f, 0.f, 0.f}, sk1 = {0.f, 0.f, 0.f, 0.f};
#pragma unroll
        for (int c = 0; c < 4; ++c) {
            const short8 k0 = *(const short8*)&sh.s.kst[cur][ws][c][lane * 8];
            const short8 k1 = *(const short8*)&sh.s.kst[cur][ws][4 + c][lane * 8];
            sk0 = __builtin_amdgcn_mfma_f32_16x16x32_bf16(qf[c], k0, sk0, 0, 0, 0);
            sk1 = __builtin_amdgcn_mfma_f32_16x16x32_bf16(qf[c], k1, sk1, 0, 0, 0);
        }
        unsigned short* pl = cur ? pl1 : pl0;
#pragma unroll
        for (int r = 0; r < 4; ++r) {
            const int a = baddr[r];
            const float b0 = __int_as_float(__builtin_amdgcn_ds_bpermute(a, __float_as_int(sp0[r])));
            const float b1 = __int_as_float(__builtin_amdgcn_ds_bpermute(a, __float_as_int(sp1[r])));
            const float b2 = __int_as_float(__builtin_amdgcn_ds_bpermute(a, __float_as_int(sp2[r])));
            const float v0 = sk0[r] + (bsel[r] ? b0 : b1);
            const float v1 = sk1[r] + (bsel[r] ? b1 : b2);
            pl[(lq * 4 + r) * 56 + lm]      = f2bf(__expf(v0 - ATTN_FM));
            pl[(lq * 4 + r) * 56 + 16 + lm] = f2bf(__expf(v1 - ATTN_FM));
        }
        asm volatile("" ::: "memory");
        const short8 pf = *(const short8*)(pl + lm * 56 + lq * 8);
#pragma unroll
        for (int nt = 0; nt < 8; ++nt) {
            const short8 vf = *(const short8*)&sh.s.vst[cur][ws][nt][lane * 8];
            acc[nt] = __builtin_amdgcn_mfma_f32_16x16x32_bf16(pf, vf, acc[nt], 0, 0, 0);
        }
        accl = __builtin_amdgcn_mfma_f32_16x16x32_bf16(pf, onesf, accl, 0, 0, 0);
        sp_carry = sp2;
#pragma unroll
        for (int c = 0; c < 4; ++c) { n1c[c] = n1n[c]; n2c[c] = n2n[c]; }
        pk += 8192; pv += 8192; pp += 8192;
        __syncthreads();                        // drain prefetch; buf[cur] reads done -> reusable
    }

    // ---- combine the two key-halves through LDS (fixed-max softmax => partials are additive) ----
    if (ws == 1) {
        float* cb = &sh.cmb[wh][lane][0];
#pragma unroll
        for (int nt = 0; nt < 8; ++nt)
#pragma unroll
            for (int r = 0; r < 4; ++r) cb[nt * 4 + r] = acc[nt][r];
#pragma unroll
        for (int r = 0; r < 4; ++r) cb[32 + r] = accl[r];
    }
    __syncthreads();
    if (ws == 1) return;
    {
        const float* cb = &sh.cmb[wh][lane][0];
#pragma unroll
        for (int nt = 0; nt < 8; ++nt)
#pragma unroll
            for (int r = 0; r < 4; ++r) acc[nt][r] += cb[nt * 4 + r];
#pragma unroll
        for (int r = 0; r < 4; ++r) accl[r] += cb[32 + r];
    }

#pragma unroll
    for (int r = 0; r < 4; ++r) {
        const int tok = b * 1024 + s0 + lq * 4 + r;
        const int e = selidx[tok * 8 + h];
        const float g = selval[tok * 8 + h] / accl[r];
        const int mt = tok >> 4, tm = tok & 15;
#pragma unroll
        for (int nt = 0; nt < 8; ++nt) {
            const int k = e * 128 + nt * 16 + lm;
            const int kc = k >> 5;
            const int lane2 = (((k & 31) >> 3) << 4) + tm;
            zfrag[(((size_t)mt * 64 + kc) * 64 + lane2) * 8 + (k & 7)] = f2bf(acc[nt][r] * g);
        }
    }
}

extern "C" void kernel_launch(void* const* d_in, const int* in_sizes, int n_in,
                              void* d_out, int out_size, void* d_ws, size_t ws_size,
                              hipStream_t stream) {
    const float* curr    = (const float*)d_in[0];  // (4,1024,1024)
    const float* attend  = (const float*)d_in[1];  // (4,1024,1024)
    const float* w_q     = (const float*)d_in[2];  // (16,1024,128)
    const float* w_kv    = (const float*)d_in[3];  // (1024,256)
    const float* w_out   = (const float*)d_in[4];  // (16,128,1024)
    const float* pos_pk  = (const float*)d_in[5];  // (128,1024)
    const float* sel_dst = (const float*)d_in[6];  // (16,1024)
    const float* scale   = (const float*)d_in[7];  // (1,)
    float* out = (float*)d_out;

    char* ws = (char*)d_ws;
    float* selval = (float*)ws;                                        // 128 KB
    int*   selidx = (int*)(ws + 131072);                               // 128 KB
    unsigned short* kposfg  = (unsigned short*)(ws + 262144);          // 512 KB
    unsigned short* kfragg  = (unsigned short*)(ws + 786432);          // 1 MB
    unsigned short* vfragg  = (unsigned short*)(ws + 1835008);         // 1 MB
    unsigned short* bfragq  = (unsigned short*)(ws + 2883584);         // 4 MB
    unsigned short* bfragw  = (unsigned short*)(ws + 7077888);         // 4 MB
    unsigned short* bfragkv = (unsigned short*)(ws + 11272192);        // 512 KB
    unsigned short* afrag   = (unsigned short*)(ws + 11796480);        // 8 MB (curr A-frag)
    unsigned short* qall    = (unsigned short*)(ws + 20185088);        // 16 MB
    unsigned short* zfrag   = (unsigned short*)(ws + 36962304);        // 16 MB
    // Aliases inside zfrag (all fully consumed before zfrag's memset):
    //   pefrag  = zfrag[0 .. 4MB)       (pe A-frag, consumed by k_gemm_kpos)
    //   bfragp  = zfrag[4MB .. 4.25MB)  (pos_pk B-frag, consumed by k_gemm_kpos)
    //   attfrag = zfrag[8MB .. 16MB)    (attend A-frag, consumed by k_gemm_kv)
    unsigned short* pefrag  = zfrag;                                   // 4 MB
    unsigned short* bfragp  = zfrag + 2097152;                         // 256 KB
    unsigned short* attfrag = zfrag + 4194304;                         // 8 MB
    // total ~51.3 MB

    k_prep<<<4760, 256, 0, stream>>>(curr, attend, w_q, w_out, w_kv, pos_pk, sel_dst,
                                     selval, selidx, afrag, attfrag,
                                     bfragq, bfragw, bfragkv, bfragp, pefrag);
    k_gemm_kpos<<<dim3(16, 2), 256, 0, stream>>>(pefrag, bfragp, scale, kposfg);
    k_gemm_qall<<<dim3(32, 32), 256, 0, stream>>>(afrag, bfragq, scale, qall);
    k_gemm_kv<<<dim3(32, 4), 256, 0, stream>>>(attfrag, bfragkv, scale, kfragg, vfragg);
    hipMemsetAsync(zfrag, 0, (size_t)16777216, stream);
    k_attn<<<1024, 256, 0, stream>>>(qall, kfragg, vfragg, kposfg, selidx, selval, zfrag);
    k_gemm_out<<<dim3(32, 16), 256, 0, stream>>>(zfrag, bfragw, out);
}

// Round 8
// 284.865 us; speedup vs baseline: 1.0979x; 1.0979x over previous
//
#include <hip/hip_runtime.h>
#include <math.h>

// B=4 S=1024 D=1024 P=128 H=8 E=16, NT=4096, TPOS=2047

typedef __attribute__((ext_vector_type(8))) short short8;
typedef __attribute__((ext_vector_type(4))) float floatx4;

__device__ __forceinline__ float bf2f(unsigned int u) {
    union { unsigned int i; float f; } x; x.i = (u & 0xffffu) << 16; return x.f;
}
__device__ __forceinline__ unsigned short f2bf(float f) {
    union { float f; unsigned int i; } x; x.f = f;
    unsigned int r = x.i + 0x7fffu + ((x.i >> 16) & 1u);
    return (unsigned short)(r >> 16);
}

// async global->LDS: per-lane global addr, wave-uniform LDS base; lane data at base + lane*16
__device__ __forceinline__ void gload16(const void* g, void* l) {
    __builtin_amdgcn_global_load_lds(
        (const __attribute__((address_space(1))) unsigned int*)(uintptr_t)g,
        (__attribute__((address_space(3))) unsigned int*)(uintptr_t)l,
        16, 0, 0);
}

// Fragment layouts (16x16x32 bf16 MFMA), HW-verified R2-R6:
//   A-frag (MxK):  afrag[m>>4][k>>5][((k&31)>>3)*16 + (m&15)][k&7]
//   B-frag (KxN):  bfrag[n>>4][k>>5][((k&31)>>3)*16 + (n&15)][k&7]
//   C/D:           col = lane&15, row = (lane>>4)*4 + reg

// ---------------- k_prep (R6 version, reverted): fused conv_w + pe + sel + conv_act ----------------
// blocks [0,4480): weights -> B-frags; [4480,6528): pos-emb -> pe A-frag;
// [6528,10624): selection+top8 + curr -> A-frag; [10624,14720): attend -> attfrag A-frag.
__global__ __launch_bounds__(256) void k_prep(const float* __restrict__ curr,
                                              const float* __restrict__ attend,
                                              const float* __restrict__ w_q,
                                              const float* __restrict__ w_out,
                                              const float* __restrict__ w_kv,
                                              const float* __restrict__ pos_pk,
                                              const float* __restrict__ sel_dst,
                                              float* __restrict__ selval,
                                              int* __restrict__ selidx,
                                              unsigned short* __restrict__ afrag,
                                              unsigned short* __restrict__ attfrag,
                                              unsigned short* __restrict__ bfragq,
                                              unsigned short* __restrict__ bfragw,
                                              unsigned short* __restrict__ bfragkv,
                                              unsigned short* __restrict__ bfragp,
                                              unsigned short* __restrict__ pefrag) {
    __shared__ float row[1024];
    __shared__ float sel[16];
    const int bx = blockIdx.x;
    const int t = threadIdx.x;

    if (bx < 4480) {
        // ---- conv_w ----
        float v[4];
        if (bx < 2048) {
            const unsigned u = bx * 256 + t;
            const int p = u & 127, e = (u >> 7) & 15, kk = u >> 11;
#pragma unroll
            for (int d = 0; d < 4; ++d) v[d] = w_q[(size_t)e * 131072 + (size_t)(4 * kk + d) * 128 + p];
            const int n = e * 128 + p;
            const int nt = n >> 4, kc = kk >> 3;
            const int lane = ((kk & 7) >> 1) * 16 + (n & 15);
            const size_t off = (((size_t)nt * 32 + kc) * 64 + lane) * 8 + 4 * (kk & 1);
            uint2 o;
            o.x = (unsigned)f2bf(v[0]) | ((unsigned)f2bf(v[1]) << 16);
            o.y = (unsigned)f2bf(v[2]) | ((unsigned)f2bf(v[3]) << 16);
            *(uint2*)(bfragq + off) = o;
        } else if (bx < 4096) {
            const unsigned u = (bx - 2048) * 256 + t;
            const int n = ((bx & 3) * 256 + t) & 1023;
            const int kk = u >> 10;
#pragma unroll
            for (int d = 0; d < 4; ++d) v[d] = w_out[(size_t)(4 * kk + d) * 1024 + n];
            const int nt = n >> 4, kc = kk >> 3;
            const int lane = ((kk & 7) >> 1) * 16 + (n & 15);
            const size_t off = (((size_t)nt * 64 + kc) * 64 + lane) * 8 + 4 * (kk & 1);
            uint2 o;
            o.x = (unsigned)f2bf(v[0]) | ((unsigned)f2bf(v[1]) << 16);
            o.y = (unsigned)f2bf(v[2]) | ((unsigned)f2bf(v[3]) << 16);
            *(uint2*)(bfragw + off) = o;
        } else if (bx < 4352) {
            const int n = t;
            const int kk = bx - 4096;
#pragma unroll
            for (int d = 0; d < 4; ++d) v[d] = w_kv[(size_t)(4 * kk + d) * 256 + n];
            const int nt = n >> 4, kc = kk >> 3;
            const int lane = ((kk & 7) >> 1) * 16 + (n & 15);
            const size_t off = (((size_t)nt * 32 + kc) * 64 + lane) * 8 + 4 * (kk & 1);
            uint2 o;
            o.x = (unsigned)f2bf(v[0]) | ((unsigned)f2bf(v[1]) << 16);
            o.y = (unsigned)f2bf(v[2]) | ((unsigned)f2bf(v[3]) << 16);
            *(uint2*)(bfragkv + off) = o;
        } else {
            const int n = bx - 4352;
#pragma unroll
            for (int d = 0; d < 4; ++d) v[d] = pos_pk[(size_t)n * 1024 + 4 * t + d];
            const int nt = n >> 4, kc = t >> 3;
            const int lane = ((t & 7) >> 1) * 16 + (n & 15);
            const size_t off = (((size_t)nt * 32 + kc) * 64 + lane) * 8 + 4 * (t & 1);
            uint2 o;
            o.x = (unsigned)f2bf(v[0]) | ((unsigned)f2bf(v[1]) << 16);
            o.y = (unsigned)f2bf(v[2]) | ((unsigned)f2bf(v[3]) << 16);
            *(uint2*)(bfragp + off) = o;
        }
    } else if (bx < 6528) {
        // ---- pe: sinusoidal pos embedding -> A-frag (2048 rows, row 2047 = 0) ----
        const int m = bx - 4480;
        uint2 o;
        if (m >= 2047) {
            o.x = 0u; o.y = 0u;
        } else {
            const float c1 = -logf(10000.f) / 1024.f;
            const float pos = (float)(m - 1023);
            const float a0 = pos * expf((float)(4 * t) * c1);
            const float a1 = pos * expf((float)(4 * t + 2) * c1);
            o.x = (unsigned)f2bf(sinf(a0)) | ((unsigned)f2bf(cosf(a0)) << 16);
            o.y = (unsigned)f2bf(sinf(a1)) | ((unsigned)f2bf(cosf(a1)) << 16);
        }
        const int mt = m >> 4, kc = t >> 3;
        const int lane = ((t & 7) >> 1) * 16 + (m & 15);
        const size_t off = (((size_t)mt * 32 + kc) * 64 + lane) * 8 + 4 * (t & 1);
        *(uint2*)(pefrag + off) = o;
    } else if (bx < 10624) {
        // ---- sel: selection + top-8 + sigmoid + curr->A-frag ----
        const int token = bx - 6528;
        const float4 v = ((const float4*)(curr + (size_t)token * 1024))[t];
        ((float4*)row)[t] = v;
        {
            const int mt = token >> 4, kc = t >> 3;
            const int lane = ((t & 7) >> 1) * 16 + (token & 15);
            const size_t off = (((size_t)mt * 32 + kc) * 64 + lane) * 8 + 4 * (t & 1);
            uint2 o;
            o.x = (unsigned)f2bf(v.x) | ((unsigned)f2bf(v.y) << 16);
            o.y = (unsigned)f2bf(v.z) | ((unsigned)f2bf(v.w) << 16);
            *(uint2*)(afrag + off) = o;
        }
        __syncthreads();
        const int wv = t >> 6, lane = t & 63;
        for (int e0 = 0; e0 < 4; ++e0) {
            const int e = wv * 4 + e0;
            const float* w = sel_dst + e * 1024;
            float p = 0.f;
            for (int i = lane; i < 1024; i += 64) p += row[i] * w[i];
            for (int off = 32; off; off >>= 1) p += __shfl_down(p, off, 64);
            if (lane == 0) sel[e] = p;
        }
        __syncthreads();
        if (t == 0) {
            float v16[16];
#pragma unroll
            for (int e = 0; e < 16; ++e) v16[e] = sel[e];
#pragma unroll
            for (int r = 0; r < 8; ++r) {
                int bi = 0; float bv = v16[0];
#pragma unroll
                for (int e = 1; e < 16; ++e) { if (v16[e] > bv) { bv = v16[e]; bi = e; } }
                selidx[token * 8 + r] = bi;
                selval[token * 8 + r] = 1.f / (1.f + __expf(-bv));
                v16[bi] = -INFINITY;
            }
        }
    } else {
        // ---- conv_act: attend f32 row-major -> attfrag A-frag bf16 ----
        const int m = bx - 10624;
        const float4 v = *(const float4*)(attend + (size_t)m * 1024 + 4 * t);
        const int mt = m >> 4, kc = t >> 3;
        const int lane = ((t & 7) >> 1) * 16 + (m & 15);
        const size_t off = (((size_t)mt * 32 + kc) * 64 + lane) * 8 + 4 * (t & 1);
        uint2 o;
        o.x = (unsigned)f2bf(v.x) | ((unsigned)f2bf(v.y) << 16);
        o.y = (unsigned)f2bf(v.z) | ((unsigned)f2bf(v.w) << 16);
        *(uint2*)(attfrag + off) = o;
    }
}

// ---------------- MFMA GEMM core: 128x64 tile, 4 waves, frag-ordered global in ----------------
__device__ __forceinline__ void gemm_core64(const unsigned short* __restrict__ Afrag,
                                            const unsigned short* __restrict__ Bfrag,
                                            int mt0, int nt0, int KC,
                                            unsigned short (*aT)[512],
                                            unsigned short (*bT)[512],
                                            floatx4 acc[4][2]) {
    const int t = threadIdx.x;
    const int w = t >> 6, lane = t & 63;
    const int wm = w >> 1, wn = w & 1;
    for (int kc = 0; kc < KC; ++kc) {
        __syncthreads();
        {
            const int fi = w * 3;
#pragma unroll
            for (int l = 0; l < 3; ++l) {
                const int f = fi + l;   // 0..11: 8 A-frags then 4 B-frags
                if (f < 8)
                    gload16(Afrag + (((size_t)(mt0 + f) * KC + kc) * 64 + lane) * 8, &aT[f][0]);
                else
                    gload16(Bfrag + (((size_t)(nt0 + f - 8) * KC + kc) * 64 + lane) * 8, &bT[f - 8][0]);
            }
        }
        __syncthreads();
        short8 af[4], bf[2];
#pragma unroll
        for (int i = 0; i < 4; ++i) af[i] = *(const short8*)&aT[wm * 4 + i][lane * 8];
#pragma unroll
        for (int j = 0; j < 2; ++j) bf[j] = *(const short8*)&bT[wn * 2 + j][lane * 8];
#pragma unroll
        for (int i = 0; i < 4; ++i)
#pragma unroll
            for (int j = 0; j < 2; ++j)
                acc[i][j] = __builtin_amdgcn_mfma_f32_16x16x32_bf16(af[i], bf[j], acc[i][j], 0, 0, 0);
    }
}

// ---------------- k_gemm3: fused qall + kv + kpos (all independent, one launch) ----------------
// blocks [0,1024): qall (32x32); [1024,1152): kv (32x4); [1152,1184): kpos (16x2).
__global__ __launch_bounds__(256) void k_gemm3(const unsigned short* __restrict__ afrag,
                                               const unsigned short* __restrict__ bfragq,
                                               const unsigned short* __restrict__ attfrag,
                                               const unsigned short* __restrict__ bfragkv,
                                               const unsigned short* __restrict__ pefrag,
                                               const unsigned short* __restrict__ bfragp,
                                               const float* __restrict__ scale,
                                               unsigned short* __restrict__ qall,
                                               unsigned short* __restrict__ kfragg,
                                               unsigned short* __restrict__ vfragg,
                                               unsigned short* __restrict__ kposfg) {
    __shared__ __align__(16) unsigned short aT[8][512], bT[4][512];
    floatx4 acc[4][2];
#pragma unroll
    for (int i = 0; i < 4; ++i) { acc[i][0] = (floatx4){0,0,0,0}; acc[i][1] = (floatx4){0,0,0,0}; }
    const int bx = blockIdx.x;
    const int t = threadIdx.x, w = t >> 6, lane = t & 63;
    const int wm = w >> 1, wn = w & 1, lq = lane >> 4, lm = lane & 15;
    const float sc = sqrtf(scale[0]);

    if (bx < 1024) {
        const int gx = bx & 31, gy = bx >> 5;
        gemm_core64(afrag, bfragq, gx * 8, gy * 4, 32, aT, bT, acc);
#pragma unroll
        for (int i = 0; i < 4; ++i)
#pragma unroll
            for (int j = 0; j < 2; ++j)
#pragma unroll
                for (int r = 0; r < 4; ++r)
                    qall[(size_t)(gx * 128 + (wm * 4 + i) * 16 + lq * 4 + r) * 2048 +
                         gy * 64 + (wn * 2 + j) * 16 + lm] = f2bf(acc[i][j][r] * sc);
    } else if (bx < 1152) {
        const int q = bx - 1024;
        const int gx = q & 31, gy = q >> 5;
        gemm_core64(attfrag, bfragkv, gx * 8, gy * 4, 32, aT, bT, acc);
#pragma unroll
        for (int i = 0; i < 4; ++i)
#pragma unroll
            for (int j = 0; j < 2; ++j) {
                const int n = gy * 64 + (wn * 2 + j) * 16 + lm;
#pragma unroll
                for (int r = 0; r < 4; ++r) {
                    const int tok = gx * 128 + (wm * 4 + i) * 16 + lq * 4 + r;
                    const int bb = tok >> 10, jj = tok & 1023;
                    if (n < 128) {
                        const int p = n;
                        const size_t addr = ((((size_t)bb * 64 + (jj >> 4)) * 4 + (p >> 5)) * 64 +
                                             ((p & 31) >> 3) * 16 + (jj & 15)) * 8 + (p & 7);
                        kfragg[addr] = f2bf(acc[i][j][r] * sc);
                    } else {
                        const int p = n - 128;
                        const size_t addr = ((((size_t)bb * 32 + (jj >> 5)) * 8 + (p >> 4)) * 64 +
                                             ((jj & 31) >> 3) * 16 + (p & 15)) * 8 + (jj & 7);
                        vfragg[addr] = f2bf(acc[i][j][r]);
                    }
                }
            }
    } else {
        const int q = bx - 1152;
        const int gx = q & 15, gy = q >> 4;
        gemm_core64(pefrag, bfragp, gx * 8, gy * 4, 32, aT, bT, acc);
#pragma unroll
        for (int i = 0; i < 4; ++i)
#pragma unroll
            for (int j = 0; j < 2; ++j) {
                const int p = gy * 64 + (wn * 2 + j) * 16 + lm;
#pragma unroll
                for (int r = 0; r < 4; ++r) {
                    const int tp = gx * 128 + (wm * 4 + i) * 16 + lq * 4 + r;
                    const size_t addr = (((size_t)(tp >> 4) * 4 + (p >> 5)) * 64 +
                                         ((p & 31) >> 3) * 16 + (tp & 15)) * 8 + (p & 7);
                    kposfg[addr] = f2bf(acc[i][j][r] * sc);
                }
            }
    }
}

// ---------------- GEMM: out = zfrag @ w_out -> f32 row-major 4096x1024 ----------------
__global__ __launch_bounds__(256) void k_gemm_out(const unsigned short* __restrict__ Afrag,
                                                  const unsigned short* __restrict__ Bfrag,
                                                  float* __restrict__ out) {
    __shared__ __align__(16) unsigned short aT[8][512], bT[4][512];
    floatx4 acc[4][2];
#pragma unroll
    for (int i = 0; i < 4; ++i) { acc[i][0] = (floatx4){0,0,0,0}; acc[i][1] = (floatx4){0,0,0,0}; }
    gemm_core64(Afrag, Bfrag, blockIdx.x * 8, blockIdx.y * 4, 64, aT, bT, acc);
    const int t = threadIdx.x, w = t >> 6, lane = t & 63;
    const int wm = w >> 1, wn = w & 1, lq = lane >> 4, lm = lane & 15;
#pragma unroll
    for (int i = 0; i < 4; ++i)
#pragma unroll
        for (int j = 0; j < 2; ++j)
#pragma unroll
            for (int r = 0; r < 4; ++r)
                out[(size_t)(blockIdx.x * 128 + (wm * 4 + i) * 16 + lq * 4 + r) * 1024 +
                    blockIdx.y * 64 + (wn * 2 + j) * 16 + lm] = acc[i][j][r];
}

// ---------------- k_attn (unchanged from R4): key-split 2x + K/V LDS double-buffer + sp carry ----------------
#define ATTN_FM 8.0f

__global__ __launch_bounds__(256, 2) void k_attn(const unsigned short* __restrict__ qall,
                                                 const unsigned short* __restrict__ kfragg,
                                                 const unsigned short* __restrict__ vfragg,
                                                 const unsigned short* __restrict__ kposfg,
                                                 const int* __restrict__ selidx,
                                                 const float* __restrict__ selval,
                                                 unsigned short* __restrict__ zfrag) {
    // pl+kst+vst live only inside the K-loop; cmb live only after the post-loop barrier.
    __shared__ __align__(16) union {
        struct {
            unsigned short pl[2][4][16][56];      // 14336 B (per-wave P staging, double-buffered)
            unsigned short kst[2][2][8][512];     // 32768 B [buf][ws][q]: 8x1KB K chunks per half
            unsigned short vst[2][2][8][512];     // 32768 B [buf][ws][q]: 8x1KB V chunks per half
        } s;
        float cmb[2][64][37];                     // 18944 B (37: bank-conflict pad)
    } sh;                                         // 79872 B total

    const int t = threadIdx.x;
    const int w = t >> 6, lane = t & 63;
    const int st = blockIdx.x & 63;
    const int hg = (blockIdx.x >> 6) & 3;       // 4 head-pairs
    const int b = blockIdx.x >> 8;
    const int wh = w & 1;                       // head within pair
    const int ws = w >> 1;                      // key-split half (0: keys 0-511, 1: keys 512-1023)
    const int h = hg * 2 + wh;
    const int s0 = st * 16;
    const int lq = lane >> 4;
    const int lm = lane & 15;
    const int loff = lane * 16;

    short8 qf[4];
    {
        const int token = b * 1024 + s0 + lm;
        const int e = selidx[token * 8 + h];
        const unsigned short* qb = qall + (size_t)token * 2048 + e * 128 + lq * 8;
#pragma unroll
        for (int c = 0; c < 4; ++c) qf[c] = *(const short8*)(qb + c * 32);
    }
    short8 onesf;
#pragma unroll
    for (int i = 0; i < 8; ++i) onesf[i] = (short)0x3F80;

    int baddr[4], bsel[4];
#pragma unroll
    for (int r = 0; r < 4; ++r) {
        const int c0 = 15 + lm - (lq * 4 + r);
        baddr[r] = (lq * 16 + (c0 & 15)) * 4;
        bsel[r] = (c0 < 16) ? 1 : 0;
    }

    floatx4 acc[8], accl;
#pragma unroll
    for (int nt = 0; nt < 8; ++nt) acc[nt] = (floatx4){0.f, 0.f, 0.f, 0.f};
    accl = (floatx4){0.f, 0.f, 0.f, 0.f};

    // second-half waves start 16 steps (512 keys / 512 positions) in
    const size_t koff = (size_t)ws * 131072;
    const char* pk = (const char*)kfragg + (size_t)b * 262144 + koff;
    const char* pv = (const char*)vfragg + (size_t)b * 262144 + koff;
    const char* pp = (const char*)kposfg + (size_t)((1008 - s0) >> 4) * 4096 + koff;

    // ---- prologue: stage iter-0 K/V into buf0; load pos frags; fold cry into sp_carry ----
    if (wh == 0) {
#pragma unroll
        for (int q = 0; q < 8; ++q)
            gload16(pk + q * 1024 + loff, &sh.s.kst[0][ws][q][0]);
    } else {
#pragma unroll
        for (int q = 0; q < 8; ++q)
            gload16(pv + q * 1024 + loff, &sh.s.vst[0][ws][q][0]);
    }
    short8 n1c[4], n2c[4];
    floatx4 sp_carry = {0.f, 0.f, 0.f, 0.f};
    {
        short8 cry[4];
#pragma unroll
        for (int c = 0; c < 4; ++c) {
            cry[c] = *(const short8*)(pp + c * 1024 + loff);
            n1c[c] = *(const short8*)(pp + 4096 + c * 1024 + loff);
            n2c[c] = *(const short8*)(pp + 8192 + c * 1024 + loff);
        }
#pragma unroll
        for (int c = 0; c < 4; ++c)
            sp_carry = __builtin_amdgcn_mfma_f32_16x16x32_bf16(qf[c], cry[c], sp_carry, 0, 0, 0);
    }
    __syncthreads();                            // buf0 staged

    unsigned short* pl0 = &sh.s.pl[0][w][0][0];
    unsigned short* pl1 = &sh.s.pl[1][w][0][0];

    for (int it = 0; it < 16; ++it) {
        const int cur = it & 1, nxt = cur ^ 1;
        // issue next-iteration staging FIRST: a full iteration of compute covers the latency
        if (it < 15) {
            if (wh == 0) {
#pragma unroll
                for (int q = 0; q < 8; ++q)
                    gload16(pk + 8192 + q * 1024 + loff, &sh.s.kst[nxt][ws][q][0]);
            } else {
#pragma unroll
                for (int q = 0; q < 8; ++q)
                    gload16(pv + 8192 + q * 1024 + loff, &sh.s.vst[nxt][ws][q][0]);
            }
        }
        // prefetch next-iteration pos fragments into regs
        short8 n1n[4], n2n[4];
        if (it < 15) {
#pragma unroll
            for (int c = 0; c < 4; ++c) {
                n1n[c] = *(const short8*)(pp + 12288 + c * 1024 + loff);
                n2n[c] = *(const short8*)(pp + 16384 + c * 1024 + loff);
            }
        }
        // sp0 carried from previous iteration's sp2 (cry == prev n2)
        const floatx4 sp0 = sp_carry;
        floatx4 sp1 = {0.f, 0.f, 0.f, 0.f}, sp2 = {0.f, 0.f, 0.f, 0.f};
#pragma unroll
        for (int c = 0; c < 4; ++c) {
            sp1 = __builtin_amdgcn_mfma_f32_16x16x32_bf16(qf[c], n1c[c], sp1, 0, 0, 0);
            sp2 = __builtin_amdgcn_mfma_f32_16x16x32_bf16(qf[c], n2c[c], sp2, 0, 0, 0);
        }
        floatx4 sk0 = {0.f, 0.f, 0.f, 0.f}, sk1 = {0.f, 0.f, 0.f, 0.f};
#pragma unroll
        for (int c = 0; c < 4; ++c) {
            const short8 k0 = *(const short8*)&sh.s.kst[cur][ws][c][lane * 8];
            const short8 k1 = *(const short8*)&sh.s.kst[cur][ws][4 + c][lane * 8];
            sk0 = __builtin_amdgcn_mfma_f32_16x16x32_bf16(qf[c], k0, sk0, 0, 0, 0);
            sk1 = __builtin_amdgcn_mfma_f32_16x16x32_bf16(qf[c], k1, sk1, 0, 0, 0);
        }
        unsigned short* pl = cur ? pl1 : pl0;
#pragma unroll
        for (int r = 0; r < 4; ++r) {
            const int a = baddr[r];
            const float b0 = __int_as_float(__builtin_amdgcn_ds_bpermute(a, __float_as_int(sp0[r])));
            const float b1 = __int_as_float(__builtin_amdgcn_ds_bpermute(a, __float_as_int(sp1[r])));
            const float b2 = __int_as_float(__builtin_amdgcn_ds_bpermute(a, __float_as_int(sp2[r])));
            const float v0 = sk0[r] + (bsel[r] ? b0 : b1);
            const float v1 = sk1[r] + (bsel[r] ? b1 : b2);
            pl[(lq * 4 + r) * 56 + lm]      = f2bf(__expf(v0 - ATTN_FM));
            pl[(lq * 4 + r) * 56 + 16 + lm] = f2bf(__expf(v1 - ATTN_FM));
        }
        asm volatile("" ::: "memory");
        const short8 pf = *(const short8*)(pl + lm * 56 + lq * 8);
#pragma unroll
        for (int nt = 0; nt < 8; ++nt) {
            const short8 vf = *(const short8*)&sh.s.vst[cur][ws][nt][lane * 8];
            acc[nt] = __builtin_amdgcn_mfma_f32_16x16x32_bf16(pf, vf, acc[nt], 0, 0, 0);
        }
        accl = __builtin_amdgcn_mfma_f32_16x16x32_bf16(pf, onesf, accl, 0, 0, 0);
        sp_carry = sp2;
#pragma unroll
        for (int c = 0; c < 4; ++c) { n1c[c] = n1n[c]; n2c[c] = n2n[c]; }
        pk += 8192; pv += 8192; pp += 8192;
        __syncthreads();                        // drain prefetch; buf[cur] reads done -> reusable
    }

    // ---- combine the two key-halves through LDS (fixed-max softmax => partials are additive) ----
    if (ws == 1) {
        float* cb = &sh.cmb[wh][lane][0];
#pragma unroll
        for (int nt = 0; nt < 8; ++nt)
#pragma unroll
            for (int r = 0; r < 4; ++r) cb[nt * 4 + r] = acc[nt][r];
#pragma unroll
        for (int r = 0; r < 4; ++r) cb[32 + r] = accl[r];
    }
    __syncthreads();
    if (ws == 1) return;
    {
        const float* cb = &sh.cmb[wh][lane][0];
#pragma unroll
        for (int nt = 0; nt < 8; ++nt)
#pragma unroll
            for (int r = 0; r < 4; ++r) acc[nt][r] += cb[nt * 4 + r];
#pragma unroll
        for (int r = 0; r < 4; ++r) accl[r] += cb[32 + r];
    }

#pragma unroll
    for (int r = 0; r < 4; ++r) {
        const int tok = b * 1024 + s0 + lq * 4 + r;
        const int e = selidx[tok * 8 + h];
        const float g = selval[tok * 8 + h] / accl[r];
        const int mt = tok >> 4, tm = tok & 15;
#pragma unroll
        for (int nt = 0; nt < 8; ++nt) {
            const int k = e * 128 + nt * 16 + lm;
            const int kc = k >> 5;
            const int lane2 = (((k & 31) >> 3) << 4) + tm;
            zfrag[(((size_t)mt * 64 + kc) * 64 + lane2) * 8 + (k & 7)] = f2bf(acc[nt][r] * g);
        }
    }
}

extern "C" void kernel_launch(void* const* d_in, const int* in_sizes, int n_in,
                              void* d_out, int out_size, void* d_ws, size_t ws_size,
                              hipStream_t stream) {
    const float* curr    = (const float*)d_in[0];  // (4,1024,1024)
    const float* attend  = (const float*)d_in[1];  // (4,1024,1024)
    const float* w_q     = (const float*)d_in[2];  // (16,1024,128)
    const float* w_kv    = (const float*)d_in[3];  // (1024,256)
    const float* w_out   = (const float*)d_in[4];  // (16,128,1024)
    const float* pos_pk  = (const float*)d_in[5];  // (128,1024)
    const float* sel_dst = (const float*)d_in[6];  // (16,1024)
    const float* scale   = (const float*)d_in[7];  // (1,)
    float* out = (float*)d_out;

    char* ws = (char*)d_ws;
    float* selval = (float*)ws;                                        // 128 KB
    int*   selidx = (int*)(ws + 131072);                               // 128 KB
    unsigned short* kposfg  = (unsigned short*)(ws + 262144);          // 512 KB
    unsigned short* kfragg  = (unsigned short*)(ws + 786432);          // 1 MB
    unsigned short* vfragg  = (unsigned short*)(ws + 1835008);         // 1 MB
    unsigned short* bfragq  = (unsigned short*)(ws + 2883584);         // 4 MB
    unsigned short* bfragw  = (unsigned short*)(ws + 7077888);         // 4 MB
    unsigned short* bfragkv = (unsigned short*)(ws + 11272192);        // 512 KB
    unsigned short* afrag   = (unsigned short*)(ws + 11796480);        // 8 MB (curr A-frag)
    unsigned short* qall    = (unsigned short*)(ws + 20185088);        // 16 MB
    unsigned short* zfrag   = (unsigned short*)(ws + 36962304);        // 16 MB
    // Aliases inside zfrag (all fully consumed by k_gemm3 BEFORE zfrag's memset):
    //   pefrag  = zfrag[0 .. 4MB)       (pe A-frag)
    //   bfragp  = zfrag[4MB .. 4.25MB)  (pos_pk B-frag)
    //   attfrag = zfrag[8MB .. 16MB)    (attend A-frag)
    unsigned short* pefrag  = zfrag;                                   // 4 MB
    unsigned short* bfragp  = zfrag + 2097152;                         // 256 KB
    unsigned short* attfrag = zfrag + 4194304;                         // 8 MB
    // total ~51.3 MB

    k_prep<<<14720, 256, 0, stream>>>(curr, attend, w_q, w_out, w_kv, pos_pk, sel_dst,
                                      selval, selidx, afrag, attfrag,
                                      bfragq, bfragw, bfragkv, bfragp, pefrag);
    k_gemm3<<<1184, 256, 0, stream>>>(afrag, bfragq, attfrag, bfragkv, pefrag, bfragp,
                                      scale, qall, kfragg, vfragg, kposfg);
    hipMemsetAsync(zfrag, 0, (size_t)16777216, stream);
    k_attn<<<1024, 256, 0, stream>>>(qall, kfragg, vfragg, kposfg, selidx, selval, zfrag);
    k_gemm_out<<<dim3(32, 16), 256, 0, stream>>>(zfrag, bfragw, out);
}

// Round 9
// 270.253 us; speedup vs baseline: 1.1573x; 1.0541x over previous
//
#include <hip/hip_runtime.h>
#include <math.h>

// B=4 S=1024 D=1024 P=128 H=8 E=16, NT=4096, TPOS=2047

typedef __attribute__((ext_vector_type(8))) short short8;
typedef __attribute__((ext_vector_type(4))) float floatx4;

__device__ __forceinline__ float bf2f(unsigned int u) {
    union { unsigned int i; float f; } x; x.i = (u & 0xffffu) << 16; return x.f;
}
__device__ __forceinline__ unsigned short f2bf(float f) {
    union { float f; unsigned int i; } x; x.f = f;
    unsigned int r = x.i + 0x7fffu + ((x.i >> 16) & 1u);
    return (unsigned short)(r >> 16);
}

// async global->LDS: per-lane global addr, wave-uniform LDS base; lane data at base + lane*16
__device__ __forceinline__ void gload16(const void* g, void* l) {
    __builtin_amdgcn_global_load_lds(
        (const __attribute__((address_space(1))) unsigned int*)(uintptr_t)g,
        (__attribute__((address_space(3))) unsigned int*)(uintptr_t)l,
        16, 0, 0);
}

// Fragment layouts (16x16x32 bf16 MFMA), HW-verified R2-R6:
//   A-frag (MxK):  afrag[m>>4][k>>5][((k&31)>>3)*16 + (m&15)][k&7]
//   B-frag (KxN):  bfrag[n>>4][k>>5][((k&31)>>3)*16 + (n&15)][k&7]
//   C/D:           col = lane&15, row = (lane>>4)*4 + reg
// R9 dense-write converters: u-bits [0]=half(j>>2), [1:4]=n/m low, [5:6]=k-octet, [7:..]=kc, nt/mt.
// Consecutive u -> consecutive 8B writes (wave = 512B dense); reads stay full-line segments.

// ---------------- k_prep R9: dense-write converters + sel (no afrag write) ----------------
// [0,2048): w_q; [2048,4096): w_out; [4096,4352): w_kv; [4352,4480): pos_pk (orig);
// [4480,6528): pe; [6528,10624): sel; [10624,14720): curr->afrag; [14720,18816): attend->attfrag.
__global__ __launch_bounds__(256) void k_prep(const float* __restrict__ curr,
                                              const float* __restrict__ attend,
                                              const float* __restrict__ w_q,
                                              const float* __restrict__ w_out,
                                              const float* __restrict__ w_kv,
                                              const float* __restrict__ pos_pk,
                                              const float* __restrict__ sel_dst,
                                              float* __restrict__ selval,
                                              int* __restrict__ selidx,
                                              unsigned short* __restrict__ afrag,
                                              unsigned short* __restrict__ attfrag,
                                              unsigned short* __restrict__ bfragq,
                                              unsigned short* __restrict__ bfragw,
                                              unsigned short* __restrict__ bfragkv,
                                              unsigned short* __restrict__ bfragp,
                                              unsigned short* __restrict__ pefrag) {
    __shared__ float row[1024];
    __shared__ float sel[16];
    const int bx = blockIdx.x;
    const int t = threadIdx.x;

    if (bx < 2048) {
        // ---- w_q -> bfragq (B-frag KC=32, N=2048): dense writes ----
        const unsigned u = (unsigned)bx * 256 + t;
        const int half = u & 1;
        const int nlow = (u >> 1) & 15;
        const int koct = (u >> 5) & 3;
        const int kc   = (u >> 7) & 31;
        const int nt   = (u >> 12) & 127;
        const int n = nt * 16 + nlow;
        const int e = n >> 7, p = n & 127;
        const int k0 = kc * 32 + koct * 8 + half * 4;
        const float* src = w_q + (size_t)e * 131072 + (size_t)k0 * 128 + p;
        uint2 o;
        o.x = (unsigned)f2bf(src[0])   | ((unsigned)f2bf(src[128]) << 16);
        o.y = (unsigned)f2bf(src[256]) | ((unsigned)f2bf(src[384]) << 16);
        const size_t chunk = ((size_t)nt * 32 + kc) * 64 + koct * 16 + nlow;
        *(uint2*)(bfragq + chunk * 8 + half * 4) = o;
    } else if (bx < 4096) {
        // ---- w_out -> bfragw (B-frag KC=64, N=1024): dense writes ----
        const unsigned u = (unsigned)(bx - 2048) * 256 + t;
        const int half = u & 1;
        const int nlow = (u >> 1) & 15;
        const int koct = (u >> 5) & 3;
        const int kc   = (u >> 7) & 63;
        const int nt   = (u >> 13) & 63;
        const int n = nt * 16 + nlow;
        const int k0 = kc * 32 + koct * 8 + half * 4;
        const float* src = w_out + (size_t)k0 * 1024 + n;
        uint2 o;
        o.x = (unsigned)f2bf(src[0])    | ((unsigned)f2bf(src[1024]) << 16);
        o.y = (unsigned)f2bf(src[2048]) | ((unsigned)f2bf(src[3072]) << 16);
        const size_t chunk = ((size_t)nt * 64 + kc) * 64 + koct * 16 + nlow;
        *(uint2*)(bfragw + chunk * 8 + half * 4) = o;
    } else if (bx < 4352) {
        // ---- w_kv -> bfragkv (B-frag KC=32, N=256): dense writes ----
        const unsigned u = (unsigned)(bx - 4096) * 256 + t;
        const int half = u & 1;
        const int nlow = (u >> 1) & 15;
        const int koct = (u >> 5) & 3;
        const int kc   = (u >> 7) & 31;
        const int nt   = (u >> 12) & 15;
        const int n = nt * 16 + nlow;
        const int k0 = kc * 32 + koct * 8 + half * 4;
        const float* src = w_kv + (size_t)k0 * 256 + n;
        uint2 o;
        o.x = (unsigned)f2bf(src[0])   | ((unsigned)f2bf(src[256]) << 16);
        o.y = (unsigned)f2bf(src[512]) | ((unsigned)f2bf(src[768]) << 16);
        const size_t chunk = ((size_t)nt * 32 + kc) * 64 + koct * 16 + nlow;
        *(uint2*)(bfragkv + chunk * 8 + half * 4) = o;
    } else if (bx < 4480) {
        // ---- pos_pk -> bfragp (small; original mapping, coalesced row reads) ----
        const int n = bx - 4352;
        float v[4];
#pragma unroll
        for (int d = 0; d < 4; ++d) v[d] = pos_pk[(size_t)n * 1024 + 4 * t + d];
        const int nt = n >> 4, kc = t >> 3;
        const int lane = ((t & 7) >> 1) * 16 + (n & 15);
        const size_t off = (((size_t)nt * 32 + kc) * 64 + lane) * 8 + 4 * (t & 1);
        uint2 o;
        o.x = (unsigned)f2bf(v[0]) | ((unsigned)f2bf(v[1]) << 16);
        o.y = (unsigned)f2bf(v[2]) | ((unsigned)f2bf(v[3]) << 16);
        *(uint2*)(bfragp + off) = o;
    } else if (bx < 6528) {
        // ---- pe -> pefrag (A-frag, 2048 rows, row 2047 = 0): dense writes ----
        const unsigned u = (unsigned)(bx - 4480) * 256 + t;
        const int half = u & 1;
        const int mlow = (u >> 1) & 15;
        const int koct = (u >> 5) & 3;
        const int kc   = (u >> 7) & 31;
        const int mt   = (u >> 12) & 127;
        const int m = mt * 16 + mlow;
        const int k0 = kc * 32 + koct * 8 + half * 4;
        uint2 o;
        if (m >= 2047) {
            o.x = 0u; o.y = 0u;
        } else {
            const float c1 = -logf(10000.f) / 1024.f;
            const float pos = (float)(m - 1023);
            const float a0 = pos * expf((float)k0 * c1);
            const float a1 = pos * expf((float)(k0 + 2) * c1);
            o.x = (unsigned)f2bf(sinf(a0)) | ((unsigned)f2bf(cosf(a0)) << 16);
            o.y = (unsigned)f2bf(sinf(a1)) | ((unsigned)f2bf(cosf(a1)) << 16);
        }
        const size_t chunk = ((size_t)mt * 32 + kc) * 64 + koct * 16 + mlow;
        *(uint2*)(pefrag + chunk * 8 + half * 4) = o;
    } else if (bx < 10624) {
        // ---- sel: selection + top-8 + sigmoid (afrag written by the dense curr section) ----
        const int token = bx - 6528;
        const float4 v = ((const float4*)(curr + (size_t)token * 1024))[t];
        ((float4*)row)[t] = v;
        __syncthreads();
        const int wv = t >> 6, lane = t & 63;
        for (int e0 = 0; e0 < 4; ++e0) {
            const int e = wv * 4 + e0;
            const float* w = sel_dst + e * 1024;
            float p = 0.f;
            for (int i = lane; i < 1024; i += 64) p += row[i] * w[i];
            for (int off = 32; off; off >>= 1) p += __shfl_down(p, off, 64);
            if (lane == 0) sel[e] = p;
        }
        __syncthreads();
        if (t == 0) {
            float v16[16];
#pragma unroll
            for (int e = 0; e < 16; ++e) v16[e] = sel[e];
#pragma unroll
            for (int r = 0; r < 8; ++r) {
                int bi = 0; float bv = v16[0];
#pragma unroll
                for (int e = 1; e < 16; ++e) { if (v16[e] > bv) { bv = v16[e]; bi = e; } }
                selidx[token * 8 + r] = bi;
                selval[token * 8 + r] = 1.f / (1.f + __expf(-bv));
                v16[bi] = -INFINITY;
            }
        }
    } else if (bx < 14720) {
        // ---- curr -> afrag (A-frag, 4096 rows): dense writes, full-line float4 reads ----
        const unsigned u = (unsigned)(bx - 10624) * 256 + t;
        const int half = u & 1;
        const int mlow = (u >> 1) & 15;
        const int koct = (u >> 5) & 3;
        const int kc   = (u >> 7) & 31;
        const int mt   = (u >> 12) & 255;
        const int m = mt * 16 + mlow;
        const int k0 = kc * 32 + koct * 8 + half * 4;
        const float4 v = *(const float4*)(curr + (size_t)m * 1024 + k0);
        uint2 o;
        o.x = (unsigned)f2bf(v.x) | ((unsigned)f2bf(v.y) << 16);
        o.y = (unsigned)f2bf(v.z) | ((unsigned)f2bf(v.w) << 16);
        const size_t chunk = ((size_t)mt * 32 + kc) * 64 + koct * 16 + mlow;
        *(uint2*)(afrag + chunk * 8 + half * 4) = o;
    } else {
        // ---- attend -> attfrag (A-frag, 4096 rows): dense writes ----
        const unsigned u = (unsigned)(bx - 14720) * 256 + t;
        const int half = u & 1;
        const int mlow = (u >> 1) & 15;
        const int koct = (u >> 5) & 3;
        const int kc   = (u >> 7) & 31;
        const int mt   = (u >> 12) & 255;
        const int m = mt * 16 + mlow;
        const int k0 = kc * 32 + koct * 8 + half * 4;
        const float4 v = *(const float4*)(attend + (size_t)m * 1024 + k0);
        uint2 o;
        o.x = (unsigned)f2bf(v.x) | ((unsigned)f2bf(v.y) << 16);
        o.y = (unsigned)f2bf(v.z) | ((unsigned)f2bf(v.w) << 16);
        const size_t chunk = ((size_t)mt * 32 + kc) * 64 + koct * 16 + mlow;
        *(uint2*)(attfrag + chunk * 8 + half * 4) = o;
    }
}

// ---------------- MFMA GEMM core: 128x64 tile, 4 waves, frag-ordered global in ----------------
__device__ __forceinline__ void gemm_core64(const unsigned short* __restrict__ Afrag,
                                            const unsigned short* __restrict__ Bfrag,
                                            int mt0, int nt0, int KC,
                                            unsigned short (*aT)[512],
                                            unsigned short (*bT)[512],
                                            floatx4 acc[4][2]) {
    const int t = threadIdx.x;
    const int w = t >> 6, lane = t & 63;
    const int wm = w >> 1, wn = w & 1;
    for (int kc = 0; kc < KC; ++kc) {
        __syncthreads();
        {
            const int fi = w * 3;
#pragma unroll
            for (int l = 0; l < 3; ++l) {
                const int f = fi + l;   // 0..11: 8 A-frags then 4 B-frags
                if (f < 8)
                    gload16(Afrag + (((size_t)(mt0 + f) * KC + kc) * 64 + lane) * 8, &aT[f][0]);
                else
                    gload16(Bfrag + (((size_t)(nt0 + f - 8) * KC + kc) * 64 + lane) * 8, &bT[f - 8][0]);
            }
        }
        __syncthreads();
        short8 af[4], bf[2];
#pragma unroll
        for (int i = 0; i < 4; ++i) af[i] = *(const short8*)&aT[wm * 4 + i][lane * 8];
#pragma unroll
        for (int j = 0; j < 2; ++j) bf[j] = *(const short8*)&bT[wn * 2 + j][lane * 8];
#pragma unroll
        for (int i = 0; i < 4; ++i)
#pragma unroll
            for (int j = 0; j < 2; ++j)
                acc[i][j] = __builtin_amdgcn_mfma_f32_16x16x32_bf16(af[i], bf[j], acc[i][j], 0, 0, 0);
    }
}

// ---------------- k_gemm3: fused qall + kv + kpos (all independent, one launch) ----------------
// blocks [0,1024): qall (32x32); [1024,1152): kv (32x4); [1152,1184): kpos (16x2).
__global__ __launch_bounds__(256) void k_gemm3(const unsigned short* __restrict__ afrag,
                                               const unsigned short* __restrict__ bfragq,
                                               const unsigned short* __restrict__ attfrag,
                                               const unsigned short* __restrict__ bfragkv,
                                               const unsigned short* __restrict__ pefrag,
                                               const unsigned short* __restrict__ bfragp,
                                               const float* __restrict__ scale,
                                               unsigned short* __restrict__ qall,
                                               unsigned short* __restrict__ kfragg,
                                               unsigned short* __restrict__ vfragg,
                                               unsigned short* __restrict__ kposfg) {
    __shared__ __align__(16) unsigned short aT[8][512], bT[4][512];
    floatx4 acc[4][2];
#pragma unroll
    for (int i = 0; i < 4; ++i) { acc[i][0] = (floatx4){0,0,0,0}; acc[i][1] = (floatx4){0,0,0,0}; }
    const int bx = blockIdx.x;
    const int t = threadIdx.x, w = t >> 6, lane = t & 63;
    const int wm = w >> 1, wn = w & 1, lq = lane >> 4, lm = lane & 15;
    const float sc = sqrtf(scale[0]);

    if (bx < 1024) {
        const int gx = bx & 31, gy = bx >> 5;
        gemm_core64(afrag, bfragq, gx * 8, gy * 4, 32, aT, bT, acc);
#pragma unroll
        for (int i = 0; i < 4; ++i)
#pragma unroll
            for (int j = 0; j < 2; ++j)
#pragma unroll
                for (int r = 0; r < 4; ++r)
                    qall[(size_t)(gx * 128 + (wm * 4 + i) * 16 + lq * 4 + r) * 2048 +
                         gy * 64 + (wn * 2 + j) * 16 + lm] = f2bf(acc[i][j][r] * sc);
    } else if (bx < 1152) {
        const int q = bx - 1024;
        const int gx = q & 31, gy = q >> 5;
        gemm_core64(attfrag, bfragkv, gx * 8, gy * 4, 32, aT, bT, acc);
#pragma unroll
        for (int i = 0; i < 4; ++i)
#pragma unroll
            for (int j = 0; j < 2; ++j) {
                const int n = gy * 64 + (wn * 2 + j) * 16 + lm;
#pragma unroll
                for (int r = 0; r < 4; ++r) {
                    const int tok = gx * 128 + (wm * 4 + i) * 16 + lq * 4 + r;
                    const int bb = tok >> 10, jj = tok & 1023;
                    if (n < 128) {
                        const int p = n;
                        const size_t addr = ((((size_t)bb * 64 + (jj >> 4)) * 4 + (p >> 5)) * 64 +
                                             ((p & 31) >> 3) * 16 + (jj & 15)) * 8 + (p & 7);
                        kfragg[addr] = f2bf(acc[i][j][r] * sc);
                    } else {
                        const int p = n - 128;
                        const size_t addr = ((((size_t)bb * 32 + (jj >> 5)) * 8 + (p >> 4)) * 64 +
                                             ((jj & 31) >> 3) * 16 + (p & 15)) * 8 + (jj & 7);
                        vfragg[addr] = f2bf(acc[i][j][r]);
                    }
                }
            }
    } else {
        const int q = bx - 1152;
        const int gx = q & 15, gy = q >> 4;
        gemm_core64(pefrag, bfragp, gx * 8, gy * 4, 32, aT, bT, acc);
#pragma unroll
        for (int i = 0; i < 4; ++i)
#pragma unroll
            for (int j = 0; j < 2; ++j) {
                const int p = gy * 64 + (wn * 2 + j) * 16 + lm;
#pragma unroll
                for (int r = 0; r < 4; ++r) {
                    const int tp = gx * 128 + (wm * 4 + i) * 16 + lq * 4 + r;
                    const size_t addr = (((size_t)(tp >> 4) * 4 + (p >> 5)) * 64 +
                                         ((p & 31) >> 3) * 16 + (tp & 15)) * 8 + (p & 7);
                    kposfg[addr] = f2bf(acc[i][j][r] * sc);
                }
            }
    }
}

// ---------------- GEMM: out = zfrag @ w_out -> f32 row-major 4096x1024 ----------------
__global__ __launch_bounds__(256) void k_gemm_out(const unsigned short* __restrict__ Afrag,
                                                  const unsigned short* __restrict__ Bfrag,
                                                  float* __restrict__ out) {
    __shared__ __align__(16) unsigned short aT[8][512], bT[4][512];
    floatx4 acc[4][2];
#pragma unroll
    for (int i = 0; i < 4; ++i) { acc[i][0] = (floatx4){0,0,0,0}; acc[i][1] = (floatx4){0,0,0,0}; }
    gemm_core64(Afrag, Bfrag, blockIdx.x * 8, blockIdx.y * 4, 64, aT, bT, acc);
    const int t = threadIdx.x, w = t >> 6, lane = t & 63;
    const int wm = w >> 1, wn = w & 1, lq = lane >> 4, lm = lane & 15;
#pragma unroll
    for (int i = 0; i < 4; ++i)
#pragma unroll
        for (int j = 0; j < 2; ++j)
#pragma unroll
            for (int r = 0; r < 4; ++r)
                out[(size_t)(blockIdx.x * 128 + (wm * 4 + i) * 16 + lq * 4 + r) * 1024 +
                    blockIdx.y * 64 + (wn * 2 + j) * 16 + lm] = acc[i][j][r];
}

// ---------------- k_attn (unchanged from R4): key-split 2x + K/V LDS double-buffer + sp carry ----------------
#define ATTN_FM 8.0f

__global__ __launch_bounds__(256, 2) void k_attn(const unsigned short* __restrict__ qall,
                                                 const unsigned short* __restrict__ kfragg,
                                                 const unsigned short* __restrict__ vfragg,
                                                 const unsigned short* __restrict__ kposfg,
                                                 const int* __restrict__ selidx,
                                                 const float* __restrict__ selval,
                                                 unsigned short* __restrict__ zfrag) {
    // pl+kst+vst live only inside the K-loop; cmb live only after the post-loop barrier.
    __shared__ __align__(16) union {
        struct {
            unsigned short pl[2][4][16][56];      // 14336 B (per-wave P staging, double-buffered)
            unsigned short kst[2][2][8][512];     // 32768 B [buf][ws][q]: 8x1KB K chunks per half
            unsigned short vst[2][2][8][512];     // 32768 B [buf][ws][q]: 8x1KB V chunks per half
        } s;
        float cmb[2][64][37];                     // 18944 B (37: bank-conflict pad)
    } sh;                                         // 79872 B total

    const int t = threadIdx.x;
    const int w = t >> 6, lane = t & 63;
    const int st = blockIdx.x & 63;
    const int hg = (blockIdx.x >> 6) & 3;       // 4 head-pairs
    const int b = blockIdx.x >> 8;
    const int wh = w & 1;                       // head within pair
    const int ws = w >> 1;                      // key-split half (0: keys 0-511, 1: keys 512-1023)
    const int h = hg * 2 + wh;
    const int s0 = st * 16;
    const int lq = lane >> 4;
    const int lm = lane & 15;
    const int loff = lane * 16;

    short8 qf[4];
    {
        const int token = b * 1024 + s0 + lm;
        const int e = selidx[token * 8 + h];
        const unsigned short* qb = qall + (size_t)token * 2048 + e * 128 + lq * 8;
#pragma unroll
        for (int c = 0; c < 4; ++c) qf[c] = *(const short8*)(qb + c * 32);
    }
    short8 onesf;
#pragma unroll
    for (int i = 0; i < 8; ++i) onesf[i] = (short)0x3F80;

    int baddr[4], bsel[4];
#pragma unroll
    for (int r = 0; r < 4; ++r) {
        const int c0 = 15 + lm - (lq * 4 + r);
        baddr[r] = (lq * 16 + (c0 & 15)) * 4;
        bsel[r] = (c0 < 16) ? 1 : 0;
    }

    floatx4 acc[8], accl;
#pragma unroll
    for (int nt = 0; nt < 8; ++nt) acc[nt] = (floatx4){0.f, 0.f, 0.f, 0.f};
    accl = (floatx4){0.f, 0.f, 0.f, 0.f};

    // second-half waves start 16 steps (512 keys / 512 positions) in
    const size_t koff = (size_t)ws * 131072;
    const char* pk = (const char*)kfragg + (size_t)b * 262144 + koff;
    const char* pv = (const char*)vfragg + (size_t)b * 262144 + koff;
    const char* pp = (const char*)kposfg + (size_t)((1008 - s0) >> 4) * 4096 + koff;

    // ---- prologue: stage iter-0 K/V into buf0; load pos frags; fold cry into sp_carry ----
    if (wh == 0) {
#pragma unroll
        for (int q = 0; q < 8; ++q)
            gload16(pk + q * 1024 + loff, &sh.s.kst[0][ws][q][0]);
    } else {
#pragma unroll
        for (int q = 0; q < 8; ++q)
            gload16(pv + q * 1024 + loff, &sh.s.vst[0][ws][q][0]);
    }
    short8 n1c[4], n2c[4];
    floatx4 sp_carry = {0.f, 0.f, 0.f, 0.f};
    {
        short8 cry[4];
#pragma unroll
        for (int c = 0; c < 4; ++c) {
            cry[c] = *(const short8*)(pp + c * 1024 + loff);
            n1c[c] = *(const short8*)(pp + 4096 + c * 1024 + loff);
            n2c[c] = *(const short8*)(pp + 8192 + c * 1024 + loff);
        }
#pragma unroll
        for (int c = 0; c < 4; ++c)
            sp_carry = __builtin_amdgcn_mfma_f32_16x16x32_bf16(qf[c], cry[c], sp_carry, 0, 0, 0);
    }
    __syncthreads();                            // buf0 staged

    unsigned short* pl0 = &sh.s.pl[0][w][0][0];
    unsigned short* pl1 = &sh.s.pl[1][w][0][0];

    for (int it = 0; it < 16; ++it) {
        const int cur = it & 1, nxt = cur ^ 1;
        // issue next-iteration staging FIRST: a full iteration of compute covers the latency
        if (it < 15) {
            if (wh == 0) {
#pragma unroll
                for (int q = 0; q < 8; ++q)
                    gload16(pk + 8192 + q * 1024 + loff, &sh.s.kst[nxt][ws][q][0]);
            } else {
#pragma unroll
                for (int q = 0; q < 8; ++q)
                    gload16(pv + 8192 + q * 1024 + loff, &sh.s.vst[nxt][ws][q][0]);
            }
        }
        // prefetch next-iteration pos fragments into regs
        short8 n1n[4], n2n[4];
        if (it < 15) {
#pragma unroll
            for (int c = 0; c < 4; ++c) {
                n1n[c] = *(const short8*)(pp + 12288 + c * 1024 + loff);
                n2n[c] = *(const short8*)(pp + 16384 + c * 1024 + loff);
            }
        }
        // sp0 carried from previous iteration's sp2 (cry == prev n2)
        const floatx4 sp0 = sp_carry;
        floatx4 sp1 = {0.f, 0.f, 0.f, 0.f}, sp2 = {0.f, 0.f, 0.f, 0.f};
#pragma unroll
        for (int c = 0; c < 4; ++c) {
            sp1 = __builtin_amdgcn_mfma_f32_16x16x32_bf16(qf[c], n1c[c], sp1, 0, 0, 0);
            sp2 = __builtin_amdgcn_mfma_f32_16x16x32_bf16(qf[c], n2c[c], sp2, 0, 0, 0);
        }
        floatx4 sk0 = {0.f, 0.f, 0.f, 0.f}, sk1 = {0.f, 0.f, 0.f, 0.f};
#pragma unroll
        for (int c = 0; c < 4; ++c) {
            const short8 k0 = *(const short8*)&sh.s.kst[cur][ws][c][lane * 8];
            const short8 k1 = *(const short8*)&sh.s.kst[cur][ws][4 + c][lane * 8];
            sk0 = __builtin_amdgcn_mfma_f32_16x16x32_bf16(qf[c], k0, sk0, 0, 0, 0);
            sk1 = __builtin_amdgcn_mfma_f32_16x16x32_bf16(qf[c], k1, sk1, 0, 0, 0);
        }
        unsigned short* pl = cur ? pl1 : pl0;
#pragma unroll
        for (int r = 0; r < 4; ++r) {
            const int a = baddr[r];
            const float b0 = __int_as_float(__builtin_amdgcn_ds_bpermute(a, __float_as_int(sp0[r])));
            const float b1 = __int_as_float(__builtin_amdgcn_ds_bpermute(a, __float_as_int(sp1[r])));
            const float b2 = __int_as_float(__builtin_amdgcn_ds_bpermute(a, __float_as_int(sp2[r])));
            const float v0 = sk0[r] + (bsel[r] ? b0 : b1);
            const float v1 = sk1[r] + (bsel[r] ? b1 : b2);
            pl[(lq * 4 + r) * 56 + lm]      = f2bf(__expf(v0 - ATTN_FM));
            pl[(lq * 4 + r) * 56 + 16 + lm] = f2bf(__expf(v1 - ATTN_FM));
        }
        asm volatile("" ::: "memory");
        const short8 pf = *(const short8*)(pl + lm * 56 + lq * 8);
#pragma unroll
        for (int nt = 0; nt < 8; ++nt) {
            const short8 vf = *(const short8*)&sh.s.vst[cur][ws][nt][lane * 8];
            acc[nt] = __builtin_amdgcn_mfma_f32_16x16x32_bf16(pf, vf, acc[nt], 0, 0, 0);
        }
        accl = __builtin_amdgcn_mfma_f32_16x16x32_bf16(pf, onesf, accl, 0, 0, 0);
        sp_carry = sp2;
#pragma unroll
        for (int c = 0; c < 4; ++c) { n1c[c] = n1n[c]; n2c[c] = n2n[c]; }
        pk += 8192; pv += 8192; pp += 8192;
        __syncthreads();                        // drain prefetch; buf[cur] reads done -> reusable
    }

    // ---- combine the two key-halves through LDS (fixed-max softmax => partials are additive) ----
    if (ws == 1) {
        float* cb = &sh.cmb[wh][lane][0];
#pragma unroll
        for (int nt = 0; nt < 8; ++nt)
#pragma unroll
            for (int r = 0; r < 4; ++r) cb[nt * 4 + r] = acc[nt][r];
#pragma unroll
        for (int r = 0; r < 4; ++r) cb[32 + r] = accl[r];
    }
    __syncthreads();
    if (ws == 1) return;
    {
        const float* cb = &sh.cmb[wh][lane][0];
#pragma unroll
        for (int nt = 0; nt < 8; ++nt)
#pragma unroll
            for (int r = 0; r < 4; ++r) acc[nt][r] += cb[nt * 4 + r];
#pragma unroll
        for (int r = 0; r < 4; ++r) accl[r] += cb[32 + r];
    }

#pragma unroll
    for (int r = 0; r < 4; ++r) {
        const int tok = b * 1024 + s0 + lq * 4 + r;
        const int e = selidx[tok * 8 + h];
        const float g = selval[tok * 8 + h] / accl[r];
        const int mt = tok >> 4, tm = tok & 15;
#pragma unroll
        for (int nt = 0; nt < 8; ++nt) {
            const int k = e * 128 + nt * 16 + lm;
            const int kc = k >> 5;
            const int lane2 = (((k & 31) >> 3) << 4) + tm;
            zfrag[(((size_t)mt * 64 + kc) * 64 + lane2) * 8 + (k & 7)] = f2bf(acc[nt][r] * g);
        }
    }
}

extern "C" void kernel_launch(void* const* d_in, const int* in_sizes, int n_in,
                              void* d_out, int out_size, void* d_ws, size_t ws_size,
                              hipStream_t stream) {
    const float* curr    = (const float*)d_in[0];  // (4,1024,1024)
    const float* attend  = (const float*)d_in[1];  // (4,1024,1024)
    const float* w_q     = (const float*)d_in[2];  // (16,1024,128)
    const float* w_kv    = (const float*)d_in[3];  // (1024,256)
    const float* w_out   = (const float*)d_in[4];  // (16,128,1024)
    const float* pos_pk  = (const float*)d_in[5];  // (128,1024)
    const float* sel_dst = (const float*)d_in[6];  // (16,1024)
    const float* scale   = (const float*)d_in[7];  // (1,)
    float* out = (float*)d_out;

    char* ws = (char*)d_ws;
    float* selval = (float*)ws;                                        // 128 KB
    int*   selidx = (int*)(ws + 131072);                               // 128 KB
    unsigned short* kposfg  = (unsigned short*)(ws + 262144);          // 512 KB
    unsigned short* kfragg  = (unsigned short*)(ws + 786432);          // 1 MB
    unsigned short* vfragg  = (unsigned short*)(ws + 1835008);         // 1 MB
    unsigned short* bfragq  = (unsigned short*)(ws + 2883584);         // 4 MB
    unsigned short* bfragw  = (unsigned short*)(ws + 7077888);         // 4 MB
    unsigned short* bfragkv = (unsigned short*)(ws + 11272192);        // 512 KB
    unsigned short* afrag   = (unsigned short*)(ws + 11796480);        // 8 MB (curr A-frag)
    unsigned short* qall    = (unsigned short*)(ws + 20185088);        // 16 MB
    unsigned short* zfrag   = (unsigned short*)(ws + 36962304);        // 16 MB
    // Aliases inside zfrag (all fully consumed by k_gemm3 BEFORE zfrag's memset):
    //   pefrag  = zfrag[0 .. 4MB)       (pe A-frag)
    //   bfragp  = zfrag[4MB .. 4.25MB)  (pos_pk B-frag)
    //   attfrag = zfrag[8MB .. 16MB)    (attend A-frag)
    unsigned short* pefrag  = zfrag;                                   // 4 MB
    unsigned short* bfragp  = zfrag + 2097152;                         // 256 KB
    unsigned short* attfrag = zfrag + 4194304;                         // 8 MB
    // total ~51.3 MB

    k_prep<<<18816, 256, 0, stream>>>(curr, attend, w_q, w_out, w_kv, pos_pk, sel_dst,
                                      selval, selidx, afrag, attfrag,
                                      bfragq, bfragw, bfragkv, bfragp, pefrag);
    k_gemm3<<<1184, 256, 0, stream>>>(afrag, bfragq, attfrag, bfragkv, pefrag, bfragp,
                                      scale, qall, kfragg, vfragg, kposfg);
    hipMemsetAsync(zfrag, 0, (size_t)16777216, stream);
    k_attn<<<1024, 256, 0, stream>>>(qall, kfragg, vfragg, kposfg, selidx, selval, zfrag);
    k_gemm_out<<<dim3(32, 16), 256, 0, stream>>>(zfrag, bfragw, out);
}

// Round 10
// 259.439 us; speedup vs baseline: 1.2055x; 1.0417x over previous
//
#include <hip/hip_runtime.h>
#include <math.h>

// B=4 S=1024 D=1024 P=128 H=8 E=16, NT=4096, TPOS=2047

typedef __attribute__((ext_vector_type(8))) short short8;
typedef __attribute__((ext_vector_type(4))) float floatx4;

__device__ __forceinline__ float bf2f(unsigned int u) {
    union { unsigned int i; float f; } x; x.i = (u & 0xffffu) << 16; return x.f;
}
__device__ __forceinline__ unsigned short f2bf(float f) {
    union { float f; unsigned int i; } x; x.f = f;
    unsigned int r = x.i + 0x7fffu + ((x.i >> 16) & 1u);
    return (unsigned short)(r >> 16);
}

// async global->LDS: per-lane global addr, wave-uniform LDS base; lane data at base + lane*16
__device__ __forceinline__ void gload16(const void* g, void* l) {
    __builtin_amdgcn_global_load_lds(
        (const __attribute__((address_space(1))) unsigned int*)(uintptr_t)g,
        (__attribute__((address_space(3))) unsigned int*)(uintptr_t)l,
        16, 0, 0);
}

// Fragment layouts (16x16x32 bf16 MFMA), HW-verified R2-R6:
//   A-frag (MxK):  afrag[m>>4][k>>5][((k&31)>>3)*16 + (m&15)][k&7]
//   B-frag (KxN):  bfrag[n>>4][k>>5][((k&31)>>3)*16 + (n&15)][k&7]
//   C/D:           col = lane&15, row = (lane>>4)*4 + reg
// R9 dense-write converters: u-bits [0]=half(j>>2), [1:4]=n/m low, [5:6]=k-octet, [7:..]=kc, nt/mt.

// ---------------- k_prep R9: dense-write converters + sel (no afrag write) ----------------
// [0,2048): w_q; [2048,4096): w_out; [4096,4352): w_kv; [4352,4480): pos_pk (orig);
// [4480,6528): pe; [6528,10624): sel; [10624,14720): curr->afrag; [14720,18816): attend->attfrag.
__global__ __launch_bounds__(256) void k_prep(const float* __restrict__ curr,
                                              const float* __restrict__ attend,
                                              const float* __restrict__ w_q,
                                              const float* __restrict__ w_out,
                                              const float* __restrict__ w_kv,
                                              const float* __restrict__ pos_pk,
                                              const float* __restrict__ sel_dst,
                                              float* __restrict__ selval,
                                              int* __restrict__ selidx,
                                              unsigned short* __restrict__ afrag,
                                              unsigned short* __restrict__ attfrag,
                                              unsigned short* __restrict__ bfragq,
                                              unsigned short* __restrict__ bfragw,
                                              unsigned short* __restrict__ bfragkv,
                                              unsigned short* __restrict__ bfragp,
                                              unsigned short* __restrict__ pefrag) {
    __shared__ float row[1024];
    __shared__ float sel[16];
    const int bx = blockIdx.x;
    const int t = threadIdx.x;

    if (bx < 2048) {
        const unsigned u = (unsigned)bx * 256 + t;
        const int half = u & 1;
        const int nlow = (u >> 1) & 15;
        const int koct = (u >> 5) & 3;
        const int kc   = (u >> 7) & 31;
        const int nt   = (u >> 12) & 127;
        const int n = nt * 16 + nlow;
        const int e = n >> 7, p = n & 127;
        const int k0 = kc * 32 + koct * 8 + half * 4;
        const float* src = w_q + (size_t)e * 131072 + (size_t)k0 * 128 + p;
        uint2 o;
        o.x = (unsigned)f2bf(src[0])   | ((unsigned)f2bf(src[128]) << 16);
        o.y = (unsigned)f2bf(src[256]) | ((unsigned)f2bf(src[384]) << 16);
        const size_t chunk = ((size_t)nt * 32 + kc) * 64 + koct * 16 + nlow;
        *(uint2*)(bfragq + chunk * 8 + half * 4) = o;
    } else if (bx < 4096) {
        const unsigned u = (unsigned)(bx - 2048) * 256 + t;
        const int half = u & 1;
        const int nlow = (u >> 1) & 15;
        const int koct = (u >> 5) & 3;
        const int kc   = (u >> 7) & 63;
        const int nt   = (u >> 13) & 63;
        const int n = nt * 16 + nlow;
        const int k0 = kc * 32 + koct * 8 + half * 4;
        const float* src = w_out + (size_t)k0 * 1024 + n;
        uint2 o;
        o.x = (unsigned)f2bf(src[0])    | ((unsigned)f2bf(src[1024]) << 16);
        o.y = (unsigned)f2bf(src[2048]) | ((unsigned)f2bf(src[3072]) << 16);
        const size_t chunk = ((size_t)nt * 64 + kc) * 64 + koct * 16 + nlow;
        *(uint2*)(bfragw + chunk * 8 + half * 4) = o;
    } else if (bx < 4352) {
        const unsigned u = (unsigned)(bx - 4096) * 256 + t;
        const int half = u & 1;
        const int nlow = (u >> 1) & 15;
        const int koct = (u >> 5) & 3;
        const int kc   = (u >> 7) & 31;
        const int nt   = (u >> 12) & 15;
        const int n = nt * 16 + nlow;
        const int k0 = kc * 32 + koct * 8 + half * 4;
        const float* src = w_kv + (size_t)k0 * 256 + n;
        uint2 o;
        o.x = (unsigned)f2bf(src[0])   | ((unsigned)f2bf(src[256]) << 16);
        o.y = (unsigned)f2bf(src[512]) | ((unsigned)f2bf(src[768]) << 16);
        const size_t chunk = ((size_t)nt * 32 + kc) * 64 + koct * 16 + nlow;
        *(uint2*)(bfragkv + chunk * 8 + half * 4) = o;
    } else if (bx < 4480) {
        const int n = bx - 4352;
        float v[4];
#pragma unroll
        for (int d = 0; d < 4; ++d) v[d] = pos_pk[(size_t)n * 1024 + 4 * t + d];
        const int nt = n >> 4, kc = t >> 3;
        const int lane = ((t & 7) >> 1) * 16 + (n & 15);
        const size_t off = (((size_t)nt * 32 + kc) * 64 + lane) * 8 + 4 * (t & 1);
        uint2 o;
        o.x = (unsigned)f2bf(v[0]) | ((unsigned)f2bf(v[1]) << 16);
        o.y = (unsigned)f2bf(v[2]) | ((unsigned)f2bf(v[3]) << 16);
        *(uint2*)(bfragp + off) = o;
    } else if (bx < 6528) {
        const unsigned u = (unsigned)(bx - 4480) * 256 + t;
        const int half = u & 1;
        const int mlow = (u >> 1) & 15;
        const int koct = (u >> 5) & 3;
        const int kc   = (u >> 7) & 31;
        const int mt   = (u >> 12) & 127;
        const int m = mt * 16 + mlow;
        const int k0 = kc * 32 + koct * 8 + half * 4;
        uint2 o;
        if (m >= 2047) {
            o.x = 0u; o.y = 0u;
        } else {
            const float c1 = -logf(10000.f) / 1024.f;
            const float pos = (float)(m - 1023);
            const float a0 = pos * expf((float)k0 * c1);
            const float a1 = pos * expf((float)(k0 + 2) * c1);
            o.x = (unsigned)f2bf(sinf(a0)) | ((unsigned)f2bf(cosf(a0)) << 16);
            o.y = (unsigned)f2bf(sinf(a1)) | ((unsigned)f2bf(cosf(a1)) << 16);
        }
        const size_t chunk = ((size_t)mt * 32 + kc) * 64 + koct * 16 + mlow;
        *(uint2*)(pefrag + chunk * 8 + half * 4) = o;
    } else if (bx < 10624) {
        const int token = bx - 6528;
        const float4 v = ((const float4*)(curr + (size_t)token * 1024))[t];
        ((float4*)row)[t] = v;
        __syncthreads();
        const int wv = t >> 6, lane = t & 63;
        for (int e0 = 0; e0 < 4; ++e0) {
            const int e = wv * 4 + e0;
            const float* w = sel_dst + e * 1024;
            float p = 0.f;
            for (int i = lane; i < 1024; i += 64) p += row[i] * w[i];
            for (int off = 32; off; off >>= 1) p += __shfl_down(p, off, 64);
            if (lane == 0) sel[e] = p;
        }
        __syncthreads();
        if (t == 0) {
            float v16[16];
#pragma unroll
            for (int e = 0; e < 16; ++e) v16[e] = sel[e];
#pragma unroll
            for (int r = 0; r < 8; ++r) {
                int bi = 0; float bv = v16[0];
#pragma unroll
                for (int e = 1; e < 16; ++e) { if (v16[e] > bv) { bv = v16[e]; bi = e; } }
                selidx[token * 8 + r] = bi;
                selval[token * 8 + r] = 1.f / (1.f + __expf(-bv));
                v16[bi] = -INFINITY;
            }
        }
    } else if (bx < 14720) {
        const unsigned u = (unsigned)(bx - 10624) * 256 + t;
        const int half = u & 1;
        const int mlow = (u >> 1) & 15;
        const int koct = (u >> 5) & 3;
        const int kc   = (u >> 7) & 31;
        const int mt   = (u >> 12) & 255;
        const int m = mt * 16 + mlow;
        const int k0 = kc * 32 + koct * 8 + half * 4;
        const float4 v = *(const float4*)(curr + (size_t)m * 1024 + k0);
        uint2 o;
        o.x = (unsigned)f2bf(v.x) | ((unsigned)f2bf(v.y) << 16);
        o.y = (unsigned)f2bf(v.z) | ((unsigned)f2bf(v.w) << 16);
        const size_t chunk = ((size_t)mt * 32 + kc) * 64 + koct * 16 + mlow;
        *(uint2*)(afrag + chunk * 8 + half * 4) = o;
    } else {
        const unsigned u = (unsigned)(bx - 14720) * 256 + t;
        const int half = u & 1;
        const int mlow = (u >> 1) & 15;
        const int koct = (u >> 5) & 3;
        const int kc   = (u >> 7) & 31;
        const int mt   = (u >> 12) & 255;
        const int m = mt * 16 + mlow;
        const int k0 = kc * 32 + koct * 8 + half * 4;
        const float4 v = *(const float4*)(attend + (size_t)m * 1024 + k0);
        uint2 o;
        o.x = (unsigned)f2bf(v.x) | ((unsigned)f2bf(v.y) << 16);
        o.y = (unsigned)f2bf(v.z) | ((unsigned)f2bf(v.w) << 16);
        const size_t chunk = ((size_t)mt * 32 + kc) * 64 + koct * 16 + mlow;
        *(uint2*)(attfrag + chunk * 8 + half * 4) = o;
    }
}

// ---------------- MFMA GEMM core: 128x64 tile, 4 waves, frag-ordered global in ----------------
__device__ __forceinline__ void gemm_core64(const unsigned short* __restrict__ Afrag,
                                            const unsigned short* __restrict__ Bfrag,
                                            int mt0, int nt0, int KC,
                                            unsigned short (*aT)[512],
                                            unsigned short (*bT)[512],
                                            floatx4 acc[4][2]) {
    const int t = threadIdx.x;
    const int w = t >> 6, lane = t & 63;
    const int wm = w >> 1, wn = w & 1;
    for (int kc = 0; kc < KC; ++kc) {
        __syncthreads();
        {
            const int fi = w * 3;
#pragma unroll
            for (int l = 0; l < 3; ++l) {
                const int f = fi + l;   // 0..11: 8 A-frags then 4 B-frags
                if (f < 8)
                    gload16(Afrag + (((size_t)(mt0 + f) * KC + kc) * 64 + lane) * 8, &aT[f][0]);
                else
                    gload16(Bfrag + (((size_t)(nt0 + f - 8) * KC + kc) * 64 + lane) * 8, &bT[f - 8][0]);
            }
        }
        __syncthreads();
        short8 af[4], bf[2];
#pragma unroll
        for (int i = 0; i < 4; ++i) af[i] = *(const short8*)&aT[wm * 4 + i][lane * 8];
#pragma unroll
        for (int j = 0; j < 2; ++j) bf[j] = *(const short8*)&bT[wn * 2 + j][lane * 8];
#pragma unroll
        for (int i = 0; i < 4; ++i)
#pragma unroll
            for (int j = 0; j < 2; ++j)
                acc[i][j] = __builtin_amdgcn_mfma_f32_16x16x32_bf16(af[i], bf[j], acc[i][j], 0, 0, 0);
    }
}

// ---------------- k_gemm3: fused qall + kv + kpos (all independent, one launch) ----------------
// blocks [0,1024): qall (32x32); [1024,1152): kv (32x4); [1152,1184): kpos (16x2).
__global__ __launch_bounds__(256) void k_gemm3(const unsigned short* __restrict__ afrag,
                                               const unsigned short* __restrict__ bfragq,
                                               const unsigned short* __restrict__ attfrag,
                                               const unsigned short* __restrict__ bfragkv,
                                               const unsigned short* __restrict__ pefrag,
                                               const unsigned short* __restrict__ bfragp,
                                               const float* __restrict__ scale,
                                               unsigned short* __restrict__ qall,
                                               unsigned short* __restrict__ kfragg,
                                               unsigned short* __restrict__ vfragg,
                                               unsigned short* __restrict__ kposfg) {
    __shared__ __align__(16) unsigned short aT[8][512], bT[4][512];
    floatx4 acc[4][2];
#pragma unroll
    for (int i = 0; i < 4; ++i) { acc[i][0] = (floatx4){0,0,0,0}; acc[i][1] = (floatx4){0,0,0,0}; }
    const int bx = blockIdx.x;
    const int t = threadIdx.x, w = t >> 6, lane = t & 63;
    const int wm = w >> 1, wn = w & 1, lq = lane >> 4, lm = lane & 15;
    const float sc = sqrtf(scale[0]);

    if (bx < 1024) {
        const int gx = bx & 31, gy = bx >> 5;
        gemm_core64(afrag, bfragq, gx * 8, gy * 4, 32, aT, bT, acc);
#pragma unroll
        for (int i = 0; i < 4; ++i)
#pragma unroll
            for (int j = 0; j < 2; ++j)
#pragma unroll
                for (int r = 0; r < 4; ++r)
                    qall[(size_t)(gx * 128 + (wm * 4 + i) * 16 + lq * 4 + r) * 2048 +
                         gy * 64 + (wn * 2 + j) * 16 + lm] = f2bf(acc[i][j][r] * sc);
    } else if (bx < 1152) {
        const int q = bx - 1024;
        const int gx = q & 31, gy = q >> 5;
        gemm_core64(attfrag, bfragkv, gx * 8, gy * 4, 32, aT, bT, acc);
#pragma unroll
        for (int i = 0; i < 4; ++i)
#pragma unroll
            for (int j = 0; j < 2; ++j) {
                const int n = gy * 64 + (wn * 2 + j) * 16 + lm;
#pragma unroll
                for (int r = 0; r < 4; ++r) {
                    const int tok = gx * 128 + (wm * 4 + i) * 16 + lq * 4 + r;
                    const int bb = tok >> 10, jj = tok & 1023;
                    if (n < 128) {
                        const int p = n;
                        const size_t addr = ((((size_t)bb * 64 + (jj >> 4)) * 4 + (p >> 5)) * 64 +
                                             ((p & 31) >> 3) * 16 + (jj & 15)) * 8 + (p & 7);
                        kfragg[addr] = f2bf(acc[i][j][r] * sc);
                    } else {
                        const int p = n - 128;
                        const size_t addr = ((((size_t)bb * 32 + (jj >> 5)) * 8 + (p >> 4)) * 64 +
                                             ((jj & 31) >> 3) * 16 + (p & 15)) * 8 + (jj & 7);
                        vfragg[addr] = f2bf(acc[i][j][r]);
                    }
                }
            }
    } else {
        const int q = bx - 1152;
        const int gx = q & 15, gy = q >> 4;
        gemm_core64(pefrag, bfragp, gx * 8, gy * 4, 32, aT, bT, acc);
#pragma unroll
        for (int i = 0; i < 4; ++i)
#pragma unroll
            for (int j = 0; j < 2; ++j) {
                const int p = gy * 64 + (wn * 2 + j) * 16 + lm;
#pragma unroll
                for (int r = 0; r < 4; ++r) {
                    const int tp = gx * 128 + (wm * 4 + i) * 16 + lq * 4 + r;
                    const size_t addr = (((size_t)(tp >> 4) * 4 + (p >> 5)) * 64 +
                                         ((p & 31) >> 3) * 16 + (tp & 15)) * 8 + (p & 7);
                    kposfg[addr] = f2bf(acc[i][j][r] * sc);
                }
            }
    }
}

// ---------------- GEMM: out = zfrag @ w_out -> f32 row-major 4096x1024 ----------------
__global__ __launch_bounds__(256) void k_gemm_out(const unsigned short* __restrict__ Afrag,
                                                  const unsigned short* __restrict__ Bfrag,
                                                  float* __restrict__ out) {
    __shared__ __align__(16) unsigned short aT[8][512], bT[4][512];
    floatx4 acc[4][2];
#pragma unroll
    for (int i = 0; i < 4; ++i) { acc[i][0] = (floatx4){0,0,0,0}; acc[i][1] = (floatx4){0,0,0,0}; }
    gemm_core64(Afrag, Bfrag, blockIdx.x * 8, blockIdx.y * 4, 64, aT, bT, acc);
    const int t = threadIdx.x, w = t >> 6, lane = t & 63;
    const int wm = w >> 1, wn = w & 1, lq = lane >> 4, lm = lane & 15;
#pragma unroll
    for (int i = 0; i < 4; ++i)
#pragma unroll
        for (int j = 0; j < 2; ++j)
#pragma unroll
            for (int r = 0; r < 4; ++r)
                out[(size_t)(blockIdx.x * 128 + (wm * 4 + i) * 16 + lq * 4 + r) * 1024 +
                    blockIdx.y * 64 + (wn * 2 + j) * 16 + lm] = acc[i][j][r];
}

// ---------------- k_attn R10: 2 q-tiles/wave (32 tokens), key-split 2x, single-buffer K/V ----------------
// grid 512 = 4b x 4hg x 32st2; block = 2 heads x 2 key-halves; each wave: 32 Q-rows vs 512 keys.
// Doubles MFMA per staged step (25->50/wave) at identical K/V staging; 512 blocks = 2/CU, ONE batch.
// Pos windows of the two q-tiles differ by one 4KB tile -> 3 shared tile-loads/iter + per-qt sp-carry.
#define ATTN_FM 8.0f

__global__ __launch_bounds__(256, 2) void k_attn(const unsigned short* __restrict__ qall,
                                                 const unsigned short* __restrict__ kfragg,
                                                 const unsigned short* __restrict__ vfragg,
                                                 const unsigned short* __restrict__ kposfg,
                                                 const int* __restrict__ selidx,
                                                 const float* __restrict__ selval,
                                                 unsigned short* __restrict__ zfrag) {
    __shared__ __align__(16) union {
        struct {
            unsigned short pl[4][2][16][56];   // 14336 B: per-wave, per-qt P staging
            unsigned short kst[2][8][512];     // 16384 B [ws][q] single-buffered K
            unsigned short vst[2][8][512];     // 16384 B [ws][q] single-buffered V
        } s;
        float cmb[2][2][64][37];               // 37888 B [wh][qt][lane][.] (37: pad)
    } sh;                                      // 47104 B

    const int t = threadIdx.x;
    const int w = t >> 6, lane = t & 63;
    const int st2 = blockIdx.x & 31;
    const int hg = (blockIdx.x >> 5) & 3;
    const int b = blockIdx.x >> 7;
    const int wh = w & 1;                       // head within pair
    const int ws = w >> 1;                      // key-split half
    const int h = hg * 2 + wh;
    const int s0 = st2 * 32;
    const int lq = lane >> 4;
    const int lm = lane & 15;
    const int loff = lane * 16;

    short8 qf[2][4];
#pragma unroll
    for (int qt = 0; qt < 2; ++qt) {
        const int token = b * 1024 + s0 + qt * 16 + lm;
        const int e = selidx[token * 8 + h];
        const unsigned short* qb = qall + (size_t)token * 2048 + e * 128 + lq * 8;
#pragma unroll
        for (int c = 0; c < 4; ++c) qf[qt][c] = *(const short8*)(qb + c * 32);
    }
    short8 onesf;
#pragma unroll
    for (int i = 0; i < 8; ++i) onesf[i] = (short)0x3F80;

    int baddr[4], bsel[4];
#pragma unroll
    for (int r = 0; r < 4; ++r) {
        const int c0 = 15 + lm - (lq * 4 + r);
        baddr[r] = (lq * 16 + (c0 & 15)) * 4;
        bsel[r] = (c0 < 16) ? 1 : 0;
    }

    floatx4 acc[2][8], accl[2];
#pragma unroll
    for (int qt = 0; qt < 2; ++qt) {
#pragma unroll
        for (int nt = 0; nt < 8; ++nt) acc[qt][nt] = (floatx4){0.f, 0.f, 0.f, 0.f};
        accl[qt] = (floatx4){0.f, 0.f, 0.f, 0.f};
    }

    const size_t koff = (size_t)ws * 131072;
    const char* pk = (const char*)kfragg + (size_t)b * 262144 + koff;
    const char* pv = (const char*)vfragg + (size_t)b * 262144 + koff;
    // qt0 window base tile = 63 - 2*st2; qt1 base = one tile lower (pp - 4096).
    const char* pp = (const char*)kposfg + (size_t)(63 - 2 * st2) * 4096 + koff;

    // prologue: fold each qt's first cry tile into its sp-carry
    floatx4 spc[2] = {{0.f,0.f,0.f,0.f},{0.f,0.f,0.f,0.f}};
    {
#pragma unroll
        for (int c = 0; c < 4; ++c) {
            const short8 c0 = *(const short8*)(pp + c * 1024 + loff);
            const short8 c1 = *(const short8*)(pp - 4096 + c * 1024 + loff);
            spc[0] = __builtin_amdgcn_mfma_f32_16x16x32_bf16(qf[0][c], c0, spc[0], 0, 0, 0);
            spc[1] = __builtin_amdgcn_mfma_f32_16x16x32_bf16(qf[1][c], c1, spc[1], 0, 0, 0);
        }
    }

    unsigned short* plw[2] = { &sh.s.pl[w][0][0][0], &sh.s.pl[w][1][0][0] };

    for (int it = 0; it < 16; ++it) {
        __syncthreads();                       // A: prior iter's kst/vst reads complete
        if (wh == 0) {
#pragma unroll
            for (int q = 0; q < 8; ++q)
                gload16(pk + q * 1024 + loff, &sh.s.kst[ws][q][0]);
        } else {
#pragma unroll
            for (int q = 0; q < 8; ++q)
                gload16(pv + q * 1024 + loff, &sh.s.vst[ws][q][0]);
        }
        // pos tiles: ta=pp+0 (qt1 n1), tb=pp+4096 (qt0 n1 / qt1 n2), tc=pp+8192 (qt0 n2)
        floatx4 sp1[2] = {{0.f,0.f,0.f,0.f},{0.f,0.f,0.f,0.f}};
        floatx4 sp2[2] = {{0.f,0.f,0.f,0.f},{0.f,0.f,0.f,0.f}};
#pragma unroll
        for (int c = 0; c < 4; ++c) {
            const short8 ta = *(const short8*)(pp + c * 1024 + loff);
            const short8 tb = *(const short8*)(pp + 4096 + c * 1024 + loff);
            const short8 tc = *(const short8*)(pp + 8192 + c * 1024 + loff);
            sp1[0] = __builtin_amdgcn_mfma_f32_16x16x32_bf16(qf[0][c], tb, sp1[0], 0, 0, 0);
            sp2[0] = __builtin_amdgcn_mfma_f32_16x16x32_bf16(qf[0][c], tc, sp2[0], 0, 0, 0);
            sp1[1] = __builtin_amdgcn_mfma_f32_16x16x32_bf16(qf[1][c], ta, sp1[1], 0, 0, 0);
            sp2[1] = __builtin_amdgcn_mfma_f32_16x16x32_bf16(qf[1][c], tb, sp2[1], 0, 0, 0);
        }
        __syncthreads();                       // B: kst/vst staged (vmcnt drain)
        floatx4 sk0[2] = {{0.f,0.f,0.f,0.f},{0.f,0.f,0.f,0.f}};
        floatx4 sk1[2] = {{0.f,0.f,0.f,0.f},{0.f,0.f,0.f,0.f}};
#pragma unroll
        for (int c = 0; c < 4; ++c) {
            const short8 k0 = *(const short8*)&sh.s.kst[ws][c][lane * 8];
            const short8 k1 = *(const short8*)&sh.s.kst[ws][4 + c][lane * 8];
            sk0[0] = __builtin_amdgcn_mfma_f32_16x16x32_bf16(qf[0][c], k0, sk0[0], 0, 0, 0);
            sk1[0] = __builtin_amdgcn_mfma_f32_16x16x32_bf16(qf[0][c], k1, sk1[0], 0, 0, 0);
            sk0[1] = __builtin_amdgcn_mfma_f32_16x16x32_bf16(qf[1][c], k0, sk0[1], 0, 0, 0);
            sk1[1] = __builtin_amdgcn_mfma_f32_16x16x32_bf16(qf[1][c], k1, sk1[1], 0, 0, 0);
        }
#pragma unroll
        for (int qt = 0; qt < 2; ++qt) {
            unsigned short* pl = plw[qt];
#pragma unroll
            for (int r = 0; r < 4; ++r) {
                const int a = baddr[r];
                const float b0 = __int_as_float(__builtin_amdgcn_ds_bpermute(a, __float_as_int(spc[qt][r])));
                const float b1 = __int_as_float(__builtin_amdgcn_ds_bpermute(a, __float_as_int(sp1[qt][r])));
                const float b2 = __int_as_float(__builtin_amdgcn_ds_bpermute(a, __float_as_int(sp2[qt][r])));
                const float v0 = sk0[qt][r] + (bsel[r] ? b0 : b1);
                const float v1 = sk1[qt][r] + (bsel[r] ? b1 : b2);
                pl[(lq * 4 + r) * 56 + lm]      = f2bf(__expf(v0 - ATTN_FM));
                pl[(lq * 4 + r) * 56 + 16 + lm] = f2bf(__expf(v1 - ATTN_FM));
            }
        }
        asm volatile("" ::: "memory");
        const short8 pf0 = *(const short8*)(plw[0] + lm * 56 + lq * 8);
        const short8 pf1 = *(const short8*)(plw[1] + lm * 56 + lq * 8);
#pragma unroll
        for (int nt = 0; nt < 8; ++nt) {
            const short8 vf = *(const short8*)&sh.s.vst[ws][nt][lane * 8];
            acc[0][nt] = __builtin_amdgcn_mfma_f32_16x16x32_bf16(pf0, vf, acc[0][nt], 0, 0, 0);
            acc[1][nt] = __builtin_amdgcn_mfma_f32_16x16x32_bf16(pf1, vf, acc[1][nt], 0, 0, 0);
        }
        accl[0] = __builtin_amdgcn_mfma_f32_16x16x32_bf16(pf0, onesf, accl[0], 0, 0, 0);
        accl[1] = __builtin_amdgcn_mfma_f32_16x16x32_bf16(pf1, onesf, accl[1], 0, 0, 0);
        spc[0] = sp2[0]; spc[1] = sp2[1];
        pk += 8192; pv += 8192; pp += 8192;
    }

    // ---- combine the two key-halves through LDS (fixed-max softmax => partials additive) ----
    __syncthreads();
    if (ws == 1) {
#pragma unroll
        for (int qt = 0; qt < 2; ++qt) {
            float* cb = &sh.cmb[wh][qt][lane][0];
#pragma unroll
            for (int nt = 0; nt < 8; ++nt)
#pragma unroll
                for (int r = 0; r < 4; ++r) cb[nt * 4 + r] = acc[qt][nt][r];
#pragma unroll
            for (int r = 0; r < 4; ++r) cb[32 + r] = accl[qt][r];
        }
    }
    __syncthreads();
    if (ws == 1) return;
#pragma unroll
    for (int qt = 0; qt < 2; ++qt) {
        const float* cb = &sh.cmb[wh][qt][lane][0];
#pragma unroll
        for (int nt = 0; nt < 8; ++nt)
#pragma unroll
            for (int r = 0; r < 4; ++r) acc[qt][nt][r] += cb[nt * 4 + r];
#pragma unroll
        for (int r = 0; r < 4; ++r) accl[qt][r] += cb[32 + r];
    }

#pragma unroll
    for (int qt = 0; qt < 2; ++qt)
#pragma unroll
        for (int r = 0; r < 4; ++r) {
            const int tok = b * 1024 + s0 + qt * 16 + lq * 4 + r;
            const int e = selidx[tok * 8 + h];
            const float g = selval[tok * 8 + h] / accl[qt][r];
            const int mt = tok >> 4, tm = tok & 15;
#pragma unroll
            for (int nt = 0; nt < 8; ++nt) {
                const int k = e * 128 + nt * 16 + lm;
                const int kc = k >> 5;
                const int lane2 = (((k & 31) >> 3) << 4) + tm;
                zfrag[(((size_t)mt * 64 + kc) * 64 + lane2) * 8 + (k & 7)] = f2bf(acc[qt][nt][r] * g);
            }
        }
}

extern "C" void kernel_launch(void* const* d_in, const int* in_sizes, int n_in,
                              void* d_out, int out_size, void* d_ws, size_t ws_size,
                              hipStream_t stream) {
    const float* curr    = (const float*)d_in[0];  // (4,1024,1024)
    const float* attend  = (const float*)d_in[1];  // (4,1024,1024)
    const float* w_q     = (const float*)d_in[2];  // (16,1024,128)
    const float* w_kv    = (const float*)d_in[3];  // (1024,256)
    const float* w_out   = (const float*)d_in[4];  // (16,128,1024)
    const float* pos_pk  = (const float*)d_in[5];  // (128,1024)
    const float* sel_dst = (const float*)d_in[6];  // (16,1024)
    const float* scale   = (const float*)d_in[7];  // (1,)
    float* out = (float*)d_out;

    char* ws = (char*)d_ws;
    float* selval = (float*)ws;                                        // 128 KB
    int*   selidx = (int*)(ws + 131072);                               // 128 KB
    unsigned short* kposfg  = (unsigned short*)(ws + 262144);          // 512 KB
    unsigned short* kfragg  = (unsigned short*)(ws + 786432);          // 1 MB
    unsigned short* vfragg  = (unsigned short*)(ws + 1835008);         // 1 MB
    unsigned short* bfragq  = (unsigned short*)(ws + 2883584);         // 4 MB
    unsigned short* bfragw  = (unsigned short*)(ws + 7077888);         // 4 MB
    unsigned short* bfragkv = (unsigned short*)(ws + 11272192);        // 512 KB
    unsigned short* afrag   = (unsigned short*)(ws + 11796480);        // 8 MB (curr A-frag)
    unsigned short* qall    = (unsigned short*)(ws + 20185088);        // 16 MB
    unsigned short* zfrag   = (unsigned short*)(ws + 36962304);        // 16 MB
    // Aliases inside zfrag (all fully consumed by k_gemm3 BEFORE zfrag's memset):
    //   pefrag  = zfrag[0 .. 4MB)       (pe A-frag)
    //   bfragp  = zfrag[4MB .. 4.25MB)  (pos_pk B-frag)
    //   attfrag = zfrag[8MB .. 16MB)    (attend A-frag)
    unsigned short* pefrag  = zfrag;                                   // 4 MB
    unsigned short* bfragp  = zfrag + 2097152;                         // 256 KB
    unsigned short* attfrag = zfrag + 4194304;                         // 8 MB
    // total ~51.3 MB

    k_prep<<<18816, 256, 0, stream>>>(curr, attend, w_q, w_out, w_kv, pos_pk, sel_dst,
                                      selval, selidx, afrag, attfrag,
                                      bfragq, bfragw, bfragkv, bfragp, pefrag);
    k_gemm3<<<1184, 256, 0, stream>>>(afrag, bfragq, attfrag, bfragkv, pefrag, bfragp,
                                      scale, qall, kfragg, vfragg, kposfg);
    hipMemsetAsync(zfrag, 0, (size_t)16777216, stream);
    k_attn<<<512, 256, 0, stream>>>(qall, kfragg, vfragg, kposfg, selidx, selval, zfrag);
    k_gemm_out<<<dim3(32, 16), 256, 0, stream>>>(zfrag, bfragw, out);
}

// Round 11
// 241.274 us; speedup vs baseline: 1.2963x; 1.0753x over previous
//
#include <hip/hip_runtime.h>
#include <math.h>

// B=4 S=1024 D=1024 P=128 H=8 E=16, NT=4096, TPOS=2047

typedef __attribute__((ext_vector_type(8))) short short8;
typedef __attribute__((ext_vector_type(4))) float floatx4;

__device__ __forceinline__ float bf2f(unsigned int u) {
    union { unsigned int i; float f; } x; x.i = (u & 0xffffu) << 16; return x.f;
}
__device__ __forceinline__ unsigned short f2bf(float f) {
    union { float f; unsigned int i; } x; x.f = f;
    unsigned int r = x.i + 0x7fffu + ((x.i >> 16) & 1u);
    return (unsigned short)(r >> 16);
}

// async global->LDS: per-lane global addr, wave-uniform LDS base; lane data at base + lane*16
__device__ __forceinline__ void gload16(const void* g, void* l) {
    __builtin_amdgcn_global_load_lds(
        (const __attribute__((address_space(1))) unsigned int*)(uintptr_t)g,
        (__attribute__((address_space(3))) unsigned int*)(uintptr_t)l,
        16, 0, 0);
}

// Fragment layouts (16x16x32 bf16 MFMA), HW-verified R2-R6:
//   A-frag (MxK):  afrag[m>>4][k>>5][((k&31)>>3)*16 + (m&15)][k&7]
//   B-frag (KxN):  bfrag[n>>4][k>>5][((k&31)>>3)*16 + (n&15)][k&7]
//   C/D:           col = lane&15, row = (lane>>4)*4 + reg
// R9 dense-write converters: u-bits [0]=half(j>>2), [1:4]=n/m low, [5:6]=k-octet, [7:..]=kc, nt/mt.

// ---------------- k_prep R11: sel first (batched dot + wave-parallel top-8) + dense converters ----------------
// [0,4096): sel; [4096,6144): w_q; [6144,8192): w_out; [8192,8448): w_kv; [8448,8576): pos_pk;
// [8576,10624): pe; [10624,14720): curr->afrag; [14720,18816): attend->attfrag.
__global__ __launch_bounds__(256) void k_prep(const float* __restrict__ curr,
                                              const float* __restrict__ attend,
                                              const float* __restrict__ w_q,
                                              const float* __restrict__ w_out,
                                              const float* __restrict__ w_kv,
                                              const float* __restrict__ pos_pk,
                                              const float* __restrict__ sel_dst,
                                              float* __restrict__ selval,
                                              int* __restrict__ selidx,
                                              unsigned short* __restrict__ afrag,
                                              unsigned short* __restrict__ attfrag,
                                              unsigned short* __restrict__ bfragq,
                                              unsigned short* __restrict__ bfragw,
                                              unsigned short* __restrict__ bfragkv,
                                              unsigned short* __restrict__ bfragp,
                                              unsigned short* __restrict__ pefrag) {
    __shared__ float row[1024];
    __shared__ float sel[16];
    const int bx = blockIdx.x;
    const int t = threadIdx.x;

    if (bx < 4096) {
        // ---- sel: batched-load dot product + wave-parallel top-8 ----
        const int token = bx;
        const float4 v4 = ((const float4*)(curr + (size_t)token * 1024))[t];
        ((float4*)row)[t] = v4;
        __syncthreads();
        const int wv = t >> 6, lane = t & 63;
        for (int e0 = 0; e0 < 4; ++e0) {
            const int e = wv * 4 + e0;
            const float* wp = sel_dst + e * 1024;
            float p = 0.f;
#pragma unroll
            for (int i = 0; i < 16; ++i) p += row[lane + i * 64] * wp[lane + i * 64];
#pragma unroll
            for (int off = 32; off; off >>= 1) p += __shfl_down(p, off, 64);
            if (lane == 0) sel[e] = p;
        }
        __syncthreads();
        if (t < 64) {
            float v = (t < 16) ? sel[t] : -INFINITY;
#pragma unroll
            for (int r = 0; r < 8; ++r) {
                float mv = v; int mi = t;
#pragma unroll
                for (int off = 8; off; off >>= 1) {
                    const float ov = __shfl_xor(mv, off, 64);
                    const int oi = __shfl_xor(mi, off, 64);
                    if (ov > mv || (ov == mv && oi < mi)) { mv = ov; mi = oi; }
                }
                if (t == 0) {
                    selidx[token * 8 + r] = mi;
                    selval[token * 8 + r] = 1.f / (1.f + __expf(-mv));
                }
                if (t == mi) v = -INFINITY;
            }
        }
    } else if (bx < 6144) {
        // ---- w_q -> bfragq (B-frag KC=32, N=2048): dense writes ----
        const unsigned u = (unsigned)(bx - 4096) * 256 + t;
        const int half = u & 1;
        const int nlow = (u >> 1) & 15;
        const int koct = (u >> 5) & 3;
        const int kc   = (u >> 7) & 31;
        const int nt   = (u >> 12) & 127;
        const int n = nt * 16 + nlow;
        const int e = n >> 7, p = n & 127;
        const int k0 = kc * 32 + koct * 8 + half * 4;
        const float* src = w_q + (size_t)e * 131072 + (size_t)k0 * 128 + p;
        uint2 o;
        o.x = (unsigned)f2bf(src[0])   | ((unsigned)f2bf(src[128]) << 16);
        o.y = (unsigned)f2bf(src[256]) | ((unsigned)f2bf(src[384]) << 16);
        const size_t chunk = ((size_t)nt * 32 + kc) * 64 + koct * 16 + nlow;
        *(uint2*)(bfragq + chunk * 8 + half * 4) = o;
    } else if (bx < 8192) {
        // ---- w_out -> bfragw (B-frag KC=64, N=1024): dense writes ----
        const unsigned u = (unsigned)(bx - 6144) * 256 + t;
        const int half = u & 1;
        const int nlow = (u >> 1) & 15;
        const int koct = (u >> 5) & 3;
        const int kc   = (u >> 7) & 63;
        const int nt   = (u >> 13) & 63;
        const int n = nt * 16 + nlow;
        const int k0 = kc * 32 + koct * 8 + half * 4;
        const float* src = w_out + (size_t)k0 * 1024 + n;
        uint2 o;
        o.x = (unsigned)f2bf(src[0])    | ((unsigned)f2bf(src[1024]) << 16);
        o.y = (unsigned)f2bf(src[2048]) | ((unsigned)f2bf(src[3072]) << 16);
        const size_t chunk = ((size_t)nt * 64 + kc) * 64 + koct * 16 + nlow;
        *(uint2*)(bfragw + chunk * 8 + half * 4) = o;
    } else if (bx < 8448) {
        // ---- w_kv -> bfragkv (B-frag KC=32, N=256): dense writes ----
        const unsigned u = (unsigned)(bx - 8192) * 256 + t;
        const int half = u & 1;
        const int nlow = (u >> 1) & 15;
        const int koct = (u >> 5) & 3;
        const int kc   = (u >> 7) & 31;
        const int nt   = (u >> 12) & 15;
        const int n = nt * 16 + nlow;
        const int k0 = kc * 32 + koct * 8 + half * 4;
        const float* src = w_kv + (size_t)k0 * 256 + n;
        uint2 o;
        o.x = (unsigned)f2bf(src[0])   | ((unsigned)f2bf(src[256]) << 16);
        o.y = (unsigned)f2bf(src[512]) | ((unsigned)f2bf(src[768]) << 16);
        const size_t chunk = ((size_t)nt * 32 + kc) * 64 + koct * 16 + nlow;
        *(uint2*)(bfragkv + chunk * 8 + half * 4) = o;
    } else if (bx < 8576) {
        // ---- pos_pk -> bfragp (small; original mapping, coalesced row reads) ----
        const int n = bx - 8448;
        float v[4];
#pragma unroll
        for (int d = 0; d < 4; ++d) v[d] = pos_pk[(size_t)n * 1024 + 4 * t + d];
        const int nt = n >> 4, kc = t >> 3;
        const int lane = ((t & 7) >> 1) * 16 + (n & 15);
        const size_t off = (((size_t)nt * 32 + kc) * 64 + lane) * 8 + 4 * (t & 1);
        uint2 o;
        o.x = (unsigned)f2bf(v[0]) | ((unsigned)f2bf(v[1]) << 16);
        o.y = (unsigned)f2bf(v[2]) | ((unsigned)f2bf(v[3]) << 16);
        *(uint2*)(bfragp + off) = o;
    } else if (bx < 10624) {
        // ---- pe -> pefrag (A-frag, 2048 rows, row 2047 = 0): dense writes ----
        const unsigned u = (unsigned)(bx - 8576) * 256 + t;
        const int half = u & 1;
        const int mlow = (u >> 1) & 15;
        const int koct = (u >> 5) & 3;
        const int kc   = (u >> 7) & 31;
        const int mt   = (u >> 12) & 127;
        const int m = mt * 16 + mlow;
        const int k0 = kc * 32 + koct * 8 + half * 4;
        uint2 o;
        if (m >= 2047) {
            o.x = 0u; o.y = 0u;
        } else {
            const float c1 = -logf(10000.f) / 1024.f;
            const float pos = (float)(m - 1023);
            const float a0 = pos * expf((float)k0 * c1);
            const float a1 = pos * expf((float)(k0 + 2) * c1);
            o.x = (unsigned)f2bf(sinf(a0)) | ((unsigned)f2bf(cosf(a0)) << 16);
            o.y = (unsigned)f2bf(sinf(a1)) | ((unsigned)f2bf(cosf(a1)) << 16);
        }
        const size_t chunk = ((size_t)mt * 32 + kc) * 64 + koct * 16 + mlow;
        *(uint2*)(pefrag + chunk * 8 + half * 4) = o;
    } else if (bx < 14720) {
        // ---- curr -> afrag (A-frag, 4096 rows): dense writes, full-line float4 reads ----
        const unsigned u = (unsigned)(bx - 10624) * 256 + t;
        const int half = u & 1;
        const int mlow = (u >> 1) & 15;
        const int koct = (u >> 5) & 3;
        const int kc   = (u >> 7) & 31;
        const int mt   = (u >> 12) & 255;
        const int m = mt * 16 + mlow;
        const int k0 = kc * 32 + koct * 8 + half * 4;
        const float4 v = *(const float4*)(curr + (size_t)m * 1024 + k0);
        uint2 o;
        o.x = (unsigned)f2bf(v.x) | ((unsigned)f2bf(v.y) << 16);
        o.y = (unsigned)f2bf(v.z) | ((unsigned)f2bf(v.w) << 16);
        const size_t chunk = ((size_t)mt * 32 + kc) * 64 + koct * 16 + mlow;
        *(uint2*)(afrag + chunk * 8 + half * 4) = o;
    } else {
        // ---- attend -> attfrag (A-frag, 4096 rows): dense writes ----
        const unsigned u = (unsigned)(bx - 14720) * 256 + t;
        const int half = u & 1;
        const int mlow = (u >> 1) & 15;
        const int koct = (u >> 5) & 3;
        const int kc   = (u >> 7) & 31;
        const int mt   = (u >> 12) & 255;
        const int m = mt * 16 + mlow;
        const int k0 = kc * 32 + koct * 8 + half * 4;
        const float4 v = *(const float4*)(attend + (size_t)m * 1024 + k0);
        uint2 o;
        o.x = (unsigned)f2bf(v.x) | ((unsigned)f2bf(v.y) << 16);
        o.y = (unsigned)f2bf(v.z) | ((unsigned)f2bf(v.w) << 16);
        const size_t chunk = ((size_t)mt * 32 + kc) * 64 + koct * 16 + mlow;
        *(uint2*)(attfrag + chunk * 8 + half * 4) = o;
    }
}

// ---------------- MFMA GEMM core: 128x64 tile, 4 waves, frag-ordered global in ----------------
__device__ __forceinline__ void gemm_core64(const unsigned short* __restrict__ Afrag,
                                            const unsigned short* __restrict__ Bfrag,
                                            int mt0, int nt0, int KC,
                                            unsigned short (*aT)[512],
                                            unsigned short (*bT)[512],
                                            floatx4 acc[4][2]) {
    const int t = threadIdx.x;
    const int w = t >> 6, lane = t & 63;
    const int wm = w >> 1, wn = w & 1;
    for (int kc = 0; kc < KC; ++kc) {
        __syncthreads();
        {
            const int fi = w * 3;
#pragma unroll
            for (int l = 0; l < 3; ++l) {
                const int f = fi + l;   // 0..11: 8 A-frags then 4 B-frags
                if (f < 8)
                    gload16(Afrag + (((size_t)(mt0 + f) * KC + kc) * 64 + lane) * 8, &aT[f][0]);
                else
                    gload16(Bfrag + (((size_t)(nt0 + f - 8) * KC + kc) * 64 + lane) * 8, &bT[f - 8][0]);
            }
        }
        __syncthreads();
        short8 af[4], bf[2];
#pragma unroll
        for (int i = 0; i < 4; ++i) af[i] = *(const short8*)&aT[wm * 4 + i][lane * 8];
#pragma unroll
        for (int j = 0; j < 2; ++j) bf[j] = *(const short8*)&bT[wn * 2 + j][lane * 8];
#pragma unroll
        for (int i = 0; i < 4; ++i)
#pragma unroll
            for (int j = 0; j < 2; ++j)
                acc[i][j] = __builtin_amdgcn_mfma_f32_16x16x32_bf16(af[i], bf[j], acc[i][j], 0, 0, 0);
    }
}

// ---------------- k_gemm3: fused qall + kv + kpos (all independent, one launch) ----------------
// blocks [0,1024): qall (32x32); [1024,1152): kv (32x4); [1152,1184): kpos (16x2).
__global__ __launch_bounds__(256) void k_gemm3(const unsigned short* __restrict__ afrag,
                                               const unsigned short* __restrict__ bfragq,
                                               const unsigned short* __restrict__ attfrag,
                                               const unsigned short* __restrict__ bfragkv,
                                               const unsigned short* __restrict__ pefrag,
                                               const unsigned short* __restrict__ bfragp,
                                               const float* __restrict__ scale,
                                               unsigned short* __restrict__ qall,
                                               unsigned short* __restrict__ kfragg,
                                               unsigned short* __restrict__ vfragg,
                                               unsigned short* __restrict__ kposfg) {
    __shared__ __align__(16) unsigned short aT[8][512], bT[4][512];
    floatx4 acc[4][2];
#pragma unroll
    for (int i = 0; i < 4; ++i) { acc[i][0] = (floatx4){0,0,0,0}; acc[i][1] = (floatx4){0,0,0,0}; }
    const int bx = blockIdx.x;
    const int t = threadIdx.x, w = t >> 6, lane = t & 63;
    const int wm = w >> 1, wn = w & 1, lq = lane >> 4, lm = lane & 15;
    const float sc = sqrtf(scale[0]);

    if (bx < 1024) {
        const int gx = bx & 31, gy = bx >> 5;
        gemm_core64(afrag, bfragq, gx * 8, gy * 4, 32, aT, bT, acc);
#pragma unroll
        for (int i = 0; i < 4; ++i)
#pragma unroll
            for (int j = 0; j < 2; ++j)
#pragma unroll
                for (int r = 0; r < 4; ++r)
                    qall[(size_t)(gx * 128 + (wm * 4 + i) * 16 + lq * 4 + r) * 2048 +
                         gy * 64 + (wn * 2 + j) * 16 + lm] = f2bf(acc[i][j][r] * sc);
    } else if (bx < 1152) {
        const int q = bx - 1024;
        const int gx = q & 31, gy = q >> 5;
        gemm_core64(attfrag, bfragkv, gx * 8, gy * 4, 32, aT, bT, acc);
#pragma unroll
        for (int i = 0; i < 4; ++i)
#pragma unroll
            for (int j = 0; j < 2; ++j) {
                const int n = gy * 64 + (wn * 2 + j) * 16 + lm;
#pragma unroll
                for (int r = 0; r < 4; ++r) {
                    const int tok = gx * 128 + (wm * 4 + i) * 16 + lq * 4 + r;
                    const int bb = tok >> 10, jj = tok & 1023;
                    if (n < 128) {
                        const int p = n;
                        const size_t addr = ((((size_t)bb * 64 + (jj >> 4)) * 4 + (p >> 5)) * 64 +
                                             ((p & 31) >> 3) * 16 + (jj & 15)) * 8 + (p & 7);
                        kfragg[addr] = f2bf(acc[i][j][r] * sc);
                    } else {
                        const int p = n - 128;
                        const size_t addr = ((((size_t)bb * 32 + (jj >> 5)) * 8 + (p >> 4)) * 64 +
                                             ((jj & 31) >> 3) * 16 + (p & 15)) * 8 + (jj & 7);
                        vfragg[addr] = f2bf(acc[i][j][r]);
                    }
                }
            }
    } else {
        const int q = bx - 1152;
        const int gx = q & 15, gy = q >> 4;
        gemm_core64(pefrag, bfragp, gx * 8, gy * 4, 32, aT, bT, acc);
#pragma unroll
        for (int i = 0; i < 4; ++i)
#pragma unroll
            for (int j = 0; j < 2; ++j) {
                const int p = gy * 64 + (wn * 2 + j) * 16 + lm;
#pragma unroll
                for (int r = 0; r < 4; ++r) {
                    const int tp = gx * 128 + (wm * 4 + i) * 16 + lq * 4 + r;
                    const size_t addr = (((size_t)(tp >> 4) * 4 + (p >> 5)) * 64 +
                                         ((p & 31) >> 3) * 16 + (tp & 15)) * 8 + (p & 7);
                    kposfg[addr] = f2bf(acc[i][j][r] * sc);
                }
            }
    }
}

// ---------------- GEMM: out = zfrag @ w_out -> f32 row-major 4096x1024 ----------------
__global__ __launch_bounds__(256) void k_gemm_out(const unsigned short* __restrict__ Afrag,
                                                  const unsigned short* __restrict__ Bfrag,
                                                  float* __restrict__ out) {
    __shared__ __align__(16) unsigned short aT[8][512], bT[4][512];
    floatx4 acc[4][2];
#pragma unroll
    for (int i = 0; i < 4; ++i) { acc[i][0] = (floatx4){0,0,0,0}; acc[i][1] = (floatx4){0,0,0,0}; }
    gemm_core64(Afrag, Bfrag, blockIdx.x * 8, blockIdx.y * 4, 64, aT, bT, acc);
    const int t = threadIdx.x, w = t >> 6, lane = t & 63;
    const int wm = w >> 1, wn = w & 1, lq = lane >> 4, lm = lane & 15;
#pragma unroll
    for (int i = 0; i < 4; ++i)
#pragma unroll
        for (int j = 0; j < 2; ++j)
#pragma unroll
            for (int r = 0; r < 4; ++r)
                out[(size_t)(blockIdx.x * 128 + (wm * 4 + i) * 16 + lq * 4 + r) * 1024 +
                    blockIdx.y * 64 + (wn * 2 + j) * 16 + lm] = acc[i][j][r];
}

// ---------------- k_attn (unchanged from R10): 2 q-tiles/wave, key-split 2x, single-buffer K/V ----------------
#define ATTN_FM 8.0f

__global__ __launch_bounds__(256, 2) void k_attn(const unsigned short* __restrict__ qall,
                                                 const unsigned short* __restrict__ kfragg,
                                                 const unsigned short* __restrict__ vfragg,
                                                 const unsigned short* __restrict__ kposfg,
                                                 const int* __restrict__ selidx,
                                                 const float* __restrict__ selval,
                                                 unsigned short* __restrict__ zfrag) {
    __shared__ __align__(16) union {
        struct {
            unsigned short pl[4][2][16][56];   // 14336 B: per-wave, per-qt P staging
            unsigned short kst[2][8][512];     // 16384 B [ws][q] single-buffered K
            unsigned short vst[2][8][512];     // 16384 B [ws][q] single-buffered V
        } s;
        float cmb[2][2][64][37];               // 37888 B [wh][qt][lane][.] (37: pad)
    } sh;                                      // 47104 B

    const int t = threadIdx.x;
    const int w = t >> 6, lane = t & 63;
    const int st2 = blockIdx.x & 31;
    const int hg = (blockIdx.x >> 5) & 3;
    const int b = blockIdx.x >> 7;
    const int wh = w & 1;                       // head within pair
    const int ws = w >> 1;                      // key-split half
    const int h = hg * 2 + wh;
    const int s0 = st2 * 32;
    const int lq = lane >> 4;
    const int lm = lane & 15;
    const int loff = lane * 16;

    short8 qf[2][4];
#pragma unroll
    for (int qt = 0; qt < 2; ++qt) {
        const int token = b * 1024 + s0 + qt * 16 + lm;
        const int e = selidx[token * 8 + h];
        const unsigned short* qb = qall + (size_t)token * 2048 + e * 128 + lq * 8;
#pragma unroll
        for (int c = 0; c < 4; ++c) qf[qt][c] = *(const short8*)(qb + c * 32);
    }
    short8 onesf;
#pragma unroll
    for (int i = 0; i < 8; ++i) onesf[i] = (short)0x3F80;

    int baddr[4], bsel[4];
#pragma unroll
    for (int r = 0; r < 4; ++r) {
        const int c0 = 15 + lm - (lq * 4 + r);
        baddr[r] = (lq * 16 + (c0 & 15)) * 4;
        bsel[r] = (c0 < 16) ? 1 : 0;
    }

    floatx4 acc[2][8], accl[2];
#pragma unroll
    for (int qt = 0; qt < 2; ++qt) {
#pragma unroll
        for (int nt = 0; nt < 8; ++nt) acc[qt][nt] = (floatx4){0.f, 0.f, 0.f, 0.f};
        accl[qt] = (floatx4){0.f, 0.f, 0.f, 0.f};
    }

    const size_t koff = (size_t)ws * 131072;
    const char* pk = (const char*)kfragg + (size_t)b * 262144 + koff;
    const char* pv = (const char*)vfragg + (size_t)b * 262144 + koff;
    // qt0 window base tile = 63 - 2*st2; qt1 base = one tile lower (pp - 4096).
    const char* pp = (const char*)kposfg + (size_t)(63 - 2 * st2) * 4096 + koff;

    // prologue: fold each qt's first cry tile into its sp-carry
    floatx4 spc[2] = {{0.f,0.f,0.f,0.f},{0.f,0.f,0.f,0.f}};
    {
#pragma unroll
        for (int c = 0; c < 4; ++c) {
            const short8 c0 = *(const short8*)(pp + c * 1024 + loff);
            const short8 c1 = *(const short8*)(pp - 4096 + c * 1024 + loff);
            spc[0] = __builtin_amdgcn_mfma_f32_16x16x32_bf16(qf[0][c], c0, spc[0], 0, 0, 0);
            spc[1] = __builtin_amdgcn_mfma_f32_16x16x32_bf16(qf[1][c], c1, spc[1], 0, 0, 0);
        }
    }

    unsigned short* plw[2] = { &sh.s.pl[w][0][0][0], &sh.s.pl[w][1][0][0] };

    for (int it = 0; it < 16; ++it) {
        __syncthreads();                       // A: prior iter's kst/vst reads complete
        if (wh == 0) {
#pragma unroll
            for (int q = 0; q < 8; ++q)
                gload16(pk + q * 1024 + loff, &sh.s.kst[ws][q][0]);
        } else {
#pragma unroll
            for (int q = 0; q < 8; ++q)
                gload16(pv + q * 1024 + loff, &sh.s.vst[ws][q][0]);
        }
        // pos tiles: ta=pp+0 (qt1 n1), tb=pp+4096 (qt0 n1 / qt1 n2), tc=pp+8192 (qt0 n2)
        floatx4 sp1[2] = {{0.f,0.f,0.f,0.f},{0.f,0.f,0.f,0.f}};
        floatx4 sp2[2] = {{0.f,0.f,0.f,0.f},{0.f,0.f,0.f,0.f}};
#pragma unroll
        for (int c = 0; c < 4; ++c) {
            const short8 ta = *(const short8*)(pp + c * 1024 + loff);
            const short8 tb = *(const short8*)(pp + 4096 + c * 1024 + loff);
            const short8 tc = *(const short8*)(pp + 8192 + c * 1024 + loff);
            sp1[0] = __builtin_amdgcn_mfma_f32_16x16x32_bf16(qf[0][c], tb, sp1[0], 0, 0, 0);
            sp2[0] = __builtin_amdgcn_mfma_f32_16x16x32_bf16(qf[0][c], tc, sp2[0], 0, 0, 0);
            sp1[1] = __builtin_amdgcn_mfma_f32_16x16x32_bf16(qf[1][c], ta, sp1[1], 0, 0, 0);
            sp2[1] = __builtin_amdgcn_mfma_f32_16x16x32_bf16(qf[1][c], tb, sp2[1], 0, 0, 0);
        }
        __syncthreads();                       // B: kst/vst staged (vmcnt drain)
        floatx4 sk0[2] = {{0.f,0.f,0.f,0.f},{0.f,0.f,0.f,0.f}};
        floatx4 sk1[2] = {{0.f,0.f,0.f,0.f},{0.f,0.f,0.f,0.f}};
#pragma unroll
        for (int c = 0; c < 4; ++c) {
            const short8 k0 = *(const short8*)&sh.s.kst[ws][c][lane * 8];
            const short8 k1 = *(const short8*)&sh.s.kst[ws][4 + c][lane * 8];
            sk0[0] = __builtin_amdgcn_mfma_f32_16x16x32_bf16(qf[0][c], k0, sk0[0], 0, 0, 0);
            sk1[0] = __builtin_amdgcn_mfma_f32_16x16x32_bf16(qf[0][c], k1, sk1[0], 0, 0, 0);
            sk0[1] = __builtin_amdgcn_mfma_f32_16x16x32_bf16(qf[1][c], k0, sk0[1], 0, 0, 0);
            sk1[1] = __builtin_amdgcn_mfma_f32_16x16x32_bf16(qf[1][c], k1, sk1[1], 0, 0, 0);
        }
#pragma unroll
        for (int qt = 0; qt < 2; ++qt) {
            unsigned short* pl = plw[qt];
#pragma unroll
            for (int r = 0; r < 4; ++r) {
                const int a = baddr[r];
                const float b0 = __int_as_float(__builtin_amdgcn_ds_bpermute(a, __float_as_int(spc[qt][r])));
                const float b1 = __int_as_float(__builtin_amdgcn_ds_bpermute(a, __float_as_int(sp1[qt][r])));
                const float b2 = __int_as_float(__builtin_amdgcn_ds_bpermute(a, __float_as_int(sp2[qt][r])));
                const float v0 = sk0[qt][r] + (bsel[r] ? b0 : b1);
                const float v1 = sk1[qt][r] + (bsel[r] ? b1 : b2);
                pl[(lq * 4 + r) * 56 + lm]      = f2bf(__expf(v0 - ATTN_FM));
                pl[(lq * 4 + r) * 56 + 16 + lm] = f2bf(__expf(v1 - ATTN_FM));
            }
        }
        asm volatile("" ::: "memory");
        const short8 pf0 = *(const short8*)(plw[0] + lm * 56 + lq * 8);
        const short8 pf1 = *(const short8*)(plw[1] + lm * 56 + lq * 8);
#pragma unroll
        for (int nt = 0; nt < 8; ++nt) {
            const short8 vf = *(const short8*)&sh.s.vst[ws][nt][lane * 8];
            acc[0][nt] = __builtin_amdgcn_mfma_f32_16x16x32_bf16(pf0, vf, acc[0][nt], 0, 0, 0);
            acc[1][nt] = __builtin_amdgcn_mfma_f32_16x16x32_bf16(pf1, vf, acc[1][nt], 0, 0, 0);
        }
        accl[0] = __builtin_amdgcn_mfma_f32_16x16x32_bf16(pf0, onesf, accl[0], 0, 0, 0);
        accl[1] = __builtin_amdgcn_mfma_f32_16x16x32_bf16(pf1, onesf, accl[1], 0, 0, 0);
        spc[0] = sp2[0]; spc[1] = sp2[1];
        pk += 8192; pv += 8192; pp += 8192;
    }

    // ---- combine the two key-halves through LDS (fixed-max softmax => partials additive) ----
    __syncthreads();
    if (ws == 1) {
#pragma unroll
        for (int qt = 0; qt < 2; ++qt) {
            float* cb = &sh.cmb[wh][qt][lane][0];
#pragma unroll
            for (int nt = 0; nt < 8; ++nt)
#pragma unroll
                for (int r = 0; r < 4; ++r) cb[nt * 4 + r] = acc[qt][nt][r];
#pragma unroll
            for (int r = 0; r < 4; ++r) cb[32 + r] = accl[qt][r];
        }
    }
    __syncthreads();
    if (ws == 1) return;
#pragma unroll
    for (int qt = 0; qt < 2; ++qt) {
        const float* cb = &sh.cmb[wh][qt][lane][0];
#pragma unroll
        for (int nt = 0; nt < 8; ++nt)
#pragma unroll
            for (int r = 0; r < 4; ++r) acc[qt][nt][r] += cb[nt * 4 + r];
#pragma unroll
        for (int r = 0; r < 4; ++r) accl[qt][r] += cb[32 + r];
    }

#pragma unroll
    for (int qt = 0; qt < 2; ++qt)
#pragma unroll
        for (int r = 0; r < 4; ++r) {
            const int tok = b * 1024 + s0 + qt * 16 + lq * 4 + r;
            const int e = selidx[tok * 8 + h];
            const float g = selval[tok * 8 + h] / accl[qt][r];
            const int mt = tok >> 4, tm = tok & 15;
#pragma unroll
            for (int nt = 0; nt < 8; ++nt) {
                const int k = e * 128 + nt * 16 + lm;
                const int kc = k >> 5;
                const int lane2 = (((k & 31) >> 3) << 4) + tm;
                zfrag[(((size_t)mt * 64 + kc) * 64 + lane2) * 8 + (k & 7)] = f2bf(acc[qt][nt][r] * g);
            }
        }
}

extern "C" void kernel_launch(void* const* d_in, const int* in_sizes, int n_in,
                              void* d_out, int out_size, void* d_ws, size_t ws_size,
                              hipStream_t stream) {
    const float* curr    = (const float*)d_in[0];  // (4,1024,1024)
    const float* attend  = (const float*)d_in[1];  // (4,1024,1024)
    const float* w_q     = (const float*)d_in[2];  // (16,1024,128)
    const float* w_kv    = (const float*)d_in[3];  // (1024,256)
    const float* w_out   = (const float*)d_in[4];  // (16,128,1024)
    const float* pos_pk  = (const float*)d_in[5];  // (128,1024)
    const float* sel_dst = (const float*)d_in[6];  // (16,1024)
    const float* scale   = (const float*)d_in[7];  // (1,)
    float* out = (float*)d_out;

    char* ws = (char*)d_ws;
    float* selval = (float*)ws;                                        // 128 KB
    int*   selidx = (int*)(ws + 131072);                               // 128 KB
    unsigned short* kposfg  = (unsigned short*)(ws + 262144);          // 512 KB
    unsigned short* kfragg  = (unsigned short*)(ws + 786432);          // 1 MB
    unsigned short* vfragg  = (unsigned short*)(ws + 1835008);         // 1 MB
    unsigned short* bfragq  = (unsigned short*)(ws + 2883584);         // 4 MB
    unsigned short* bfragw  = (unsigned short*)(ws + 7077888);         // 4 MB
    unsigned short* bfragkv = (unsigned short*)(ws + 11272192);        // 512 KB
    unsigned short* afrag   = (unsigned short*)(ws + 11796480);        // 8 MB (curr A-frag)
    unsigned short* qall    = (unsigned short*)(ws + 20185088);        // 16 MB
    unsigned short* zfrag   = (unsigned short*)(ws + 36962304);        // 16 MB
    // Aliases inside zfrag (all fully consumed by k_gemm3 BEFORE zfrag's memset):
    //   pefrag  = zfrag[0 .. 4MB)       (pe A-frag)
    //   bfragp  = zfrag[4MB .. 4.25MB)  (pos_pk B-frag)
    //   attfrag = zfrag[8MB .. 16MB)    (attend A-frag)
    unsigned short* pefrag  = zfrag;                                   // 4 MB
    unsigned short* bfragp  = zfrag + 2097152;                         // 256 KB
    unsigned short* attfrag = zfrag + 4194304;                         // 8 MB
    // total ~51.3 MB

    k_prep<<<18816, 256, 0, stream>>>(curr, attend, w_q, w_out, w_kv, pos_pk, sel_dst,
                                      selval, selidx, afrag, attfrag,
                                      bfragq, bfragw, bfragkv, bfragp, pefrag);
    k_gemm3<<<1184, 256, 0, stream>>>(afrag, bfragq, attfrag, bfragkv, pefrag, bfragp,
                                      scale, qall, kfragg, vfragg, kposfg);
    hipMemsetAsync(zfrag, 0, (size_t)16777216, stream);
    k_attn<<<512, 256, 0, stream>>>(qall, kfragg, vfragg, kposfg, selidx, selval, zfrag);
    k_gemm_out<<<dim3(32, 16), 256, 0, stream>>>(zfrag, bfragw, out);
}

// Round 12
// 238.996 us; speedup vs baseline: 1.3087x; 1.0095x over previous
//
#include <hip/hip_runtime.h>
#include <math.h>

// B=4 S=1024 D=1024 P=128 H=8 E=16, NT=4096, TPOS=2047

typedef __attribute__((ext_vector_type(8))) short short8;
typedef __attribute__((ext_vector_type(4))) float floatx4;

__device__ __forceinline__ float bf2f(unsigned int u) {
    union { unsigned int i; float f; } x; x.i = (u & 0xffffu) << 16; return x.f;
}
__device__ __forceinline__ unsigned short f2bf(float f) {
    union { float f; unsigned int i; } x; x.f = f;
    unsigned int r = x.i + 0x7fffu + ((x.i >> 16) & 1u);
    return (unsigned short)(r >> 16);
}

// async global->LDS: per-lane global addr, wave-uniform LDS base; lane data at base + lane*16
__device__ __forceinline__ void gload16(const void* g, void* l) {
    __builtin_amdgcn_global_load_lds(
        (const __attribute__((address_space(1))) unsigned int*)(uintptr_t)g,
        (__attribute__((address_space(3))) unsigned int*)(uintptr_t)l,
        16, 0, 0);
}

// Fragment layouts (16x16x32 bf16 MFMA), HW-verified R2-R6:
//   A-frag (MxK):  afrag[m>>4][k>>5][((k&31)>>3)*16 + (m&15)][k&7]
//   B-frag (KxN):  bfrag[n>>4][k>>5][((k&31)>>3)*16 + (n&15)][k&7]
//   C/D:           col = lane&15, row = (lane>>4)*4 + reg
// R9 dense-write converters: u-bits [0]=half(j>>2), [1:4]=n/m low, [5:6]=k-octet, [7:..]=kc, nt/mt.

// ---------------- k_prep R11: sel first (batched dot + wave-parallel top-8) + dense converters ----------------
// [0,4096): sel; [4096,6144): w_q; [6144,8192): w_out; [8192,8448): w_kv; [8448,8576): pos_pk;
// [8576,10624): pe; [10624,14720): curr->afrag; [14720,18816): attend->attfrag.
__global__ __launch_bounds__(256) void k_prep(const float* __restrict__ curr,
                                              const float* __restrict__ attend,
                                              const float* __restrict__ w_q,
                                              const float* __restrict__ w_out,
                                              const float* __restrict__ w_kv,
                                              const float* __restrict__ pos_pk,
                                              const float* __restrict__ sel_dst,
                                              float* __restrict__ selval,
                                              int* __restrict__ selidx,
                                              unsigned short* __restrict__ afrag,
                                              unsigned short* __restrict__ attfrag,
                                              unsigned short* __restrict__ bfragq,
                                              unsigned short* __restrict__ bfragw,
                                              unsigned short* __restrict__ bfragkv,
                                              unsigned short* __restrict__ bfragp,
                                              unsigned short* __restrict__ pefrag) {
    __shared__ float row[1024];
    __shared__ float sel[16];
    const int bx = blockIdx.x;
    const int t = threadIdx.x;

    if (bx < 4096) {
        // ---- sel: batched-load dot product + wave-parallel top-8 ----
        const int token = bx;
        const float4 v4 = ((const float4*)(curr + (size_t)token * 1024))[t];
        ((float4*)row)[t] = v4;
        __syncthreads();
        const int wv = t >> 6, lane = t & 63;
        for (int e0 = 0; e0 < 4; ++e0) {
            const int e = wv * 4 + e0;
            const float* wp = sel_dst + e * 1024;
            float p = 0.f;
#pragma unroll
            for (int i = 0; i < 16; ++i) p += row[lane + i * 64] * wp[lane + i * 64];
#pragma unroll
            for (int off = 32; off; off >>= 1) p += __shfl_down(p, off, 64);
            if (lane == 0) sel[e] = p;
        }
        __syncthreads();
        if (t < 64) {
            float v = (t < 16) ? sel[t] : -INFINITY;
#pragma unroll
            for (int r = 0; r < 8; ++r) {
                float mv = v; int mi = t;
#pragma unroll
                for (int off = 8; off; off >>= 1) {
                    const float ov = __shfl_xor(mv, off, 64);
                    const int oi = __shfl_xor(mi, off, 64);
                    if (ov > mv || (ov == mv && oi < mi)) { mv = ov; mi = oi; }
                }
                if (t == 0) {
                    selidx[token * 8 + r] = mi;
                    selval[token * 8 + r] = 1.f / (1.f + __expf(-mv));
                }
                if (t == mi) v = -INFINITY;
            }
        }
    } else if (bx < 6144) {
        // ---- w_q -> bfragq (B-frag KC=32, N=2048): dense writes ----
        const unsigned u = (unsigned)(bx - 4096) * 256 + t;
        const int half = u & 1;
        const int nlow = (u >> 1) & 15;
        const int koct = (u >> 5) & 3;
        const int kc   = (u >> 7) & 31;
        const int nt   = (u >> 12) & 127;
        const int n = nt * 16 + nlow;
        const int e = n >> 7, p = n & 127;
        const int k0 = kc * 32 + koct * 8 + half * 4;
        const float* src = w_q + (size_t)e * 131072 + (size_t)k0 * 128 + p;
        uint2 o;
        o.x = (unsigned)f2bf(src[0])   | ((unsigned)f2bf(src[128]) << 16);
        o.y = (unsigned)f2bf(src[256]) | ((unsigned)f2bf(src[384]) << 16);
        const size_t chunk = ((size_t)nt * 32 + kc) * 64 + koct * 16 + nlow;
        *(uint2*)(bfragq + chunk * 8 + half * 4) = o;
    } else if (bx < 8192) {
        // ---- w_out -> bfragw (B-frag KC=64, N=1024): dense writes ----
        const unsigned u = (unsigned)(bx - 6144) * 256 + t;
        const int half = u & 1;
        const int nlow = (u >> 1) & 15;
        const int koct = (u >> 5) & 3;
        const int kc   = (u >> 7) & 63;
        const int nt   = (u >> 13) & 63;
        const int n = nt * 16 + nlow;
        const int k0 = kc * 32 + koct * 8 + half * 4;
        const float* src = w_out + (size_t)k0 * 1024 + n;
        uint2 o;
        o.x = (unsigned)f2bf(src[0])    | ((unsigned)f2bf(src[1024]) << 16);
        o.y = (unsigned)f2bf(src[2048]) | ((unsigned)f2bf(src[3072]) << 16);
        const size_t chunk = ((size_t)nt * 64 + kc) * 64 + koct * 16 + nlow;
        *(uint2*)(bfragw + chunk * 8 + half * 4) = o;
    } else if (bx < 8448) {
        // ---- w_kv -> bfragkv (B-frag KC=32, N=256): dense writes ----
        const unsigned u = (unsigned)(bx - 8192) * 256 + t;
        const int half = u & 1;
        const int nlow = (u >> 1) & 15;
        const int koct = (u >> 5) & 3;
        const int kc   = (u >> 7) & 31;
        const int nt   = (u >> 12) & 15;
        const int n = nt * 16 + nlow;
        const int k0 = kc * 32 + koct * 8 + half * 4;
        const float* src = w_kv + (size_t)k0 * 256 + n;
        uint2 o;
        o.x = (unsigned)f2bf(src[0])   | ((unsigned)f2bf(src[256]) << 16);
        o.y = (unsigned)f2bf(src[512]) | ((unsigned)f2bf(src[768]) << 16);
        const size_t chunk = ((size_t)nt * 32 + kc) * 64 + koct * 16 + nlow;
        *(uint2*)(bfragkv + chunk * 8 + half * 4) = o;
    } else if (bx < 8576) {
        // ---- pos_pk -> bfragp (small; original mapping, coalesced row reads) ----
        const int n = bx - 8448;
        float v[4];
#pragma unroll
        for (int d = 0; d < 4; ++d) v[d] = pos_pk[(size_t)n * 1024 + 4 * t + d];
        const int nt = n >> 4, kc = t >> 3;
        const int lane = ((t & 7) >> 1) * 16 + (n & 15);
        const size_t off = (((size_t)nt * 32 + kc) * 64 + lane) * 8 + 4 * (t & 1);
        uint2 o;
        o.x = (unsigned)f2bf(v[0]) | ((unsigned)f2bf(v[1]) << 16);
        o.y = (unsigned)f2bf(v[2]) | ((unsigned)f2bf(v[3]) << 16);
        *(uint2*)(bfragp + off) = o;
    } else if (bx < 10624) {
        // ---- pe -> pefrag (A-frag, 2048 rows, row 2047 = 0): dense writes ----
        const unsigned u = (unsigned)(bx - 8576) * 256 + t;
        const int half = u & 1;
        const int mlow = (u >> 1) & 15;
        const int koct = (u >> 5) & 3;
        const int kc   = (u >> 7) & 31;
        const int mt   = (u >> 12) & 127;
        const int m = mt * 16 + mlow;
        const int k0 = kc * 32 + koct * 8 + half * 4;
        uint2 o;
        if (m >= 2047) {
            o.x = 0u; o.y = 0u;
        } else {
            const float c1 = -logf(10000.f) / 1024.f;
            const float pos = (float)(m - 1023);
            const float a0 = pos * expf((float)k0 * c1);
            const float a1 = pos * expf((float)(k0 + 2) * c1);
            o.x = (unsigned)f2bf(sinf(a0)) | ((unsigned)f2bf(cosf(a0)) << 16);
            o.y = (unsigned)f2bf(sinf(a1)) | ((unsigned)f2bf(cosf(a1)) << 16);
        }
        const size_t chunk = ((size_t)mt * 32 + kc) * 64 + koct * 16 + mlow;
        *(uint2*)(pefrag + chunk * 8 + half * 4) = o;
    } else if (bx < 14720) {
        // ---- curr -> afrag (A-frag, 4096 rows): dense writes, full-line float4 reads ----
        const unsigned u = (unsigned)(bx - 10624) * 256 + t;
        const int half = u & 1;
        const int mlow = (u >> 1) & 15;
        const int koct = (u >> 5) & 3;
        const int kc   = (u >> 7) & 31;
        const int mt   = (u >> 12) & 255;
        const int m = mt * 16 + mlow;
        const int k0 = kc * 32 + koct * 8 + half * 4;
        const float4 v = *(const float4*)(curr + (size_t)m * 1024 + k0);
        uint2 o;
        o.x = (unsigned)f2bf(v.x) | ((unsigned)f2bf(v.y) << 16);
        o.y = (unsigned)f2bf(v.z) | ((unsigned)f2bf(v.w) << 16);
        const size_t chunk = ((size_t)mt * 32 + kc) * 64 + koct * 16 + mlow;
        *(uint2*)(afrag + chunk * 8 + half * 4) = o;
    } else {
        // ---- attend -> attfrag (A-frag, 4096 rows): dense writes ----
        const unsigned u = (unsigned)(bx - 14720) * 256 + t;
        const int half = u & 1;
        const int mlow = (u >> 1) & 15;
        const int koct = (u >> 5) & 3;
        const int kc   = (u >> 7) & 31;
        const int mt   = (u >> 12) & 255;
        const int m = mt * 16 + mlow;
        const int k0 = kc * 32 + koct * 8 + half * 4;
        const float4 v = *(const float4*)(attend + (size_t)m * 1024 + k0);
        uint2 o;
        o.x = (unsigned)f2bf(v.x) | ((unsigned)f2bf(v.y) << 16);
        o.y = (unsigned)f2bf(v.z) | ((unsigned)f2bf(v.w) << 16);
        const size_t chunk = ((size_t)mt * 32 + kc) * 64 + koct * 16 + mlow;
        *(uint2*)(attfrag + chunk * 8 + half * 4) = o;
    }
}

// ---------------- MFMA GEMM core R12: 128x64 tile, BK=64 (2 K-slices per barrier round) ----------------
// Per round: 24 frag-chunks staged (16 A + 8 B = 24 KB), 16 MFMA/wave. Half the barrier drains of BK=32.
// KC2 = KC/2 rounds. aT[fk*8+fa], bT[bk*4+nb] where fk/bk = K-slice within round.
__device__ __forceinline__ void gemm_core64(const unsigned short* __restrict__ Afrag,
                                            const unsigned short* __restrict__ Bfrag,
                                            int mt0, int nt0, int KC,
                                            unsigned short (*aT)[512],
                                            unsigned short (*bT)[512],
                                            floatx4 acc[4][2]) {
    const int t = threadIdx.x;
    const int w = t >> 6, lane = t & 63;
    const int wm = w >> 1, wn = w & 1;
    const int KC2 = KC >> 1;
    for (int kc2 = 0; kc2 < KC2; ++kc2) {
        __syncthreads();
        {
#pragma unroll
            for (int l = 0; l < 6; ++l) {
                const int f = w * 6 + l;   // 0..23: 16 A-chunks then 8 B-chunks
                if (f < 16) {
                    const int fa = f & 7, fk = f >> 3;
                    gload16(Afrag + (((size_t)(mt0 + fa) * KC + kc2 * 2 + fk) * 64 + lane) * 8,
                            &aT[fk * 8 + fa][0]);
                } else {
                    const int g = f - 16;
                    const int nb = g & 3, bk = g >> 2;
                    gload16(Bfrag + (((size_t)(nt0 + nb) * KC + kc2 * 2 + bk) * 64 + lane) * 8,
                            &bT[bk * 4 + nb][0]);
                }
            }
        }
        __syncthreads();
#pragma unroll
        for (int kk = 0; kk < 2; ++kk) {
            short8 af[4], bf[2];
#pragma unroll
            for (int i = 0; i < 4; ++i) af[i] = *(const short8*)&aT[kk * 8 + wm * 4 + i][lane * 8];
#pragma unroll
            for (int j = 0; j < 2; ++j) bf[j] = *(const short8*)&bT[kk * 4 + wn * 2 + j][lane * 8];
#pragma unroll
            for (int i = 0; i < 4; ++i)
#pragma unroll
                for (int j = 0; j < 2; ++j)
                    acc[i][j] = __builtin_amdgcn_mfma_f32_16x16x32_bf16(af[i], bf[j], acc[i][j], 0, 0, 0);
        }
    }
}

// ---------------- k_gemm3: fused qall + kv + kpos (all independent, one launch) ----------------
// blocks [0,1024): qall (32x32); [1024,1152): kv (32x4); [1152,1184): kpos (16x2).
__global__ __launch_bounds__(256) void k_gemm3(const unsigned short* __restrict__ afrag,
                                               const unsigned short* __restrict__ bfragq,
                                               const unsigned short* __restrict__ attfrag,
                                               const unsigned short* __restrict__ bfragkv,
                                               const unsigned short* __restrict__ pefrag,
                                               const unsigned short* __restrict__ bfragp,
                                               const float* __restrict__ scale,
                                               unsigned short* __restrict__ qall,
                                               unsigned short* __restrict__ kfragg,
                                               unsigned short* __restrict__ vfragg,
                                               unsigned short* __restrict__ kposfg) {
    __shared__ __align__(16) unsigned short aT[16][512], bT[8][512];   // 24 KB
    floatx4 acc[4][2];
#pragma unroll
    for (int i = 0; i < 4; ++i) { acc[i][0] = (floatx4){0,0,0,0}; acc[i][1] = (floatx4){0,0,0,0}; }
    const int bx = blockIdx.x;
    const int t = threadIdx.x, w = t >> 6, lane = t & 63;
    const int wm = w >> 1, wn = w & 1, lq = lane >> 4, lm = lane & 15;
    const float sc = sqrtf(scale[0]);

    if (bx < 1024) {
        const int gx = bx & 31, gy = bx >> 5;
        gemm_core64(afrag, bfragq, gx * 8, gy * 4, 32, aT, bT, acc);
#pragma unroll
        for (int i = 0; i < 4; ++i)
#pragma unroll
            for (int j = 0; j < 2; ++j)
#pragma unroll
                for (int r = 0; r < 4; ++r)
                    qall[(size_t)(gx * 128 + (wm * 4 + i) * 16 + lq * 4 + r) * 2048 +
                         gy * 64 + (wn * 2 + j) * 16 + lm] = f2bf(acc[i][j][r] * sc);
    } else if (bx < 1152) {
        const int q = bx - 1024;
        const int gx = q & 31, gy = q >> 5;
        gemm_core64(attfrag, bfragkv, gx * 8, gy * 4, 32, aT, bT, acc);
#pragma unroll
        for (int i = 0; i < 4; ++i)
#pragma unroll
            for (int j = 0; j < 2; ++j) {
                const int n = gy * 64 + (wn * 2 + j) * 16 + lm;
#pragma unroll
                for (int r = 0; r < 4; ++r) {
                    const int tok = gx * 128 + (wm * 4 + i) * 16 + lq * 4 + r;
                    const int bb = tok >> 10, jj = tok & 1023;
                    if (n < 128) {
                        const int p = n;
                        const size_t addr = ((((size_t)bb * 64 + (jj >> 4)) * 4 + (p >> 5)) * 64 +
                                             ((p & 31) >> 3) * 16 + (jj & 15)) * 8 + (p & 7);
                        kfragg[addr] = f2bf(acc[i][j][r] * sc);
                    } else {
                        const int p = n - 128;
                        const size_t addr = ((((size_t)bb * 32 + (jj >> 5)) * 8 + (p >> 4)) * 64 +
                                             ((jj & 31) >> 3) * 16 + (p & 15)) * 8 + (jj & 7);
                        vfragg[addr] = f2bf(acc[i][j][r]);
                    }
                }
            }
    } else {
        const int q = bx - 1152;
        const int gx = q & 15, gy = q >> 4;
        gemm_core64(pefrag, bfragp, gx * 8, gy * 4, 32, aT, bT, acc);
#pragma unroll
        for (int i = 0; i < 4; ++i)
#pragma unroll
            for (int j = 0; j < 2; ++j) {
                const int p = gy * 64 + (wn * 2 + j) * 16 + lm;
#pragma unroll
                for (int r = 0; r < 4; ++r) {
                    const int tp = gx * 128 + (wm * 4 + i) * 16 + lq * 4 + r;
                    const size_t addr = (((size_t)(tp >> 4) * 4 + (p >> 5)) * 64 +
                                         ((p & 31) >> 3) * 16 + (tp & 15)) * 8 + (p & 7);
                    kposfg[addr] = f2bf(acc[i][j][r] * sc);
                }
            }
    }
}

// ---------------- GEMM: out = zfrag @ w_out -> f32 row-major 4096x1024 ----------------
__global__ __launch_bounds__(256) void k_gemm_out(const unsigned short* __restrict__ Afrag,
                                                  const unsigned short* __restrict__ Bfrag,
                                                  float* __restrict__ out) {
    __shared__ __align__(16) unsigned short aT[16][512], bT[8][512];   // 24 KB
    floatx4 acc[4][2];
#pragma unroll
    for (int i = 0; i < 4; ++i) { acc[i][0] = (floatx4){0,0,0,0}; acc[i][1] = (floatx4){0,0,0,0}; }
    gemm_core64(Afrag, Bfrag, blockIdx.x * 8, blockIdx.y * 4, 64, aT, bT, acc);
    const int t = threadIdx.x, w = t >> 6, lane = t & 63;
    const int wm = w >> 1, wn = w & 1, lq = lane >> 4, lm = lane & 15;
#pragma unroll
    for (int i = 0; i < 4; ++i)
#pragma unroll
        for (int j = 0; j < 2; ++j)
#pragma unroll
            for (int r = 0; r < 4; ++r)
                out[(size_t)(blockIdx.x * 128 + (wm * 4 + i) * 16 + lq * 4 + r) * 1024 +
                    blockIdx.y * 64 + (wn * 2 + j) * 16 + lm] = acc[i][j][r];
}

// ---------------- k_attn (unchanged from R10): 2 q-tiles/wave, key-split 2x, single-buffer K/V ----------------
#define ATTN_FM 8.0f

__global__ __launch_bounds__(256, 2) void k_attn(const unsigned short* __restrict__ qall,
                                                 const unsigned short* __restrict__ kfragg,
                                                 const unsigned short* __restrict__ vfragg,
                                                 const unsigned short* __restrict__ kposfg,
                                                 const int* __restrict__ selidx,
                                                 const float* __restrict__ selval,
                                                 unsigned short* __restrict__ zfrag) {
    __shared__ __align__(16) union {
        struct {
            unsigned short pl[4][2][16][56];   // 14336 B: per-wave, per-qt P staging
            unsigned short kst[2][8][512];     // 16384 B [ws][q] single-buffered K
            unsigned short vst[2][8][512];     // 16384 B [ws][q] single-buffered V
        } s;
        float cmb[2][2][64][37];               // 37888 B [wh][qt][lane][.] (37: pad)
    } sh;                                      // 47104 B

    const int t = threadIdx.x;
    const int w = t >> 6, lane = t & 63;
    const int st2 = blockIdx.x & 31;
    const int hg = (blockIdx.x >> 5) & 3;
    const int b = blockIdx.x >> 7;
    const int wh = w & 1;                       // head within pair
    const int ws = w >> 1;                      // key-split half
    const int h = hg * 2 + wh;
    const int s0 = st2 * 32;
    const int lq = lane >> 4;
    const int lm = lane & 15;
    const int loff = lane * 16;

    short8 qf[2][4];
#pragma unroll
    for (int qt = 0; qt < 2; ++qt) {
        const int token = b * 1024 + s0 + qt * 16 + lm;
        const int e = selidx[token * 8 + h];
        const unsigned short* qb = qall + (size_t)token * 2048 + e * 128 + lq * 8;
#pragma unroll
        for (int c = 0; c < 4; ++c) qf[qt][c] = *(const short8*)(qb + c * 32);
    }
    short8 onesf;
#pragma unroll
    for (int i = 0; i < 8; ++i) onesf[i] = (short)0x3F80;

    int baddr[4], bsel[4];
#pragma unroll
    for (int r = 0; r < 4; ++r) {
        const int c0 = 15 + lm - (lq * 4 + r);
        baddr[r] = (lq * 16 + (c0 & 15)) * 4;
        bsel[r] = (c0 < 16) ? 1 : 0;
    }

    floatx4 acc[2][8], accl[2];
#pragma unroll
    for (int qt = 0; qt < 2; ++qt) {
#pragma unroll
        for (int nt = 0; nt < 8; ++nt) acc[qt][nt] = (floatx4){0.f, 0.f, 0.f, 0.f};
        accl[qt] = (floatx4){0.f, 0.f, 0.f, 0.f};
    }

    const size_t koff = (size_t)ws * 131072;
    const char* pk = (const char*)kfragg + (size_t)b * 262144 + koff;
    const char* pv = (const char*)vfragg + (size_t)b * 262144 + koff;
    // qt0 window base tile = 63 - 2*st2; qt1 base = one tile lower (pp - 4096).
    const char* pp = (const char*)kposfg + (size_t)(63 - 2 * st2) * 4096 + koff;

    // prologue: fold each qt's first cry tile into its sp-carry
    floatx4 spc[2] = {{0.f,0.f,0.f,0.f},{0.f,0.f,0.f,0.f}};
    {
#pragma unroll
        for (int c = 0; c < 4; ++c) {
            const short8 c0 = *(const short8*)(pp + c * 1024 + loff);
            const short8 c1 = *(const short8*)(pp - 4096 + c * 1024 + loff);
            spc[0] = __builtin_amdgcn_mfma_f32_16x16x32_bf16(qf[0][c], c0, spc[0], 0, 0, 0);
            spc[1] = __builtin_amdgcn_mfma_f32_16x16x32_bf16(qf[1][c], c1, spc[1], 0, 0, 0);
        }
    }

    unsigned short* plw[2] = { &sh.s.pl[w][0][0][0], &sh.s.pl[w][1][0][0] };

    for (int it = 0; it < 16; ++it) {
        __syncthreads();                       // A: prior iter's kst/vst reads complete
        if (wh == 0) {
#pragma unroll
            for (int q = 0; q < 8; ++q)
                gload16(pk + q * 1024 + loff, &sh.s.kst[ws][q][0]);
        } else {
#pragma unroll
            for (int q = 0; q < 8; ++q)
                gload16(pv + q * 1024 + loff, &sh.s.vst[ws][q][0]);
        }
        // pos tiles: ta=pp+0 (qt1 n1), tb=pp+4096 (qt0 n1 / qt1 n2), tc=pp+8192 (qt0 n2)
        floatx4 sp1[2] = {{0.f,0.f,0.f,0.f},{0.f,0.f,0.f,0.f}};
        floatx4 sp2[2] = {{0.f,0.f,0.f,0.f},{0.f,0.f,0.f,0.f}};
#pragma unroll
        for (int c = 0; c < 4; ++c) {
            const short8 ta = *(const short8*)(pp + c * 1024 + loff);
            const short8 tb = *(const short8*)(pp + 4096 + c * 1024 + loff);
            const short8 tc = *(const short8*)(pp + 8192 + c * 1024 + loff);
            sp1[0] = __builtin_amdgcn_mfma_f32_16x16x32_bf16(qf[0][c], tb, sp1[0], 0, 0, 0);
            sp2[0] = __builtin_amdgcn_mfma_f32_16x16x32_bf16(qf[0][c], tc, sp2[0], 0, 0, 0);
            sp1[1] = __builtin_amdgcn_mfma_f32_16x16x32_bf16(qf[1][c], ta, sp1[1], 0, 0, 0);
            sp2[1] = __builtin_amdgcn_mfma_f32_16x16x32_bf16(qf[1][c], tb, sp2[1], 0, 0, 0);
        }
        __syncthreads();                       // B: kst/vst staged (vmcnt drain)
        floatx4 sk0[2] = {{0.f,0.f,0.f,0.f},{0.f,0.f,0.f,0.f}};
        floatx4 sk1[2] = {{0.f,0.f,0.f,0.f},{0.f,0.f,0.f,0.f}};
#pragma unroll
        for (int c = 0; c < 4; ++c) {
            const short8 k0 = *(const short8*)&sh.s.kst[ws][c][lane * 8];
            const short8 k1 = *(const short8*)&sh.s.kst[ws][4 + c][lane * 8];
            sk0[0] = __builtin_amdgcn_mfma_f32_16x16x32_bf16(qf[0][c], k0, sk0[0], 0, 0, 0);
            sk1[0] = __builtin_amdgcn_mfma_f32_16x16x32_bf16(qf[0][c], k1, sk1[0], 0, 0, 0);
            sk0[1] = __builtin_amdgcn_mfma_f32_16x16x32_bf16(qf[1][c], k0, sk0[1], 0, 0, 0);
            sk1[1] = __builtin_amdgcn_mfma_f32_16x16x32_bf16(qf[1][c], k1, sk1[1], 0, 0, 0);
        }
#pragma unroll
        for (int qt = 0; qt < 2; ++qt) {
            unsigned short* pl = plw[qt];
#pragma unroll
            for (int r = 0; r < 4; ++r) {
                const int a = baddr[r];
                const float b0 = __int_as_float(__builtin_amdgcn_ds_bpermute(a, __float_as_int(spc[qt][r])));
                const float b1 = __int_as_float(__builtin_amdgcn_ds_bpermute(a, __float_as_int(sp1[qt][r])));
                const float b2 = __int_as_float(__builtin_amdgcn_ds_bpermute(a, __float_as_int(sp2[qt][r])));
                const float v0 = sk0[qt][r] + (bsel[r] ? b0 : b1);
                const float v1 = sk1[qt][r] + (bsel[r] ? b1 : b2);
                pl[(lq * 4 + r) * 56 + lm]      = f2bf(__expf(v0 - ATTN_FM));
                pl[(lq * 4 + r) * 56 + 16 + lm] = f2bf(__expf(v1 - ATTN_FM));
            }
        }
        asm volatile("" ::: "memory");
        const short8 pf0 = *(const short8*)(plw[0] + lm * 56 + lq * 8);
        const short8 pf1 = *(const short8*)(plw[1] + lm * 56 + lq * 8);
#pragma unroll
        for (int nt = 0; nt < 8; ++nt) {
            const short8 vf = *(const short8*)&sh.s.vst[ws][nt][lane * 8];
            acc[0][nt] = __builtin_amdgcn_mfma_f32_16x16x32_bf16(pf0, vf, acc[0][nt], 0, 0, 0);
            acc[1][nt] = __builtin_amdgcn_mfma_f32_16x16x32_bf16(pf1, vf, acc[1][nt], 0, 0, 0);
        }
        accl[0] = __builtin_amdgcn_mfma_f32_16x16x32_bf16(pf0, onesf, accl[0], 0, 0, 0);
        accl[1] = __builtin_amdgcn_mfma_f32_16x16x32_bf16(pf1, onesf, accl[1], 0, 0, 0);
        spc[0] = sp2[0]; spc[1] = sp2[1];
        pk += 8192; pv += 8192; pp += 8192;
    }

    // ---- combine the two key-halves through LDS (fixed-max softmax => partials additive) ----
    __syncthreads();
    if (ws == 1) {
#pragma unroll
        for (int qt = 0; qt < 2; ++qt) {
            float* cb = &sh.cmb[wh][qt][lane][0];
#pragma unroll
            for (int nt = 0; nt < 8; ++nt)
#pragma unroll
                for (int r = 0; r < 4; ++r) cb[nt * 4 + r] = acc[qt][nt][r];
#pragma unroll
            for (int r = 0; r < 4; ++r) cb[32 + r] = accl[qt][r];
        }
    }
    __syncthreads();
    if (ws == 1) return;
#pragma unroll
    for (int qt = 0; qt < 2; ++qt) {
        const float* cb = &sh.cmb[wh][qt][lane][0];
#pragma unroll
        for (int nt = 0; nt < 8; ++nt)
#pragma unroll
            for (int r = 0; r < 4; ++r) acc[qt][nt][r] += cb[nt * 4 + r];
#pragma unroll
        for (int r = 0; r < 4; ++r) accl[qt][r] += cb[32 + r];
    }

#pragma unroll
    for (int qt = 0; qt < 2; ++qt)
#pragma unroll
        for (int r = 0; r < 4; ++r) {
            const int tok = b * 1024 + s0 + qt * 16 + lq * 4 + r;
            const int e = selidx[tok * 8 + h];
            const float g = selval[tok * 8 + h] / accl[qt][r];
            const int mt = tok >> 4, tm = tok & 15;
#pragma unroll
            for (int nt = 0; nt < 8; ++nt) {
                const int k = e * 128 + nt * 16 + lm;
                const int kc = k >> 5;
                const int lane2 = (((k & 31) >> 3) << 4) + tm;
                zfrag[(((size_t)mt * 64 + kc) * 64 + lane2) * 8 + (k & 7)] = f2bf(acc[qt][nt][r] * g);
            }
        }
}

extern "C" void kernel_launch(void* const* d_in, const int* in_sizes, int n_in,
                              void* d_out, int out_size, void* d_ws, size_t ws_size,
                              hipStream_t stream) {
    const float* curr    = (const float*)d_in[0];  // (4,1024,1024)
    const float* attend  = (const float*)d_in[1];  // (4,1024,1024)
    const float* w_q     = (const float*)d_in[2];  // (16,1024,128)
    const float* w_kv    = (const float*)d_in[3];  // (1024,256)
    const float* w_out   = (const float*)d_in[4];  // (16,128,1024)
    const float* pos_pk  = (const float*)d_in[5];  // (128,1024)
    const float* sel_dst = (const float*)d_in[6];  // (16,1024)
    const float* scale   = (const float*)d_in[7];  // (1,)
    float* out = (float*)d_out;

    char* ws = (char*)d_ws;
    float* selval = (float*)ws;                                        // 128 KB
    int*   selidx = (int*)(ws + 131072);                               // 128 KB
    unsigned short* kposfg  = (unsigned short*)(ws + 262144);          // 512 KB
    unsigned short* kfragg  = (unsigned short*)(ws + 786432);          // 1 MB
    unsigned short* vfragg  = (unsigned short*)(ws + 1835008);         // 1 MB
    unsigned short* bfragq  = (unsigned short*)(ws + 2883584);         // 4 MB
    unsigned short* bfragw  = (unsigned short*)(ws + 7077888);         // 4 MB
    unsigned short* bfragkv = (unsigned short*)(ws + 11272192);        // 512 KB
    unsigned short* afrag   = (unsigned short*)(ws + 11796480);        // 8 MB (curr A-frag)
    unsigned short* qall    = (unsigned short*)(ws + 20185088);        // 16 MB
    unsigned short* zfrag   = (unsigned short*)(ws + 36962304);        // 16 MB
    // Aliases inside zfrag (all fully consumed by k_gemm3 BEFORE zfrag's memset):
    //   pefrag  = zfrag[0 .. 4MB)       (pe A-frag)
    //   bfragp  = zfrag[4MB .. 4.25MB)  (pos_pk B-frag)
    //   attfrag = zfrag[8MB .. 16MB)    (attend A-frag)
    unsigned short* pefrag  = zfrag;                                   // 4 MB
    unsigned short* bfragp  = zfrag + 2097152;                         // 256 KB
    unsigned short* attfrag = zfrag + 4194304;                         // 8 MB
    // total ~51.3 MB

    k_prep<<<18816, 256, 0, stream>>>(curr, attend, w_q, w_out, w_kv, pos_pk, sel_dst,
                                      selval, selidx, afrag, attfrag,
                                      bfragq, bfragw, bfragkv, bfragp, pefrag);
    k_gemm3<<<1184, 256, 0, stream>>>(afrag, bfragq, attfrag, bfragkv, pefrag, bfragp,
                                      scale, qall, kfragg, vfragg, kposfg);
    hipMemsetAsync(zfrag, 0, (size_t)16777216, stream);
    k_attn<<<512, 256, 0, stream>>>(qall, kfragg, vfragg, kposfg, selidx, selval, zfrag);
    k_gemm_out<<<dim3(32, 16), 256, 0, stream>>>(zfrag, bfragw, out);
}

// Round 13
// 238.728 us; speedup vs baseline: 1.3101x; 1.0011x over previous
//
#include <hip/hip_runtime.h>
#include <math.h>

// B=4 S=1024 D=1024 P=128 H=8 E=16, NT=4096, TPOS=2047

typedef __attribute__((ext_vector_type(8))) short short8;
typedef __attribute__((ext_vector_type(4))) float floatx4;

__device__ __forceinline__ float bf2f(unsigned int u) {
    union { unsigned int i; float f; } x; x.i = (u & 0xffffu) << 16; return x.f;
}
__device__ __forceinline__ unsigned short f2bf(float f) {
    union { float f; unsigned int i; } x; x.f = f;
    unsigned int r = x.i + 0x7fffu + ((x.i >> 16) & 1u);
    return (unsigned short)(r >> 16);
}

// async global->LDS: per-lane global addr, wave-uniform LDS base; lane data at base + lane*16
__device__ __forceinline__ void gload16(const void* g, void* l) {
    __builtin_amdgcn_global_load_lds(
        (const __attribute__((address_space(1))) unsigned int*)(uintptr_t)g,
        (__attribute__((address_space(3))) unsigned int*)(uintptr_t)l,
        16, 0, 0);
}

// Fragment layouts (16x16x32 bf16 MFMA), HW-verified R2-R6:
//   A-frag (MxK):  afrag[m>>4][k>>5][((k&31)>>3)*16 + (m&15)][k&7]
//   B-frag (KxN):  bfrag[n>>4][k>>5][((k&31)>>3)*16 + (n&15)][k&7]
//   C/D:           col = lane&15, row = (lane>>4)*4 + reg
// R9 dense-write converters: u-bits [0]=half(j>>2), [1:4]=n/m low, [5:6]=k-octet, [7:..]=kc, nt/mt.
// R13: XCD-aware block swizzle (T1) on k_attn / qall / gemm_out — consecutive logical blocks share
// operand panels; chunked mapping pins each 64/128-logical-block group to one XCD's L2.

// ---------------- k_prep R11: sel first (batched dot + wave-parallel top-8) + dense converters ----------------
// [0,4096): sel; [4096,6144): w_q; [6144,8192): w_out; [8192,8448): w_kv; [8448,8576): pos_pk;
// [8576,10624): pe; [10624,14720): curr->afrag; [14720,18816): attend->attfrag.
__global__ __launch_bounds__(256) void k_prep(const float* __restrict__ curr,
                                              const float* __restrict__ attend,
                                              const float* __restrict__ w_q,
                                              const float* __restrict__ w_out,
                                              const float* __restrict__ w_kv,
                                              const float* __restrict__ pos_pk,
                                              const float* __restrict__ sel_dst,
                                              float* __restrict__ selval,
                                              int* __restrict__ selidx,
                                              unsigned short* __restrict__ afrag,
                                              unsigned short* __restrict__ attfrag,
                                              unsigned short* __restrict__ bfragq,
                                              unsigned short* __restrict__ bfragw,
                                              unsigned short* __restrict__ bfragkv,
                                              unsigned short* __restrict__ bfragp,
                                              unsigned short* __restrict__ pefrag) {
    __shared__ float row[1024];
    __shared__ float sel[16];
    const int bx = blockIdx.x;
    const int t = threadIdx.x;

    if (bx < 4096) {
        // ---- sel: batched-load dot product + wave-parallel top-8 ----
        const int token = bx;
        const float4 v4 = ((const float4*)(curr + (size_t)token * 1024))[t];
        ((float4*)row)[t] = v4;
        __syncthreads();
        const int wv = t >> 6, lane = t & 63;
        for (int e0 = 0; e0 < 4; ++e0) {
            const int e = wv * 4 + e0;
            const float* wp = sel_dst + e * 1024;
            float p = 0.f;
#pragma unroll
            for (int i = 0; i < 16; ++i) p += row[lane + i * 64] * wp[lane + i * 64];
#pragma unroll
            for (int off = 32; off; off >>= 1) p += __shfl_down(p, off, 64);
            if (lane == 0) sel[e] = p;
        }
        __syncthreads();
        if (t < 64) {
            float v = (t < 16) ? sel[t] : -INFINITY;
#pragma unroll
            for (int r = 0; r < 8; ++r) {
                float mv = v; int mi = t;
#pragma unroll
                for (int off = 8; off; off >>= 1) {
                    const float ov = __shfl_xor(mv, off, 64);
                    const int oi = __shfl_xor(mi, off, 64);
                    if (ov > mv || (ov == mv && oi < mi)) { mv = ov; mi = oi; }
                }
                if (t == 0) {
                    selidx[token * 8 + r] = mi;
                    selval[token * 8 + r] = 1.f / (1.f + __expf(-mv));
                }
                if (t == mi) v = -INFINITY;
            }
        }
    } else if (bx < 6144) {
        // ---- w_q -> bfragq (B-frag KC=32, N=2048): dense writes ----
        const unsigned u = (unsigned)(bx - 4096) * 256 + t;
        const int half = u & 1;
        const int nlow = (u >> 1) & 15;
        const int koct = (u >> 5) & 3;
        const int kc   = (u >> 7) & 31;
        const int nt   = (u >> 12) & 127;
        const int n = nt * 16 + nlow;
        const int e = n >> 7, p = n & 127;
        const int k0 = kc * 32 + koct * 8 + half * 4;
        const float* src = w_q + (size_t)e * 131072 + (size_t)k0 * 128 + p;
        uint2 o;
        o.x = (unsigned)f2bf(src[0])   | ((unsigned)f2bf(src[128]) << 16);
        o.y = (unsigned)f2bf(src[256]) | ((unsigned)f2bf(src[384]) << 16);
        const size_t chunk = ((size_t)nt * 32 + kc) * 64 + koct * 16 + nlow;
        *(uint2*)(bfragq + chunk * 8 + half * 4) = o;
    } else if (bx < 8192) {
        // ---- w_out -> bfragw (B-frag KC=64, N=1024): dense writes ----
        const unsigned u = (unsigned)(bx - 6144) * 256 + t;
        const int half = u & 1;
        const int nlow = (u >> 1) & 15;
        const int koct = (u >> 5) & 3;
        const int kc   = (u >> 7) & 63;
        const int nt   = (u >> 13) & 63;
        const int n = nt * 16 + nlow;
        const int k0 = kc * 32 + koct * 8 + half * 4;
        const float* src = w_out + (size_t)k0 * 1024 + n;
        uint2 o;
        o.x = (unsigned)f2bf(src[0])    | ((unsigned)f2bf(src[1024]) << 16);
        o.y = (unsigned)f2bf(src[2048]) | ((unsigned)f2bf(src[3072]) << 16);
        const size_t chunk = ((size_t)nt * 64 + kc) * 64 + koct * 16 + nlow;
        *(uint2*)(bfragw + chunk * 8 + half * 4) = o;
    } else if (bx < 8448) {
        // ---- w_kv -> bfragkv (B-frag KC=32, N=256): dense writes ----
        const unsigned u = (unsigned)(bx - 8192) * 256 + t;
        const int half = u & 1;
        const int nlow = (u >> 1) & 15;
        const int koct = (u >> 5) & 3;
        const int kc   = (u >> 7) & 31;
        const int nt   = (u >> 12) & 15;
        const int n = nt * 16 + nlow;
        const int k0 = kc * 32 + koct * 8 + half * 4;
        const float* src = w_kv + (size_t)k0 * 256 + n;
        uint2 o;
        o.x = (unsigned)f2bf(src[0])   | ((unsigned)f2bf(src[256]) << 16);
        o.y = (unsigned)f2bf(src[512]) | ((unsigned)f2bf(src[768]) << 16);
        const size_t chunk = ((size_t)nt * 32 + kc) * 64 + koct * 16 + nlow;
        *(uint2*)(bfragkv + chunk * 8 + half * 4) = o;
    } else if (bx < 8576) {
        // ---- pos_pk -> bfragp (small; original mapping, coalesced row reads) ----
        const int n = bx - 8448;
        float v[4];
#pragma unroll
        for (int d = 0; d < 4; ++d) v[d] = pos_pk[(size_t)n * 1024 + 4 * t + d];
        const int nt = n >> 4, kc = t >> 3;
        const int lane = ((t & 7) >> 1) * 16 + (n & 15);
        const size_t off = (((size_t)nt * 32 + kc) * 64 + lane) * 8 + 4 * (t & 1);
        uint2 o;
        o.x = (unsigned)f2bf(v[0]) | ((unsigned)f2bf(v[1]) << 16);
        o.y = (unsigned)f2bf(v[2]) | ((unsigned)f2bf(v[3]) << 16);
        *(uint2*)(bfragp + off) = o;
    } else if (bx < 10624) {
        // ---- pe -> pefrag (A-frag, 2048 rows, row 2047 = 0): dense writes ----
        const unsigned u = (unsigned)(bx - 8576) * 256 + t;
        const int half = u & 1;
        const int mlow = (u >> 1) & 15;
        const int koct = (u >> 5) & 3;
        const int kc   = (u >> 7) & 31;
        const int mt   = (u >> 12) & 127;
        const int m = mt * 16 + mlow;
        const int k0 = kc * 32 + koct * 8 + half * 4;
        uint2 o;
        if (m >= 2047) {
            o.x = 0u; o.y = 0u;
        } else {
            const float c1 = -logf(10000.f) / 1024.f;
            const float pos = (float)(m - 1023);
            const float a0 = pos * expf((float)k0 * c1);
            const float a1 = pos * expf((float)(k0 + 2) * c1);
            o.x = (unsigned)f2bf(sinf(a0)) | ((unsigned)f2bf(cosf(a0)) << 16);
            o.y = (unsigned)f2bf(sinf(a1)) | ((unsigned)f2bf(cosf(a1)) << 16);
        }
        const size_t chunk = ((size_t)mt * 32 + kc) * 64 + koct * 16 + mlow;
        *(uint2*)(pefrag + chunk * 8 + half * 4) = o;
    } else if (bx < 14720) {
        // ---- curr -> afrag (A-frag, 4096 rows): dense writes, full-line float4 reads ----
        const unsigned u = (unsigned)(bx - 10624) * 256 + t;
        const int half = u & 1;
        const int mlow = (u >> 1) & 15;
        const int koct = (u >> 5) & 3;
        const int kc   = (u >> 7) & 31;
        const int mt   = (u >> 12) & 255;
        const int m = mt * 16 + mlow;
        const int k0 = kc * 32 + koct * 8 + half * 4;
        const float4 v = *(const float4*)(curr + (size_t)m * 1024 + k0);
        uint2 o;
        o.x = (unsigned)f2bf(v.x) | ((unsigned)f2bf(v.y) << 16);
        o.y = (unsigned)f2bf(v.z) | ((unsigned)f2bf(v.w) << 16);
        const size_t chunk = ((size_t)mt * 32 + kc) * 64 + koct * 16 + mlow;
        *(uint2*)(afrag + chunk * 8 + half * 4) = o;
    } else {
        // ---- attend -> attfrag (A-frag, 4096 rows): dense writes ----
        const unsigned u = (unsigned)(bx - 14720) * 256 + t;
        const int half = u & 1;
        const int mlow = (u >> 1) & 15;
        const int koct = (u >> 5) & 3;
        const int kc   = (u >> 7) & 31;
        const int mt   = (u >> 12) & 255;
        const int m = mt * 16 + mlow;
        const int k0 = kc * 32 + koct * 8 + half * 4;
        const float4 v = *(const float4*)(attend + (size_t)m * 1024 + k0);
        uint2 o;
        o.x = (unsigned)f2bf(v.x) | ((unsigned)f2bf(v.y) << 16);
        o.y = (unsigned)f2bf(v.z) | ((unsigned)f2bf(v.w) << 16);
        const size_t chunk = ((size_t)mt * 32 + kc) * 64 + koct * 16 + mlow;
        *(uint2*)(attfrag + chunk * 8 + half * 4) = o;
    }
}

// ---------------- MFMA GEMM core R12: 128x64 tile, BK=64 (2 K-slices per barrier round) ----------------
__device__ __forceinline__ void gemm_core64(const unsigned short* __restrict__ Afrag,
                                            const unsigned short* __restrict__ Bfrag,
                                            int mt0, int nt0, int KC,
                                            unsigned short (*aT)[512],
                                            unsigned short (*bT)[512],
                                            floatx4 acc[4][2]) {
    const int t = threadIdx.x;
    const int w = t >> 6, lane = t & 63;
    const int wm = w >> 1, wn = w & 1;
    const int KC2 = KC >> 1;
    for (int kc2 = 0; kc2 < KC2; ++kc2) {
        __syncthreads();
        {
#pragma unroll
            for (int l = 0; l < 6; ++l) {
                const int f = w * 6 + l;   // 0..23: 16 A-chunks then 8 B-chunks
                if (f < 16) {
                    const int fa = f & 7, fk = f >> 3;
                    gload16(Afrag + (((size_t)(mt0 + fa) * KC + kc2 * 2 + fk) * 64 + lane) * 8,
                            &aT[fk * 8 + fa][0]);
                } else {
                    const int g = f - 16;
                    const int nb = g & 3, bk = g >> 2;
                    gload16(Bfrag + (((size_t)(nt0 + nb) * KC + kc2 * 2 + bk) * 64 + lane) * 8,
                            &bT[bk * 4 + nb][0]);
                }
            }
        }
        __syncthreads();
#pragma unroll
        for (int kk = 0; kk < 2; ++kk) {
            short8 af[4], bf[2];
#pragma unroll
            for (int i = 0; i < 4; ++i) af[i] = *(const short8*)&aT[kk * 8 + wm * 4 + i][lane * 8];
#pragma unroll
            for (int j = 0; j < 2; ++j) bf[j] = *(const short8*)&bT[kk * 4 + wn * 2 + j][lane * 8];
#pragma unroll
            for (int i = 0; i < 4; ++i)
#pragma unroll
                for (int j = 0; j < 2; ++j)
                    acc[i][j] = __builtin_amdgcn_mfma_f32_16x16x32_bf16(af[i], bf[j], acc[i][j], 0, 0, 0);
        }
    }
}

// ---------------- k_gemm3: fused qall + kv + kpos; qall range XCD-swizzled ----------------
// hw blocks [0,1024) -> swizzled logical qall id (A-panel-fast mapping); [1024,1152): kv; [1152,1184): kpos.
__global__ __launch_bounds__(256) void k_gemm3(const unsigned short* __restrict__ afrag,
                                               const unsigned short* __restrict__ bfragq,
                                               const unsigned short* __restrict__ attfrag,
                                               const unsigned short* __restrict__ bfragkv,
                                               const unsigned short* __restrict__ pefrag,
                                               const unsigned short* __restrict__ bfragp,
                                               const float* __restrict__ scale,
                                               unsigned short* __restrict__ qall,
                                               unsigned short* __restrict__ kfragg,
                                               unsigned short* __restrict__ vfragg,
                                               unsigned short* __restrict__ kposfg) {
    __shared__ __align__(16) unsigned short aT[16][512], bT[8][512];   // 24 KB
    floatx4 acc[4][2];
#pragma unroll
    for (int i = 0; i < 4; ++i) { acc[i][0] = (floatx4){0,0,0,0}; acc[i][1] = (floatx4){0,0,0,0}; }
    const int bx = blockIdx.x;
    const int t = threadIdx.x, w = t >> 6, lane = t & 63;
    const int wm = w >> 1, wn = w & 1, lq = lane >> 4, lm = lane & 15;
    const float sc = sqrtf(scale[0]);

    if (bx < 1024) {
        // XCD swizzle: each XCD gets 128 consecutive logical ids = 4 A-panels x all gy (B streamed).
        const int lg = ((bx & 7) << 7) + (bx >> 3);
        const int gx = lg >> 5, gy = lg & 31;
        gemm_core64(afrag, bfragq, gx * 8, gy * 4, 32, aT, bT, acc);
#pragma unroll
        for (int i = 0; i < 4; ++i)
#pragma unroll
            for (int j = 0; j < 2; ++j)
#pragma unroll
                for (int r = 0; r < 4; ++r)
                    qall[(size_t)(gx * 128 + (wm * 4 + i) * 16 + lq * 4 + r) * 2048 +
                         gy * 64 + (wn * 2 + j) * 16 + lm] = f2bf(acc[i][j][r] * sc);
    } else if (bx < 1152) {
        const int q = bx - 1024;
        const int gx = q & 31, gy = q >> 5;
        gemm_core64(attfrag, bfragkv, gx * 8, gy * 4, 32, aT, bT, acc);
#pragma unroll
        for (int i = 0; i < 4; ++i)
#pragma unroll
            for (int j = 0; j < 2; ++j) {
                const int n = gy * 64 + (wn * 2 + j) * 16 + lm;
#pragma unroll
                for (int r = 0; r < 4; ++r) {
                    const int tok = gx * 128 + (wm * 4 + i) * 16 + lq * 4 + r;
                    const int bb = tok >> 10, jj = tok & 1023;
                    if (n < 128) {
                        const int p = n;
                        const size_t addr = ((((size_t)bb * 64 + (jj >> 4)) * 4 + (p >> 5)) * 64 +
                                             ((p & 31) >> 3) * 16 + (jj & 15)) * 8 + (p & 7);
                        kfragg[addr] = f2bf(acc[i][j][r] * sc);
                    } else {
                        const int p = n - 128;
                        const size_t addr = ((((size_t)bb * 32 + (jj >> 5)) * 8 + (p >> 4)) * 64 +
                                             ((jj & 31) >> 3) * 16 + (p & 15)) * 8 + (jj & 7);
                        vfragg[addr] = f2bf(acc[i][j][r]);
                    }
                }
            }
    } else {
        const int q = bx - 1152;
        const int gx = q & 15, gy = q >> 4;
        gemm_core64(pefrag, bfragp, gx * 8, gy * 4, 32, aT, bT, acc);
#pragma unroll
        for (int i = 0; i < 4; ++i)
#pragma unroll
            for (int j = 0; j < 2; ++j) {
                const int p = gy * 64 + (wn * 2 + j) * 16 + lm;
#pragma unroll
                for (int r = 0; r < 4; ++r) {
                    const int tp = gx * 128 + (wm * 4 + i) * 16 + lq * 4 + r;
                    const size_t addr = (((size_t)(tp >> 4) * 4 + (p >> 5)) * 64 +
                                         ((p & 31) >> 3) * 16 + (tp & 15)) * 8 + (p & 7);
                    kposfg[addr] = f2bf(acc[i][j][r] * sc);
                }
            }
    }
}

// ---------------- GEMM: out = zfrag @ w_out -> f32 4096x1024; 1D grid 512, XCD-swizzled ----------------
__global__ __launch_bounds__(256) void k_gemm_out(const unsigned short* __restrict__ Afrag,
                                                  const unsigned short* __restrict__ Bfrag,
                                                  float* __restrict__ out) {
    __shared__ __align__(16) unsigned short aT[16][512], bT[8][512];   // 24 KB
    floatx4 acc[4][2];
#pragma unroll
    for (int i = 0; i < 4; ++i) { acc[i][0] = (floatx4){0,0,0,0}; acc[i][1] = (floatx4){0,0,0,0}; }
    // 512 blocks: each XCD gets 64 logical = 4 A-panels (n-fast) + B resident
    const int lg = ((blockIdx.x & 7) << 6) + (blockIdx.x >> 3);
    const int gy = lg & 15, gx = lg >> 4;
    gemm_core64(Afrag, Bfrag, gx * 8, gy * 4, 64, aT, bT, acc);
    const int t = threadIdx.x, w = t >> 6, lane = t & 63;
    const int wm = w >> 1, wn = w & 1, lq = lane >> 4, lm = lane & 15;
#pragma unroll
    for (int i = 0; i < 4; ++i)
#pragma unroll
        for (int j = 0; j < 2; ++j)
#pragma unroll
            for (int r = 0; r < 4; ++r)
                out[(size_t)(gx * 128 + (wm * 4 + i) * 16 + lq * 4 + r) * 1024 +
                    gy * 64 + (wn * 2 + j) * 16 + lm] = acc[i][j][r];
}

// ---------------- k_attn R13: R10 structure + XCD swizzle (each XCD owns one (b, hg-pair)) ----------------
#define ATTN_FM 8.0f

__global__ __launch_bounds__(256, 2) void k_attn(const unsigned short* __restrict__ qall,
                                                 const unsigned short* __restrict__ kfragg,
                                                 const unsigned short* __restrict__ vfragg,
                                                 const unsigned short* __restrict__ kposfg,
                                                 const int* __restrict__ selidx,
                                                 const float* __restrict__ selval,
                                                 unsigned short* __restrict__ zfrag) {
    __shared__ __align__(16) union {
        struct {
            unsigned short pl[4][2][16][56];   // 14336 B: per-wave, per-qt P staging
            unsigned short kst[2][8][512];     // 16384 B [ws][q] single-buffered K
            unsigned short vst[2][8][512];     // 16384 B [ws][q] single-buffered V
        } s;
        float cmb[2][2][64][37];               // 37888 B [wh][qt][lane][.] (37: pad)
    } sh;                                      // 47104 B

    const int t = threadIdx.x;
    const int w = t >> 6, lane = t & 63;
    // XCD swizzle: 512 blocks, chunks of 64 per XCD -> one XCD covers one b x hg-pair (shared K/V/kpos)
    const int lg = ((blockIdx.x & 7) << 6) + (blockIdx.x >> 3);
    const int st2 = lg & 31;
    const int hg = (lg >> 5) & 3;
    const int b = lg >> 7;
    const int wh = w & 1;                       // head within pair
    const int ws = w >> 1;                      // key-split half
    const int h = hg * 2 + wh;
    const int s0 = st2 * 32;
    const int lq = lane >> 4;
    const int lm = lane & 15;
    const int loff = lane * 16;

    short8 qf[2][4];
#pragma unroll
    for (int qt = 0; qt < 2; ++qt) {
        const int token = b * 1024 + s0 + qt * 16 + lm;
        const int e = selidx[token * 8 + h];
        const unsigned short* qb = qall + (size_t)token * 2048 + e * 128 + lq * 8;
#pragma unroll
        for (int c = 0; c < 4; ++c) qf[qt][c] = *(const short8*)(qb + c * 32);
    }
    short8 onesf;
#pragma unroll
    for (int i = 0; i < 8; ++i) onesf[i] = (short)0x3F80;

    int baddr[4], bsel[4];
#pragma unroll
    for (int r = 0; r < 4; ++r) {
        const int c0 = 15 + lm - (lq * 4 + r);
        baddr[r] = (lq * 16 + (c0 & 15)) * 4;
        bsel[r] = (c0 < 16) ? 1 : 0;
    }

    floatx4 acc[2][8], accl[2];
#pragma unroll
    for (int qt = 0; qt < 2; ++qt) {
#pragma unroll
        for (int nt = 0; nt < 8; ++nt) acc[qt][nt] = (floatx4){0.f, 0.f, 0.f, 0.f};
        accl[qt] = (floatx4){0.f, 0.f, 0.f, 0.f};
    }

    const size_t koff = (size_t)ws * 131072;
    const char* pk = (const char*)kfragg + (size_t)b * 262144 + koff;
    const char* pv = (const char*)vfragg + (size_t)b * 262144 + koff;
    // qt0 window base tile = 63 - 2*st2; qt1 base = one tile lower (pp - 4096).
    const char* pp = (const char*)kposfg + (size_t)(63 - 2 * st2) * 4096 + koff;

    // prologue: fold each qt's first cry tile into its sp-carry
    floatx4 spc[2] = {{0.f,0.f,0.f,0.f},{0.f,0.f,0.f,0.f}};
    {
#pragma unroll
        for (int c = 0; c < 4; ++c) {
            const short8 c0 = *(const short8*)(pp + c * 1024 + loff);
            const short8 c1 = *(const short8*)(pp - 4096 + c * 1024 + loff);
            spc[0] = __builtin_amdgcn_mfma_f32_16x16x32_bf16(qf[0][c], c0, spc[0], 0, 0, 0);
            spc[1] = __builtin_amdgcn_mfma_f32_16x16x32_bf16(qf[1][c], c1, spc[1], 0, 0, 0);
        }
    }

    unsigned short* plw[2] = { &sh.s.pl[w][0][0][0], &sh.s.pl[w][1][0][0] };

    for (int it = 0; it < 16; ++it) {
        __syncthreads();                       // A: prior iter's kst/vst reads complete
        if (wh == 0) {
#pragma unroll
            for (int q = 0; q < 8; ++q)
                gload16(pk + q * 1024 + loff, &sh.s.kst[ws][q][0]);
        } else {
#pragma unroll
            for (int q = 0; q < 8; ++q)
                gload16(pv + q * 1024 + loff, &sh.s.vst[ws][q][0]);
        }
        // pos tiles: ta=pp+0 (qt1 n1), tb=pp+4096 (qt0 n1 / qt1 n2), tc=pp+8192 (qt0 n2)
        floatx4 sp1[2] = {{0.f,0.f,0.f,0.f},{0.f,0.f,0.f,0.f}};
        floatx4 sp2[2] = {{0.f,0.f,0.f,0.f},{0.f,0.f,0.f,0.f}};
#pragma unroll
        for (int c = 0; c < 4; ++c) {
            const short8 ta = *(const short8*)(pp + c * 1024 + loff);
            const short8 tb = *(const short8*)(pp + 4096 + c * 1024 + loff);
            const short8 tc = *(const short8*)(pp + 8192 + c * 1024 + loff);
            sp1[0] = __builtin_amdgcn_mfma_f32_16x16x32_bf16(qf[0][c], tb, sp1[0], 0, 0, 0);
            sp2[0] = __builtin_amdgcn_mfma_f32_16x16x32_bf16(qf[0][c], tc, sp2[0], 0, 0, 0);
            sp1[1] = __builtin_amdgcn_mfma_f32_16x16x32_bf16(qf[1][c], ta, sp1[1], 0, 0, 0);
            sp2[1] = __builtin_amdgcn_mfma_f32_16x16x32_bf16(qf[1][c], tb, sp2[1], 0, 0, 0);
        }
        __syncthreads();                       // B: kst/vst staged (vmcnt drain)
        floatx4 sk0[2] = {{0.f,0.f,0.f,0.f},{0.f,0.f,0.f,0.f}};
        floatx4 sk1[2] = {{0.f,0.f,0.f,0.f},{0.f,0.f,0.f,0.f}};
#pragma unroll
        for (int c = 0; c < 4; ++c) {
            const short8 k0 = *(const short8*)&sh.s.kst[ws][c][lane * 8];
            const short8 k1 = *(const short8*)&sh.s.kst[ws][4 + c][lane * 8];
            sk0[0] = __builtin_amdgcn_mfma_f32_16x16x32_bf16(qf[0][c], k0, sk0[0], 0, 0, 0);
            sk1[0] = __builtin_amdgcn_mfma_f32_16x16x32_bf16(qf[0][c], k1, sk1[0], 0, 0, 0);
            sk0[1] = __builtin_amdgcn_mfma_f32_16x16x32_bf16(qf[1][c], k0, sk0[1], 0, 0, 0);
            sk1[1] = __builtin_amdgcn_mfma_f32_16x16x32_bf16(qf[1][c], k1, sk1[1], 0, 0, 0);
        }
#pragma unroll
        for (int qt = 0; qt < 2; ++qt) {
            unsigned short* pl = plw[qt];
#pragma unroll
            for (int r = 0; r < 4; ++r) {
                const int a = baddr[r];
                const float b0 = __int_as_float(__builtin_amdgcn_ds_bpermute(a, __float_as_int(spc[qt][r])));
                const float b1 = __int_as_float(__builtin_amdgcn_ds_bpermute(a, __float_as_int(sp1[qt][r])));
                const float b2 = __int_as_float(__builtin_amdgcn_ds_bpermute(a, __float_as_int(sp2[qt][r])));
                const float v0 = sk0[qt][r] + (bsel[r] ? b0 : b1);
                const float v1 = sk1[qt][r] + (bsel[r] ? b1 : b2);
                pl[(lq * 4 + r) * 56 + lm]      = f2bf(__expf(v0 - ATTN_FM));
                pl[(lq * 4 + r) * 56 + 16 + lm] = f2bf(__expf(v1 - ATTN_FM));
            }
        }
        asm volatile("" ::: "memory");
        const short8 pf0 = *(const short8*)(plw[0] + lm * 56 + lq * 8);
        const short8 pf1 = *(const short8*)(plw[1] + lm * 56 + lq * 8);
#pragma unroll
        for (int nt = 0; nt < 8; ++nt) {
            const short8 vf = *(const short8*)&sh.s.vst[ws][nt][lane * 8];
            acc[0][nt] = __builtin_amdgcn_mfma_f32_16x16x32_bf16(pf0, vf, acc[0][nt], 0, 0, 0);
            acc[1][nt] = __builtin_amdgcn_mfma_f32_16x16x32_bf16(pf1, vf, acc[1][nt], 0, 0, 0);
        }
        accl[0] = __builtin_amdgcn_mfma_f32_16x16x32_bf16(pf0, onesf, accl[0], 0, 0, 0);
        accl[1] = __builtin_amdgcn_mfma_f32_16x16x32_bf16(pf1, onesf, accl[1], 0, 0, 0);
        spc[0] = sp2[0]; spc[1] = sp2[1];
        pk += 8192; pv += 8192; pp += 8192;
    }

    // ---- combine the two key-halves through LDS (fixed-max softmax => partials additive) ----
    __syncthreads();
    if (ws == 1) {
#pragma unroll
        for (int qt = 0; qt < 2; ++qt) {
            float* cb = &sh.cmb[wh][qt][lane][0];
#pragma unroll
            for (int nt = 0; nt < 8; ++nt)
#pragma unroll
                for (int r = 0; r < 4; ++r) cb[nt * 4 + r] = acc[qt][nt][r];
#pragma unroll
            for (int r = 0; r < 4; ++r) cb[32 + r] = accl[qt][r];
        }
    }
    __syncthreads();
    if (ws == 1) return;
#pragma unroll
    for (int qt = 0; qt < 2; ++qt) {
        const float* cb = &sh.cmb[wh][qt][lane][0];
#pragma unroll
        for (int nt = 0; nt < 8; ++nt)
#pragma unroll
            for (int r = 0; r < 4; ++r) acc[qt][nt][r] += cb[nt * 4 + r];
#pragma unroll
        for (int r = 0; r < 4; ++r) accl[qt][r] += cb[32 + r];
    }

#pragma unroll
    for (int qt = 0; qt < 2; ++qt)
#pragma unroll
        for (int r = 0; r < 4; ++r) {
            const int tok = b * 1024 + s0 + qt * 16 + lq * 4 + r;
            const int e = selidx[tok * 8 + h];
            const float g = selval[tok * 8 + h] / accl[qt][r];
            const int mt = tok >> 4, tm = tok & 15;
#pragma unroll
            for (int nt = 0; nt < 8; ++nt) {
                const int k = e * 128 + nt * 16 + lm;
                const int kc = k >> 5;
                const int lane2 = (((k & 31) >> 3) << 4) + tm;
                zfrag[(((size_t)mt * 64 + kc) * 64 + lane2) * 8 + (k & 7)] = f2bf(acc[qt][nt][r] * g);
            }
        }
}

extern "C" void kernel_launch(void* const* d_in, const int* in_sizes, int n_in,
                              void* d_out, int out_size, void* d_ws, size_t ws_size,
                              hipStream_t stream) {
    const float* curr    = (const float*)d_in[0];  // (4,1024,1024)
    const float* attend  = (const float*)d_in[1];  // (4,1024,1024)
    const float* w_q     = (const float*)d_in[2];  // (16,1024,128)
    const float* w_kv    = (const float*)d_in[3];  // (1024,256)
    const float* w_out   = (const float*)d_in[4];  // (16,128,1024)
    const float* pos_pk  = (const float*)d_in[5];  // (128,1024)
    const float* sel_dst = (const float*)d_in[6];  // (16,1024)
    const float* scale   = (const float*)d_in[7];  // (1,)
    float* out = (float*)d_out;

    char* ws = (char*)d_ws;
    float* selval = (float*)ws;                                        // 128 KB
    int*   selidx = (int*)(ws + 131072);                               // 128 KB
    unsigned short* kposfg  = (unsigned short*)(ws + 262144);          // 512 KB
    unsigned short* kfragg  = (unsigned short*)(ws + 786432);          // 1 MB
    unsigned short* vfragg  = (unsigned short*)(ws + 1835008);         // 1 MB
    unsigned short* bfragq  = (unsigned short*)(ws + 2883584);         // 4 MB
    unsigned short* bfragw  = (unsigned short*)(ws + 7077888);         // 4 MB
    unsigned short* bfragkv = (unsigned short*)(ws + 11272192);        // 512 KB
    unsigned short* afrag   = (unsigned short*)(ws + 11796480);        // 8 MB (curr A-frag)
    unsigned short* qall    = (unsigned short*)(ws + 20185088);        // 16 MB
    unsigned short* zfrag   = (unsigned short*)(ws + 36962304);        // 16 MB
    // Aliases inside zfrag (all fully consumed by k_gemm3 BEFORE zfrag's memset):
    //   pefrag  = zfrag[0 .. 4MB)       (pe A-frag)
    //   bfragp  = zfrag[4MB .. 4.25MB)  (pos_pk B-frag)
    //   attfrag = zfrag[8MB .. 16MB)    (attend A-frag)
    unsigned short* pefrag  = zfrag;                                   // 4 MB
    unsigned short* bfragp  = zfrag + 2097152;                         // 256 KB
    unsigned short* attfrag = zfrag + 4194304;                         // 8 MB
    // total ~51.3 MB

    k_prep<<<18816, 256, 0, stream>>>(curr, attend, w_q, w_out, w_kv, pos_pk, sel_dst,
                                      selval, selidx, afrag, attfrag,
                                      bfragq, bfragw, bfragkv, bfragp, pefrag);
    k_gemm3<<<1184, 256, 0, stream>>>(afrag, bfragq, attfrag, bfragkv, pefrag, bfragp,
                                      scale, qall, kfragg, vfragg, kposfg);
    hipMemsetAsync(zfrag, 0, (size_t)16777216, stream);
    k_attn<<<512, 256, 0, stream>>>(qall, kfragg, vfragg, kposfg, selidx, selval, zfrag);
    k_gemm_out<<<512, 256, 0, stream>>>(zfrag, bfragw, out);
}